// Round 2
// baseline (1392.258 us; speedup 1.0000x reference)
//
#include <hip/hip_runtime.h>
#include <hip/hip_bf16.h>

using bf16 = __hip_bfloat16;
typedef __attribute__((ext_vector_type(8))) short short8;
typedef __attribute__((ext_vector_type(4))) float floatx4;
typedef __attribute__((ext_vector_type(8))) unsigned short ushort8;

__device__ __forceinline__ float b2f(unsigned short u) {
    union { unsigned int i; float f; } x; x.i = ((unsigned int)u) << 16; return x.f;
}

__device__ __forceinline__ void async16(const void* g, void* l) {
    __builtin_amdgcn_global_load_lds((const __attribute__((address_space(1))) void*)g,
                                     (__attribute__((address_space(3))) void*)l,
                                     16, 0, 0);
}

// ---------------------------------------------------------------------------
// Dtype sniffer: decide whether float tensors are fp32 (flag=1) or bf16 (0).
// Reads first 256 elements of a ~N(0,1) tensor as bf16; fp32-backed data
// decodes ~44% of low-half elements to |x|>1e4 (random exponent byte).
// ---------------------------------------------------------------------------
__global__ void sniff_dtype(const unsigned short* p, int* flag) {
    int wild = 0;
    for (int i = threadIdx.x; i < 256; i += 64) {
        float a = fabsf(b2f(p[i]));
        if (!(a <= 1e4f)) wild++;          // counts huge and NaN
    }
#pragma unroll
    for (int o = 1; o < 64; o <<= 1) wild += __shfl_xor(wild, o);
    if (threadIdx.x == 0) *flag = (wild > 16) ? 1 : 0;
}

// ---------------------------------------------------------------------------
// Convert float inputs (fp32 or bf16 per flag) to canonical bf16 mirrors.
// ---------------------------------------------------------------------------
struct Cvt { const void* src; bf16* dst; int n; };
struct CvtTable { Cvt e[18]; };

__global__ __launch_bounds__(256) void convert_inputs(CvtTable t, const int* flag) {
    const Cvt c = t.e[blockIdx.y];
    const bool f32 = (*flag != 0);
    const int stride = gridDim.x * 256 * 8;
    for (int i = (blockIdx.x * 256 + threadIdx.x) * 8; i < c.n; i += stride) {
        if (f32) {
            const float* s = (const float*)c.src + i;
#pragma unroll
            for (int j = 0; j < 8; ++j) c.dst[i + j] = __float2bfloat16(s[j]);
        } else {
            *(ushort8*)((unsigned short*)c.dst + i) =
                *(const ushort8*)((const unsigned short*)c.src + i);
        }
    }
}

// ---------------------------------------------------------------------------
// Dtype-aware transpose: out[C,R] = bf16(in[R,C])^T. grid (C/32, R/32).
// ---------------------------------------------------------------------------
__global__ __launch_bounds__(256) void transpose_any(
    const void* __restrict__ in, bf16* __restrict__ out, int R, int C,
    const int* __restrict__ flag)
{
    __shared__ bf16 tile[32][33];
    const bool f32 = (*flag != 0);
    const int tx = threadIdx.x & 31;
    const int ty = threadIdx.x >> 5;
    const int bc = blockIdx.x * 32;
    const int br = blockIdx.y * 32;
#pragma unroll
    for (int i = 0; i < 32; i += 8) {
        const size_t idx = (size_t)(br + ty + i) * C + bc + tx;
        tile[ty + i][tx] = f32 ? __float2bfloat16(((const float*)in)[idx])
                               : ((const bf16*)in)[idx];
    }
    __syncthreads();
#pragma unroll
    for (int i = 0; i < 32; i += 8)
        out[(size_t)(bc + ty + i) * R + br + tx] = tile[tx][ty + i];
}

// ---------------------------------------------------------------------------
// bf16 transpose (internal buffers only).
// ---------------------------------------------------------------------------
__global__ __launch_bounds__(256) void transpose_bf16_k(
    const bf16* __restrict__ in, bf16* __restrict__ out, int R, int C)
{
    __shared__ bf16 tile[32][33];
    const int tx = threadIdx.x & 31;
    const int ty = threadIdx.x >> 5;
    const int bc = blockIdx.x * 32;
    const int br = blockIdx.y * 32;
#pragma unroll
    for (int i = 0; i < 32; i += 8)
        tile[ty + i][tx] = in[(size_t)(br + ty + i) * C + bc + tx];
    __syncthreads();
#pragma unroll
    for (int i = 0; i < 32; i += 8)
        out[(size_t)(bc + ty + i) * R + br + tx] = tile[tx][ty + i];
}

// ---------------------------------------------------------------------------
// Generic C = A * B^T GEMM.  A: [M,K] row-major (lda), B: [N,K] row-major (ldb).
// 128 x BN tile, 4 waves, mfma_f32_16x16x32_bf16, global_load_lds staging.
// ---------------------------------------------------------------------------
template <int BN, bool BIAS, bool ADDC0, bool RELU, bool F32OUT>
__global__ __launch_bounds__(256) void gemm_bt(
    const bf16* __restrict__ A, int lda, long long a_kshift,
    const bf16* __restrict__ B, int ldb,
    void* __restrict__ Cout, int ldc,
    const bf16* __restrict__ C0, int ldc0,
    const bf16* __restrict__ bias,
    int K, float scale)
{
    constexpr int BM = 128;
    constexpr int WM = 64;
    constexpr int WN = BN / 2;
    constexpr int TM = WM / 16;     // 4
    constexpr int TN = WN / 16;     // 4 (BN=128) or 2 (BN=64)

    __align__(16) __shared__ bf16 As[BM * 32];
    __align__(16) __shared__ bf16 Bs[BN * 32];

    const int tid  = threadIdx.x;
    const int lane = tid & 63;
    const int wv   = tid >> 6;
    const int m_base = blockIdx.y * BM;
    const int n_base = blockIdx.x * BN;
    A += (long long)blockIdx.x * a_kshift;

    const int wm0 = (wv >> 1) * WM;
    const int wn0 = (wv & 1) * WN;

    floatx4 zero = {0.f, 0.f, 0.f, 0.f};
    floatx4 acc[TM][TN];
#pragma unroll
    for (int mt = 0; mt < TM; ++mt)
#pragma unroll
        for (int nt = 0; nt < TN; ++nt) acc[mt][nt] = zero;

    const int ar = lane >> 2;        // row within 16-row staging chunk
    const int ac = (lane & 3) * 8;   // col (elements) within a row
    const int fr = lane & 15;
    const int fk = (lane >> 4) * 8;

    for (int k0 = 0; k0 < K; k0 += 32) {
#pragma unroll
        for (int cc = 0; cc < BM / 64; ++cc) {
            const int r0t = (wv + cc * 4) * 16;
            const bf16* g = A + (size_t)(m_base + r0t + ar) * lda + k0 + ac;
            async16(g, &As[r0t * 32]);
        }
#pragma unroll
        for (int cc = 0; cc < BN / 64; ++cc) {
            const int r0t = (wv + cc * 4) * 16;
            const bf16* g = B + (size_t)(n_base + r0t + ar) * ldb + k0 + ac;
            async16(g, &Bs[r0t * 32]);
        }
        __syncthreads();

        short8 af[TM], bfrag[TN];
#pragma unroll
        for (int mt = 0; mt < TM; ++mt)
            af[mt] = *(const short8*)&As[(wm0 + mt * 16 + fr) * 32 + fk];
#pragma unroll
        for (int nt = 0; nt < TN; ++nt)
            bfrag[nt] = *(const short8*)&Bs[(wn0 + nt * 16 + fr) * 32 + fk];
#pragma unroll
        for (int mt = 0; mt < TM; ++mt)
#pragma unroll
            for (int nt = 0; nt < TN; ++nt)
                acc[mt][nt] = __builtin_amdgcn_mfma_f32_16x16x32_bf16(
                    af[mt], bfrag[nt], acc[mt][nt], 0, 0, 0);
        __syncthreads();
    }

    // C layout: col = lane&15, row = (lane>>4)*4 + reg  [m89/m91]
    const int er = lane >> 4;
    const int ec = lane & 15;
#pragma unroll
    for (int nt = 0; nt < TN; ++nt) {
        const int col = n_base + wn0 + nt * 16 + ec;
        float bv = 0.f;
        if constexpr (BIAS) bv = __bfloat162float(bias[col]);
#pragma unroll
        for (int mt = 0; mt < TM; ++mt) {
#pragma unroll
            for (int r = 0; r < 4; ++r) {
                const int row = m_base + wm0 + mt * 16 + er * 4 + r;
                float v = acc[mt][nt][r] * scale + bv;
                if constexpr (ADDC0) v += __bfloat162float(C0[(size_t)row * ldc0 + col]);
                if constexpr (RELU) v = fmaxf(v, 0.f);
                if constexpr (F32OUT)
                    ((float*)Cout)[(size_t)row * ldc + col] = v;
                else
                    ((bf16*)Cout)[(size_t)row * ldc + col] = __float2bfloat16(v);
            }
        }
    }
}

// ---------------------------------------------------------------------------
// Fused scores + mask + softmax for one head, 16 query rows per block.
// ---------------------------------------------------------------------------
__global__ __launch_bounds__(256) void scores_softmax(
    const bf16* __restrict__ Q, const bf16* __restrict__ Kmat,
    const int* __restrict__ mask, bf16* __restrict__ aw, float scale)
{
    __align__(16) __shared__ float Qs[16][68];
    __align__(16) __shared__ bf16 Ks[256][72];   // 144B row stride, mult of 16

    const int t   = threadIdx.x;
    const int h   = blockIdx.y;
    const int r0  = blockIdx.x * 16;
    const int row = t >> 4;
    const int l16 = t & 15;

    {
        const int qr = t >> 4, qc = (t & 15) * 4;
        const unsigned short* qp =
            (const unsigned short*)Q + (size_t)(r0 + qr) * 512 + h * 64 + qc;
#pragma unroll
        for (int i = 0; i < 4; ++i) Qs[qr][qc + i] = b2f(qp[i]);
    }

    float sc[64];
    const unsigned short* Ku = (const unsigned short*)Kmat;

#pragma unroll
    for (int c = 0; c < 4; ++c) {
        const int mc = c * 256;
        __syncthreads();
#pragma unroll
        for (int p = 0; p < 4; ++p) {
            const int r = p * 64 + (t >> 2);
            const int cb = (t & 3) * 16;
            const ushort8* gp = (const ushort8*)(Ku + (size_t)(mc + r) * 512 + h * 64 + cb);
            *(ushort8*)((unsigned short*)&Ks[r][cb])     = gp[0];
            *(ushort8*)((unsigned short*)&Ks[r][cb + 8]) = gp[1];
        }
        __syncthreads();
#pragma unroll
        for (int u = 0; u < 16; ++u) {
            const int ml = u * 16 + l16;
            const unsigned short* kr = (const unsigned short*)&Ks[ml][0];
            const float* qr = &Qs[row][0];
            float acc = 0.f;
#pragma unroll
            for (int kk = 0; kk < 64; kk += 8) {
                ushort8 kv = *(const ushort8*)(kr + kk);
                acc += qr[kk+0]*b2f(kv[0]) + qr[kk+1]*b2f(kv[1])
                     + qr[kk+2]*b2f(kv[2]) + qr[kk+3]*b2f(kv[3])
                     + qr[kk+4]*b2f(kv[4]) + qr[kk+5]*b2f(kv[5])
                     + qr[kk+6]*b2f(kv[6]) + qr[kk+7]*b2f(kv[7]);
            }
            sc[c * 16 + u] = acc * scale;
        }
    }

    const int gr = r0 + row;
#pragma unroll
    for (int v = 0; v < 64; ++v) {
        const int m = (v >> 4) * 256 + (v & 15) * 16 + l16;
        if (mask[(size_t)gr * 1024 + m] == 0) sc[v] = -1e9f;
    }
    float mx = -3e38f;
#pragma unroll
    for (int v = 0; v < 64; ++v) mx = fmaxf(mx, sc[v]);
#pragma unroll
    for (int o = 1; o < 16; o <<= 1) mx = fmaxf(mx, __shfl_xor(mx, o));
    float sum = 0.f;
#pragma unroll
    for (int v = 0; v < 64; ++v) { float e = __expf(sc[v] - mx); sc[v] = e; sum += e; }
#pragma unroll
    for (int o = 1; o < 16; o <<= 1) sum += __shfl_xor(sum, o);
    const float inv = 1.0f / sum;
#pragma unroll
    for (int v = 0; v < 64; ++v) {
        const int m = (v >> 4) * 256 + (v & 15) * 16 + l16;
        aw[(size_t)gr * 8192 + h * 1024 + m] = __float2bfloat16(sc[v] * inv);
    }
}

// ---------------------------------------------------------------------------
// LayerNorm over 256 cols, fp32 in -> bf16/fp32 out per flag. 4 rows/block.
// ---------------------------------------------------------------------------
__global__ __launch_bounds__(256) void ln_rows(
    const float* __restrict__ X, const bf16* __restrict__ g,
    const bf16* __restrict__ b, void* __restrict__ out, size_t row0, int rows,
    const int* __restrict__ flag)
{
    const bool f32 = (*flag != 0);
    const int lane = threadIdx.x & 63;
    const int wv   = threadIdx.x >> 6;
    const int row  = blockIdx.x * 4 + wv;
    if (row >= rows) return;
    const float* x = X + (size_t)row * 256;
    float v[4], s = 0.f, s2 = 0.f;
#pragma unroll
    for (int i = 0; i < 4; ++i) {
        v[i] = x[lane + 64 * i];
        s += v[i]; s2 += v[i] * v[i];
    }
#pragma unroll
    for (int o = 1; o < 64; o <<= 1) { s += __shfl_xor(s, o); s2 += __shfl_xor(s2, o); }
    const float mu  = s * (1.0f / 256.0f);
    const float var = fmaxf(s2 * (1.0f / 256.0f) - mu * mu, 0.0f);
    const float inv = rsqrtf(var + 1e-5f);
#pragma unroll
    for (int i = 0; i < 4; ++i) {
        const int c = lane + 64 * i;
        const float y = (v[i] - mu) * inv * __bfloat162float(g[c]) + __bfloat162float(b[c]);
        if (f32) ((float*)out)[(row0 + row) * 256 + c] = y;
        else     ((bf16*)out)[(row0 + row) * 256 + c] = __float2bfloat16(y);
    }
}

// ---------------------------------------------------------------------------
extern "C" void kernel_launch(void* const* d_in, const int* in_sizes, int n_in,
                              void* d_out, int out_size, void* d_ws, size_t ws_size,
                              hipStream_t stream)
{
    const int L = 4096, Mm = 1024, P = 4096;

    const int* mask_l = (const int*)d_in[3];
    const int* mask_p = (const int*)d_in[4];

    char* ws = (char*)d_ws;
    size_t off = 0;
    auto alloc = [&](size_t bytes) {
        void* p = ws + off; off += (bytes + 255) & ~(size_t)255; return p;
    };

    int*  flag  = (int*)alloc(256);
    bf16* WT[9]; for (int i = 0; i < 9; ++i) WT[i] = (bf16*)alloc(512 * 512 * 2);
    bf16* WmlT  = (bf16*)alloc(1024 * 256 * 2);
    bf16* WmpT  = (bf16*)alloc(1024 * 256 * 2);
    bf16* bias_c[9]; for (int i = 0; i < 9; ++i) bias_c[i] = (bf16*)alloc(512 * 2);
    bf16* bml_c = (bf16*)alloc(256 * 2);
    bf16* bmp_c = (bf16*)alloc(256 * 2);
    bf16* g1c   = (bf16*)alloc(256 * 2);
    bf16* be1c  = (bf16*)alloc(256 * 2);
    bf16* g2c   = (bf16*)alloc(256 * 2);
    bf16* be2c  = (bf16*)alloc(256 * 2);
    bf16* embl  = (bf16*)alloc((size_t)L * 512 * 2);
    bf16* embm  = (bf16*)alloc((size_t)Mm * 512 * 2);
    bf16* embp  = (bf16*)alloc((size_t)P * 512 * 2);
    bf16* cat_l = (bf16*)alloc((size_t)L * 1024 * 2);   // [lt | fin_l]
    bf16* cat_p = (bf16*)alloc((size_t)P * 1024 * 2);   // [fin_p | pt]
    bf16* mt    = (bf16*)alloc((size_t)Mm * 512 * 2);
    bf16* Ql    = (bf16*)alloc((size_t)L * 512 * 2);
    bf16* Qp    = (bf16*)alloc((size_t)P * 512 * 2);
    bf16* Kl    = (bf16*)alloc((size_t)Mm * 512 * 2);
    bf16* Kp    = (bf16*)alloc((size_t)Mm * 512 * 2);
    bf16* Vl    = (bf16*)alloc((size_t)Mm * 512 * 2);
    bf16* Vp    = (bf16*)alloc((size_t)Mm * 512 * 2);
    bf16* VlT   = (bf16*)alloc((size_t)512 * Mm * 2);
    bf16* VpT   = (bf16*)alloc((size_t)512 * Mm * 2);
    bf16* ctx_l = (bf16*)alloc((size_t)L * 512 * 2);
    bf16* ctx_p = (bf16*)alloc((size_t)P * 512 * 2);
    bf16* ctxlT = (bf16*)alloc((size_t)512 * L * 2);
    bf16* ctxpT = (bf16*)alloc((size_t)512 * P * 2);
    bf16* mutual = (bf16*)alloc((size_t)L * P * 2);
    bf16* awl   = (bf16*)alloc((size_t)L * 8192 * 2);
    bf16* awp   = (bf16*)alloc((size_t)P * 8192 * 2);
    // overlays (dead-after-mutual-GEMM regions)
    bf16*  mutualT = awl;                        // 33.5MB into awl's 67MB
    float* tmp1    = (float*)awp;                // 4MB
    float* tmp2    = (float*)awp + (size_t)L * 256;

    // 0. dtype sniff + input canonicalization
    sniff_dtype<<<1, 64, 0, stream>>>((const unsigned short*)d_in[0], flag);

    CvtTable tab;
    tab.e[0] = { d_in[0], embl, L * 512 };
    tab.e[1] = { d_in[1], embm, Mm * 512 };
    tab.e[2] = { d_in[2], embp, P * 512 };
    for (int i = 0; i < 9; ++i) tab.e[3 + i] = { d_in[6 + 2 * i], bias_c[i], 512 };
    tab.e[12] = { d_in[24], bml_c, 256 };
    tab.e[13] = { d_in[26], bmp_c, 256 };
    tab.e[14] = { d_in[27], g1c,  256 };
    tab.e[15] = { d_in[28], be1c, 256 };
    tab.e[16] = { d_in[29], g2c,  256 };
    tab.e[17] = { d_in[30], be2c, 256 };
    convert_inputs<<<dim3(256, 18), 256, 0, stream>>>(tab, flag);

    // 1. weight transposes (dtype-aware; gemm_bt wants B as [N,K] row-major)
    for (int i = 0; i < 9; ++i)
        transpose_any<<<dim3(16, 16), 256, 0, stream>>>(d_in[5 + 2 * i], WT[i], 512, 512, flag);
    transpose_any<<<dim3(8, 32), 256, 0, stream>>>(d_in[23], WmlT, 1024, 256, flag);
    transpose_any<<<dim3(8, 32), 256, 0, stream>>>(d_in[25], WmpT, 1024, 256, flag);

    // 2. input projections
    gemm_bt<128, true, false, false, false><<<dim3(4, 32), 256, 0, stream>>>(
        embl, 512, 0, WT[0], 512, cat_l, 1024, nullptr, 0, bias_c[0], 512, 1.0f);
    gemm_bt<128, true, false, false, false><<<dim3(4, 8), 256, 0, stream>>>(
        embm, 512, 0, WT[1], 512, mt, 512, nullptr, 0, bias_c[1], 512, 1.0f);
    gemm_bt<128, true, false, false, false><<<dim3(4, 32), 256, 0, stream>>>(
        embp, 512, 0, WT[2], 512, cat_p + 512, 1024, nullptr, 0, bias_c[2], 512, 1.0f);

    // 3. QKV projections
    gemm_bt<128, true, false, false, false><<<dim3(4, 32), 256, 0, stream>>>(
        cat_l, 1024, 0, WT[3], 512, Ql, 512, nullptr, 0, bias_c[3], 512, 1.0f);
    gemm_bt<128, true, false, false, false><<<dim3(4, 8), 256, 0, stream>>>(
        mt, 512, 0, WT[4], 512, Kl, 512, nullptr, 0, bias_c[4], 512, 1.0f);
    gemm_bt<128, true, false, false, false><<<dim3(4, 8), 256, 0, stream>>>(
        mt, 512, 0, WT[5], 512, Vl, 512, nullptr, 0, bias_c[5], 512, 1.0f);
    gemm_bt<128, true, false, false, false><<<dim3(4, 32), 256, 0, stream>>>(
        cat_p + 512, 1024, 0, WT[6], 512, Qp, 512, nullptr, 0, bias_c[6], 512, 1.0f);
    gemm_bt<128, true, false, false, false><<<dim3(4, 8), 256, 0, stream>>>(
        mt, 512, 0, WT[7], 512, Kp, 512, nullptr, 0, bias_c[7], 512, 1.0f);
    gemm_bt<128, true, false, false, false><<<dim3(4, 8), 256, 0, stream>>>(
        mt, 512, 0, WT[8], 512, Vp, 512, nullptr, 0, bias_c[8], 512, 1.0f);

    transpose_bf16_k<<<dim3(16, 32), 256, 0, stream>>>(Vl, VlT, 1024, 512);
    transpose_bf16_k<<<dim3(16, 32), 256, 0, stream>>>(Vp, VpT, 1024, 512);

    // 4. fused scores + mask + softmax  (scale = 1/sqrt(64))
    scores_softmax<<<dim3(256, 8), 256, 0, stream>>>(Ql, Kl, mask_l, awl, 0.125f);
    scores_softmax<<<dim3(256, 8), 256, 0, stream>>>(Qp, Kp, mask_p, awp, 0.125f);

    // 5. ctx = relu(aw @ V) per head
    gemm_bt<64, false, false, true, false><<<dim3(8, 32), 256, 0, stream>>>(
        awl, 8192, 1024, VlT, 1024, ctx_l, 512, nullptr, 0, nullptr, 1024, 1.0f);
    gemm_bt<64, false, false, true, false><<<dim3(8, 32), 256, 0, stream>>>(
        awp, 8192, 1024, VpT, 1024, ctx_p, 512, nullptr, 0, nullptr, 1024, 1.0f);

    transpose_bf16_k<<<dim3(16, 128), 256, 0, stream>>>(ctx_l, ctxlT, 4096, 512);
    transpose_bf16_k<<<dim3(16, 128), 256, 0, stream>>>(ctx_p, ctxpT, 4096, 512);

    // 6. mutual = (awl_flat @ awp_flat^T) / 8
    gemm_bt<128, false, false, false, false><<<dim3(32, 32), 256, 0, stream>>>(
        awl, 8192, 0, awp, 8192, mutual, 4096, nullptr, 0, nullptr, 8192, 0.125f);
    // awl/awp now dead; mutualT overlays awl, tmp1/2 overlay awp
    transpose_bf16_k<<<dim3(128, 128), 256, 0, stream>>>(mutual, mutualT, 4096, 4096);

    // 7. fin_l -> cat_l[:,512:]; fin_p -> cat_p[:,:512]
    gemm_bt<128, false, true, false, false><<<dim3(4, 32), 256, 0, stream>>>(
        mutual, 4096, 0, ctxpT, 4096, cat_l + 512, 1024, ctx_l, 512, nullptr, 4096, 1.0f);
    gemm_bt<128, false, true, false, false><<<dim3(4, 32), 256, 0, stream>>>(
        mutualT, 4096, 0, ctxlT, 4096, cat_p, 1024, ctx_p, 512, nullptr, 4096, 1.0f);

    // 8. final projections (fp32) + LayerNorm -> d_out (dtype per flag)
    gemm_bt<128, true, false, false, true><<<dim3(2, 32), 256, 0, stream>>>(
        cat_l, 1024, 0, WmlT, 1024, tmp1, 256, nullptr, 0, bml_c, 1024, 1.0f);
    gemm_bt<128, true, false, false, true><<<dim3(2, 32), 256, 0, stream>>>(
        cat_p, 1024, 0, WmpT, 1024, tmp2, 256, nullptr, 0, bmp_c, 1024, 1.0f);

    ln_rows<<<dim3(1024), 256, 0, stream>>>(tmp1, g1c, be1c, d_out, 0, L, flag);
    ln_rows<<<dim3(1024), 256, 0, stream>>>(tmp2, g2c, be2c, d_out, (size_t)L, P, flag);
}

// Round 3
// 1110.960 us; speedup vs baseline: 1.2532x; 1.2532x over previous
//
#include <hip/hip_runtime.h>
#include <hip/hip_bf16.h>

using bf16 = __hip_bfloat16;
typedef __attribute__((ext_vector_type(8))) short short8;
typedef __attribute__((ext_vector_type(4))) float floatx4;
typedef __attribute__((ext_vector_type(8))) unsigned short ushort8;

__device__ __forceinline__ float b2f(unsigned short u) {
    union { unsigned int i; float f; } x; x.i = ((unsigned int)u) << 16; return x.f;
}

__device__ __forceinline__ void async16(const void* g, void* l) {
    __builtin_amdgcn_global_load_lds((const __attribute__((address_space(1))) void*)g,
                                     (__attribute__((address_space(3))) void*)l,
                                     16, 0, 0);
}

// float -> OCP e4m3fn, RNE, signed, |f| clamped to 448.
__device__ __forceinline__ unsigned char f2e4m3(float f) {
    unsigned s = (__float_as_uint(f) >> 24) & 0x80u;
    f = fminf(fabsf(f), 448.f);
    if (f < 0.015625f) {                       // denormal target: ulp 2^-9
        int d = (int)rintf(f * 512.f);         // 0..8 (8 -> min normal 2^-6)
        return (unsigned char)(s | (unsigned)d);
    }
    int E = (int)((__float_as_uint(f) >> 23) & 255u) - 127;
    float ulp_inv = __uint_as_float((unsigned)(127 + 3 - E) << 23); // 2^(3-E)
    int m = (int)rintf(f * ulp_inv);           // 8..16
    int n = (m == 16) ? ((E + 8) << 3) : (((E + 7) << 3) + (m - 8));
    if (n > 0x7E) n = 0x7E;
    return (unsigned char)(s | (unsigned)n);
}

// ---------------------------------------------------------------------------
// Dtype sniffer: fp32 data read as bf16 decodes ~44% wild exponents.
// ---------------------------------------------------------------------------
__global__ void sniff_dtype(const unsigned short* p, int* flag) {
    int wild = 0;
    for (int i = threadIdx.x; i < 256; i += 64) {
        float a = fabsf(b2f(p[i]));
        if (!(a <= 1e4f)) wild++;
    }
#pragma unroll
    for (int o = 1; o < 64; o <<= 1) wild += __shfl_xor(wild, o);
    if (threadIdx.x == 0) *flag = (wild > 16) ? 1 : 0;
}

// ---------------------------------------------------------------------------
// Convert float inputs (fp32 or bf16 per flag) to canonical bf16 mirrors.
// ---------------------------------------------------------------------------
struct Cvt { const void* src; bf16* dst; int n; };
struct CvtTable { Cvt e[18]; };

__global__ __launch_bounds__(256) void convert_inputs(CvtTable t, const int* flag) {
    const Cvt c = t.e[blockIdx.y];
    const bool f32 = (*flag != 0);
    const int stride = gridDim.x * 256 * 8;
    for (int i = (blockIdx.x * 256 + threadIdx.x) * 8; i < c.n; i += stride) {
        if (f32) {
            const float* s = (const float*)c.src + i;
#pragma unroll
            for (int j = 0; j < 8; ++j) c.dst[i + j] = __float2bfloat16(s[j]);
        } else {
            *(ushort8*)((unsigned short*)c.dst + i) =
                *(const ushort8*)((const unsigned short*)c.src + i);
        }
    }
}

// ---------------------------------------------------------------------------
// Batched 512x512 dtype-aware transpose for the 9 square weights.
// ---------------------------------------------------------------------------
struct TT9 { const void* src[9]; bf16* dst[9]; };

__global__ __launch_bounds__(256) void transpose_sq9(TT9 t, const int* flag) {
    __shared__ bf16 tile[32][33];
    const void* in = t.src[blockIdx.z];
    bf16* out = t.dst[blockIdx.z];
    const bool f32 = (*flag != 0);
    const int tx = threadIdx.x & 31;
    const int ty = threadIdx.x >> 5;
    const int bc = blockIdx.x * 32;
    const int br = blockIdx.y * 32;
#pragma unroll
    for (int i = 0; i < 32; i += 8) {
        const size_t idx = (size_t)(br + ty + i) * 512 + bc + tx;
        tile[ty + i][tx] = f32 ? __float2bfloat16(((const float*)in)[idx])
                               : ((const bf16*)in)[idx];
    }
    __syncthreads();
#pragma unroll
    for (int i = 0; i < 32; i += 8)
        out[(size_t)(bc + ty + i) * 512 + br + tx] = tile[tx][ty + i];
}

// ---------------------------------------------------------------------------
// Dtype-aware rectangular transpose (for Wml/Wmp). out[C,R] = in[R,C]^T.
// ---------------------------------------------------------------------------
__global__ __launch_bounds__(256) void transpose_any_ld(
    const void* __restrict__ in, int ils, bf16* __restrict__ out,
    int R, int C, const int* __restrict__ flag)
{
    __shared__ bf16 tile[32][33];
    const bool f32 = (*flag != 0);
    const int tx = threadIdx.x & 31;
    const int ty = threadIdx.x >> 5;
    const int bc = blockIdx.x * 32;
    const int br = blockIdx.y * 32;
#pragma unroll
    for (int i = 0; i < 32; i += 8) {
        const size_t idx = (size_t)(br + ty + i) * ils + bc + tx;
        tile[ty + i][tx] = f32 ? __float2bfloat16(((const float*)in)[idx])
                               : ((const bf16*)in)[idx];
    }
    __syncthreads();
#pragma unroll
    for (int i = 0; i < 32; i += 8)
        out[(size_t)(bc + ty + i) * R + br + tx] = tile[tx][ty + i];
}

// ---------------------------------------------------------------------------
// bf16 transpose with input ld (internal buffers). out[C,R] = in[R,C]^T.
// ---------------------------------------------------------------------------
__global__ __launch_bounds__(256) void transpose_bf16_ld(
    const bf16* __restrict__ in, int ils, bf16* __restrict__ out, int R, int C)
{
    __shared__ bf16 tile[32][33];
    const int tx = threadIdx.x & 31;
    const int ty = threadIdx.x >> 5;
    const int bc = blockIdx.x * 32;
    const int br = blockIdx.y * 32;
#pragma unroll
    for (int i = 0; i < 32; i += 8)
        tile[ty + i][tx] = in[(size_t)(br + ty + i) * ils + bc + tx];
    __syncthreads();
#pragma unroll
    for (int i = 0; i < 32; i += 8)
        out[(size_t)(bc + ty + i) * R + br + tx] = tile[tx][ty + i];
}

// ---------------------------------------------------------------------------
// Quantizing transpose: out[C,R] = e4m3(in[R,C]^T * vs).  (for V -> V8T)
// ---------------------------------------------------------------------------
__global__ __launch_bounds__(256) void transpose_q8(
    const bf16* __restrict__ in, int ils, unsigned char* __restrict__ out,
    int R, int C, float vs)
{
    __shared__ float tile[32][33];
    const int tx = threadIdx.x & 31;
    const int ty = threadIdx.x >> 5;
    const int bc = blockIdx.x * 32;
    const int br = blockIdx.y * 32;
#pragma unroll
    for (int i = 0; i < 32; i += 8)
        tile[ty + i][tx] =
            __bfloat162float(in[(size_t)(br + ty + i) * ils + bc + tx]) * vs;
    __syncthreads();
#pragma unroll
    for (int i = 0; i < 32; i += 8)
        out[(size_t)(bc + ty + i) * R + br + tx] = f2e4m3(tile[tx][ty + i]);
}

// ---------------------------------------------------------------------------
// Generic bf16 C = A * B^T GEMM (m97 structure). A:[M,K] lda, B:[N,K] ldb.
// ---------------------------------------------------------------------------
template <int BN, bool BIAS, bool ADDC0, bool RELU, bool F32OUT>
__global__ __launch_bounds__(256) void gemm_bt(
    const bf16* __restrict__ A, int lda,
    const bf16* __restrict__ B, int ldb,
    void* __restrict__ Cout, int ldc,
    const bf16* __restrict__ C0, int ldc0,
    const bf16* __restrict__ bias,
    int K, float scale)
{
    constexpr int BM = 128;
    constexpr int WN = BN / 2;
    constexpr int TM = 4;
    constexpr int TN = WN / 16;

    __align__(16) __shared__ bf16 As[BM * 32];
    __align__(16) __shared__ bf16 Bs[BN * 32];

    const int tid  = threadIdx.x;
    const int lane = tid & 63;
    const int wv   = tid >> 6;
    const int m_base = blockIdx.y * BM;
    const int n_base = blockIdx.x * BN;

    const int wm0 = (wv >> 1) * 64;
    const int wn0 = (wv & 1) * WN;

    floatx4 zero = {0.f, 0.f, 0.f, 0.f};
    floatx4 acc[TM][TN];
#pragma unroll
    for (int mt = 0; mt < TM; ++mt)
#pragma unroll
        for (int nt = 0; nt < TN; ++nt) acc[mt][nt] = zero;

    const int ar = lane >> 2;
    const int ac = (lane & 3) * 8;
    const int fr = lane & 15;
    const int fk = (lane >> 4) * 8;

    for (int k0 = 0; k0 < K; k0 += 32) {
#pragma unroll
        for (int cc = 0; cc < BM / 64; ++cc) {
            const int r0t = (wv + cc * 4) * 16;
            async16(A + (size_t)(m_base + r0t + ar) * lda + k0 + ac, &As[r0t * 32]);
        }
#pragma unroll
        for (int cc = 0; cc < BN / 64; ++cc) {
            const int r0t = (wv + cc * 4) * 16;
            async16(B + (size_t)(n_base + r0t + ar) * ldb + k0 + ac, &Bs[r0t * 32]);
        }
        __syncthreads();

        short8 af[TM], bfrag[TN];
#pragma unroll
        for (int mt = 0; mt < TM; ++mt)
            af[mt] = *(const short8*)&As[(wm0 + mt * 16 + fr) * 32 + fk];
#pragma unroll
        for (int nt = 0; nt < TN; ++nt)
            bfrag[nt] = *(const short8*)&Bs[(wn0 + nt * 16 + fr) * 32 + fk];
#pragma unroll
        for (int mt = 0; mt < TM; ++mt)
#pragma unroll
            for (int nt = 0; nt < TN; ++nt)
                acc[mt][nt] = __builtin_amdgcn_mfma_f32_16x16x32_bf16(
                    af[mt], bfrag[nt], acc[mt][nt], 0, 0, 0);
        __syncthreads();
    }

    const int er = lane >> 4;
    const int ec = lane & 15;
#pragma unroll
    for (int nt = 0; nt < TN; ++nt) {
        const int col = n_base + wn0 + nt * 16 + ec;
        float bv = 0.f;
        if constexpr (BIAS) bv = __bfloat162float(bias[col]);
#pragma unroll
        for (int mt = 0; mt < TM; ++mt) {
#pragma unroll
            for (int r = 0; r < 4; ++r) {
                const int row = m_base + wm0 + mt * 16 + er * 4 + r;
                float v = acc[mt][nt][r] * scale + bv;
                if constexpr (ADDC0) v += __bfloat162float(C0[(size_t)row * ldc0 + col]);
                if constexpr (RELU) v = fmaxf(v, 0.f);
                if constexpr (F32OUT)
                    ((float*)Cout)[(size_t)row * ldc + col] = v;
                else
                    ((bf16*)Cout)[(size_t)row * ldc + col] = __float2bfloat16(v);
            }
        }
    }
}

// ---------------------------------------------------------------------------
// fp8 C = A * B^T GEMM, BK=64, mfma_f32_16x16x32_fp8_fp8, 32 MFMA/barrier.
// a_kshift: per-n-block byte shift of A (per-head ctx GEMM).
// ---------------------------------------------------------------------------
template <int BN, bool RELU>
__global__ __launch_bounds__(256) void gemm_bt8(
    const unsigned char* __restrict__ A, int lda, long long a_kshift,
    const unsigned char* __restrict__ B, int ldb,
    bf16* __restrict__ C, int ldc,
    int K, float scale)
{
    constexpr int BM = 128;
    constexpr int WN = BN / 2;
    constexpr int TM = 4;
    constexpr int TN = WN / 16;

    __align__(16) __shared__ unsigned char As[BM * 64];
    __align__(16) __shared__ unsigned char Bs[BN * 64];

    const int tid  = threadIdx.x;
    const int lane = tid & 63;
    const int wv   = tid >> 6;
    const int m_base = blockIdx.y * BM;
    const int n_base = blockIdx.x * BN;
    A += (long long)blockIdx.x * a_kshift;

    const int wm0 = (wv >> 1) * 64;
    const int wn0 = (wv & 1) * WN;

    floatx4 zero = {0.f, 0.f, 0.f, 0.f};
    floatx4 acc[TM][TN];
#pragma unroll
    for (int mt = 0; mt < TM; ++mt)
#pragma unroll
        for (int nt = 0; nt < TN; ++nt) acc[mt][nt] = zero;

    const int ar = lane >> 2;          // 16 rows per staging instr
    const int ac = (lane & 3) * 16;    // 16B per lane within 64B row
    const int fr = lane & 15;
    const int fk = (lane >> 4) * 8;    // 8 fp8 per lane per k-step

    for (int k0 = 0; k0 < K; k0 += 64) {
#pragma unroll
        for (int cc = 0; cc < BM / 16; cc += 4) {
            const int r0t = (wv + cc) * 16;
            async16(A + (size_t)(m_base + r0t + ar) * lda + k0 + ac, &As[r0t * 64]);
        }
#pragma unroll
        for (int cc = 0; cc < BN / 16; cc += 4) {
            const int r0t = (wv + cc) * 16;
            async16(B + (size_t)(n_base + r0t + ar) * ldb + k0 + ac, &Bs[r0t * 64]);
        }
        __syncthreads();

#pragma unroll
        for (int s = 0; s < 2; ++s) {
            long af[TM], bfr[TN];
#pragma unroll
            for (int mt = 0; mt < TM; ++mt)
                af[mt] = *(const long*)&As[(wm0 + mt * 16 + fr) * 64 + s * 32 + fk];
#pragma unroll
            for (int nt = 0; nt < TN; ++nt)
                bfr[nt] = *(const long*)&Bs[(wn0 + nt * 16 + fr) * 64 + s * 32 + fk];
#pragma unroll
            for (int mt = 0; mt < TM; ++mt)
#pragma unroll
                for (int nt = 0; nt < TN; ++nt)
                    acc[mt][nt] = __builtin_amdgcn_mfma_f32_16x16x32_fp8_fp8(
                        af[mt], bfr[nt], acc[mt][nt], 0, 0, 0);
        }
        __syncthreads();
    }

    const int er = lane >> 4;
    const int ec = lane & 15;
#pragma unroll
    for (int nt = 0; nt < TN; ++nt) {
        const int col = n_base + wn0 + nt * 16 + ec;
#pragma unroll
        for (int mt = 0; mt < TM; ++mt) {
#pragma unroll
            for (int r = 0; r < 4; ++r) {
                const int row = m_base + wm0 + mt * 16 + er * 4 + r;
                float v = acc[mt][nt][r] * scale;
                if constexpr (RELU) v = fmaxf(v, 0.f);
                C[(size_t)row * ldc + col] = __float2bfloat16(v);
            }
        }
    }
}

// ---------------------------------------------------------------------------
// MFMA fused scores + mask + softmax. Block = 16 Q-rows x 1024 cols, 1 head.
// Wave w covers cols [256w, 256w+256); scores stay in C-layout registers.
// Output: aw8 = e4m3(softmax * 32) at [row, h*1024 + col].
// ---------------------------------------------------------------------------
__global__ __launch_bounds__(256) void scores_mfma(
    const bf16* __restrict__ Q,          // [Nq, 512]
    const bf16* __restrict__ Kbase,      // [1024, ldk] (head cols at h*64)
    int ldk,
    const int* __restrict__ mask,        // [Nq, 1024]
    unsigned char* __restrict__ aw8,     // [Nq, 8192]
    float scale)
{
    __shared__ float wred[16][4];
    __shared__ float wsum[16][4];

    const int t    = threadIdx.x;
    const int lane = t & 63;
    const int w    = t >> 6;
    const int h    = blockIdx.y;
    const int r0   = blockIdx.x * 16;
    const int fr   = lane & 15;
    const int fq   = lane >> 4;
    const int cbase = w * 256;

    // A fragments: Q row r0+fr, k = kc*32 + fq*8 .. +8
    const short* Qs = (const short*)Q + (size_t)(r0 + fr) * 512 + h * 64 + fq * 8;
    short8 a0 = *(const short8*)(Qs);
    short8 a1 = *(const short8*)(Qs + 32);

    floatx4 accs[16];
    const short* Kb = (const short*)Kbase + h * 64 + fq * 8;
#pragma unroll
    for (int c = 0; c < 16; ++c) {
        const int krow = cbase + c * 16 + fr;
        short8 b0 = *(const short8*)(Kb + (size_t)krow * ldk);
        short8 b1 = *(const short8*)(Kb + (size_t)krow * ldk + 32);
        floatx4 acc = {0.f, 0.f, 0.f, 0.f};
        acc = __builtin_amdgcn_mfma_f32_16x16x32_bf16(a0, b0, acc, 0, 0, 0);
        acc = __builtin_amdgcn_mfma_f32_16x16x32_bf16(a1, b1, acc, 0, 0, 0);
        accs[c] = acc;
    }

    // mask + scale (C-layout: col = cbase + c*16 + fr, row = fq*4 + r)
    float mxr[4] = {-3e38f, -3e38f, -3e38f, -3e38f};
#pragma unroll
    for (int c = 0; c < 16; ++c) {
        const int col = cbase + c * 16 + fr;
#pragma unroll
        for (int r = 0; r < 4; ++r) {
            const int row = r0 + fq * 4 + r;
            float v = (mask[(size_t)row * 1024 + col] == 0) ? -1e9f
                                                            : accs[c][r] * scale;
            accs[c][r] = v;
            mxr[r] = fmaxf(mxr[r], v);
        }
    }
#pragma unroll
    for (int o = 1; o < 16; o <<= 1)
#pragma unroll
        for (int r = 0; r < 4; ++r) mxr[r] = fmaxf(mxr[r], __shfl_xor(mxr[r], o));
    if (fr == 0)
#pragma unroll
        for (int r = 0; r < 4; ++r) wred[fq * 4 + r][w] = mxr[r];
    __syncthreads();

    float mx[4], sm[4] = {0.f, 0.f, 0.f, 0.f};
#pragma unroll
    for (int r = 0; r < 4; ++r) {
        const int row = fq * 4 + r;
        mx[r] = fmaxf(fmaxf(wred[row][0], wred[row][1]),
                      fmaxf(wred[row][2], wred[row][3]));
    }
#pragma unroll
    for (int c = 0; c < 16; ++c)
#pragma unroll
        for (int r = 0; r < 4; ++r) {
            float e = __expf(accs[c][r] - mx[r]);
            accs[c][r] = e;
            sm[r] += e;
        }
#pragma unroll
    for (int o = 1; o < 16; o <<= 1)
#pragma unroll
        for (int r = 0; r < 4; ++r) sm[r] += __shfl_xor(sm[r], o);
    if (fr == 0)
#pragma unroll
        for (int r = 0; r < 4; ++r) wsum[fq * 4 + r][w] = sm[r];
    __syncthreads();

    float inv[4];
#pragma unroll
    for (int r = 0; r < 4; ++r) {
        const int row = fq * 4 + r;
        inv[r] = 32.0f / (wsum[row][0] + wsum[row][1] + wsum[row][2] + wsum[row][3]);
    }
#pragma unroll
    for (int c = 0; c < 16; ++c) {
        const int col = cbase + c * 16 + fr;
#pragma unroll
        for (int r = 0; r < 4; ++r) {
            const int row = r0 + fq * 4 + r;
            aw8[(size_t)row * 8192 + h * 1024 + col] = f2e4m3(accs[c][r] * inv[r]);
        }
    }
}

// ---------------------------------------------------------------------------
// LayerNorm over 256 cols, fp32 in -> bf16/fp32 out per flag. 4 rows/block.
// ---------------------------------------------------------------------------
__global__ __launch_bounds__(256) void ln_rows(
    const float* __restrict__ X, const bf16* __restrict__ g,
    const bf16* __restrict__ b, void* __restrict__ out, size_t row0, int rows,
    const int* __restrict__ flag)
{
    const bool f32 = (*flag != 0);
    const int lane = threadIdx.x & 63;
    const int wv   = threadIdx.x >> 6;
    const int row  = blockIdx.x * 4 + wv;
    if (row >= rows) return;
    const float* x = X + (size_t)row * 256;
    float v[4], s = 0.f, s2 = 0.f;
#pragma unroll
    for (int i = 0; i < 4; ++i) {
        v[i] = x[lane + 64 * i];
        s += v[i]; s2 += v[i] * v[i];
    }
#pragma unroll
    for (int o = 1; o < 64; o <<= 1) { s += __shfl_xor(s, o); s2 += __shfl_xor(s2, o); }
    const float mu  = s * (1.0f / 256.0f);
    const float var = fmaxf(s2 * (1.0f / 256.0f) - mu * mu, 0.0f);
    const float inv = rsqrtf(var + 1e-5f);
#pragma unroll
    for (int i = 0; i < 4; ++i) {
        const int c = lane + 64 * i;
        const float y = (v[i] - mu) * inv * __bfloat162float(g[c]) + __bfloat162float(b[c]);
        if (f32) ((float*)out)[(row0 + row) * 256 + c] = y;
        else     ((bf16*)out)[(row0 + row) * 256 + c] = __float2bfloat16(y);
    }
}

// ---------------------------------------------------------------------------
extern "C" void kernel_launch(void* const* d_in, const int* in_sizes, int n_in,
                              void* d_out, int out_size, void* d_ws, size_t ws_size,
                              hipStream_t stream)
{
    const int L = 4096, Mm = 1024, P = 4096;

    const int* mask_l = (const int*)d_in[3];
    const int* mask_p = (const int*)d_in[4];

    char* ws = (char*)d_ws;
    size_t off = 0;
    auto alloc = [&](size_t bytes) {
        void* p = ws + off; off += (bytes + 255) & ~(size_t)255; return p;
    };

    int*  flag   = (int*)alloc(256);
    // weight slots: 0:Wl 1:Wm 2:Wp 3:Wql 4:Wqp 5:Wkl 6:Wvl 7:Wkp 8:Wvp
    bf16* wt_all = (bf16*)alloc((size_t)9 * 512 * 512 * 2);
    bf16* WmlT   = (bf16*)alloc(1024 * 256 * 2);
    bf16* WmpT   = (bf16*)alloc(1024 * 256 * 2);
    bf16* b_l    = (bf16*)alloc(512 * 2);
    bf16* b_m    = (bf16*)alloc(512 * 2);
    bf16* b_p    = (bf16*)alloc(512 * 2);
    bf16* b_ql   = (bf16*)alloc(512 * 2);
    bf16* b_qp   = (bf16*)alloc(512 * 2);
    bf16* bcat   = (bf16*)alloc(2048 * 2);     // [bkl|bvl|bkp|bvp]
    bf16* bml_c  = (bf16*)alloc(256 * 2);
    bf16* bmp_c  = (bf16*)alloc(256 * 2);
    bf16* g1c    = (bf16*)alloc(256 * 2);
    bf16* be1c   = (bf16*)alloc(256 * 2);
    bf16* g2c    = (bf16*)alloc(256 * 2);
    bf16* be2c   = (bf16*)alloc(256 * 2);
    bf16* embl   = (bf16*)alloc((size_t)L * 512 * 2);
    bf16* embm   = (bf16*)alloc((size_t)Mm * 512 * 2);
    bf16* embp   = (bf16*)alloc((size_t)P * 512 * 2);
    bf16* cat_l  = (bf16*)alloc((size_t)L * 1024 * 2);   // [lt | fin_l]
    bf16* cat_p  = (bf16*)alloc((size_t)P * 1024 * 2);   // [fin_p | pt]
    bf16* mt     = (bf16*)alloc((size_t)Mm * 512 * 2);
    bf16* Ql     = (bf16*)alloc((size_t)L * 512 * 2);
    bf16* Qp     = (bf16*)alloc((size_t)P * 512 * 2);
    bf16* kvcat  = (bf16*)alloc((size_t)Mm * 2048 * 2);  // [Kl|Vl|Kp|Vp]
    unsigned char* V8lT = (unsigned char*)alloc((size_t)512 * Mm);
    unsigned char* V8pT = (unsigned char*)alloc((size_t)512 * Mm);
    bf16* ctx_l  = (bf16*)alloc((size_t)L * 512 * 2);
    bf16* ctx_p  = (bf16*)alloc((size_t)P * 512 * 2);
    bf16* ctxlT  = (bf16*)alloc((size_t)512 * L * 2);
    bf16* ctxpT  = (bf16*)alloc((size_t)512 * P * 2);
    bf16* mutual = (bf16*)alloc((size_t)L * P * 2);
    unsigned char* awl8 = (unsigned char*)alloc((size_t)L * 8192);
    unsigned char* awp8 = (unsigned char*)alloc((size_t)P * 8192);
    // overlays: awl8/awp8 dead after the mutual GEMM
    bf16*  mutualT = (bf16*)awl8;
    float* tmp1    = (float*)awp8;
    float* tmp2    = (float*)awp8 + (size_t)L * 256;

    // 0. dtype sniff + canonicalize
    sniff_dtype<<<1, 64, 0, stream>>>((const unsigned short*)d_in[0], flag);

    CvtTable tab;
    tab.e[0]  = { d_in[0],  embl, L * 512 };
    tab.e[1]  = { d_in[1],  embm, Mm * 512 };
    tab.e[2]  = { d_in[2],  embp, P * 512 };
    tab.e[3]  = { d_in[6],  b_l,  512 };
    tab.e[4]  = { d_in[8],  b_m,  512 };
    tab.e[5]  = { d_in[10], b_p,  512 };
    tab.e[6]  = { d_in[12], b_ql, 512 };
    tab.e[7]  = { d_in[18], b_qp, 512 };
    tab.e[8]  = { d_in[14], bcat,        512 };   // bkl
    tab.e[9]  = { d_in[16], bcat + 512,  512 };   // bvl
    tab.e[10] = { d_in[20], bcat + 1024, 512 };   // bkp
    tab.e[11] = { d_in[22], bcat + 1536, 512 };   // bvp
    tab.e[12] = { d_in[24], bml_c, 256 };
    tab.e[13] = { d_in[26], bmp_c, 256 };
    tab.e[14] = { d_in[27], g1c,  256 };
    tab.e[15] = { d_in[28], be1c, 256 };
    tab.e[16] = { d_in[29], g2c,  256 };
    tab.e[17] = { d_in[30], be2c, 256 };
    convert_inputs<<<dim3(256, 18), 256, 0, stream>>>(tab, flag);

    // 1. weight transposes
    TT9 tt;
    const int slot_of[9] = {0, 1, 2, 3, 5, 6, 4, 7, 8};  // input order -> slot
    for (int i = 0; i < 9; ++i) {
        tt.src[i] = d_in[5 + 2 * i];
        tt.dst[i] = wt_all + (size_t)slot_of[i] * 512 * 512;
    }
    transpose_sq9<<<dim3(16, 16, 9), 256, 0, stream>>>(tt, flag);
    transpose_any_ld<<<dim3(8, 32), 256, 0, stream>>>(d_in[23], 256, WmlT, 1024, 256, flag);
    transpose_any_ld<<<dim3(8, 32), 256, 0, stream>>>(d_in[25], 256, WmpT, 1024, 256, flag);

    bf16* WlT  = wt_all;
    bf16* WmT  = wt_all + (size_t)1 * 512 * 512;
    bf16* WpT  = wt_all + (size_t)2 * 512 * 512;
    bf16* WqlT = wt_all + (size_t)3 * 512 * 512;
    bf16* WqpT = wt_all + (size_t)4 * 512 * 512;
    bf16* WkvT = wt_all + (size_t)5 * 512 * 512;  // [2048, 512]

    // 2. input projections
    gemm_bt<64, true, false, false, false><<<dim3(8, 32), 256, 0, stream>>>(
        embl, 512, WlT, 512, cat_l, 1024, nullptr, 0, b_l, 512, 1.0f);
    gemm_bt<64, true, false, false, false><<<dim3(8, 8), 256, 0, stream>>>(
        embm, 512, WmT, 512, mt, 512, nullptr, 0, b_m, 512, 1.0f);
    gemm_bt<64, true, false, false, false><<<dim3(8, 32), 256, 0, stream>>>(
        embp, 512, WpT, 512, cat_p + 512, 1024, nullptr, 0, b_p, 512, 1.0f);

    // 3. Q projections + fused K/V projection  kvcat = mt @ [Wkl|Wvl|Wkp|Wvp]
    gemm_bt<64, true, false, false, false><<<dim3(8, 32), 256, 0, stream>>>(
        cat_l, 1024, WqlT, 512, Ql, 512, nullptr, 0, b_ql, 512, 1.0f);
    gemm_bt<64, true, false, false, false><<<dim3(8, 32), 256, 0, stream>>>(
        cat_p + 512, 1024, WqpT, 512, Qp, 512, nullptr, 0, b_qp, 512, 1.0f);
    gemm_bt<64, true, false, false, false><<<dim3(32, 8), 256, 0, stream>>>(
        mt, 512, WkvT, 512, kvcat, 2048, nullptr, 0, bcat, 512, 1.0f);

    // V8T = e4m3(V^T * 4)
    transpose_q8<<<dim3(16, 32), 256, 0, stream>>>(kvcat + 512,  2048, V8lT, 1024, 512, 4.0f);
    transpose_q8<<<dim3(16, 32), 256, 0, stream>>>(kvcat + 1536, 2048, V8pT, 1024, 512, 4.0f);

    // 4. fused MFMA scores + mask + softmax -> aw8 (= softmax * 32 in e4m3)
    scores_mfma<<<dim3(256, 8), 256, 0, stream>>>(Ql, kvcat,        2048, mask_l, awl8, 0.125f);
    scores_mfma<<<dim3(256, 8), 256, 0, stream>>>(Qp, kvcat + 1024, 2048, mask_p, awp8, 0.125f);

    // 5. ctx = relu(aw @ V) per head (fp8), scale 1/(32*4)
    gemm_bt8<64, true><<<dim3(8, 32), 256, 0, stream>>>(
        awl8, 8192, 1024, V8lT, 1024, ctx_l, 512, 1024, 1.0f / 128.0f);
    gemm_bt8<64, true><<<dim3(8, 32), 256, 0, stream>>>(
        awp8, 8192, 1024, V8pT, 1024, ctx_p, 512, 1024, 1.0f / 128.0f);

    transpose_bf16_ld<<<dim3(16, 128), 256, 0, stream>>>(ctx_l, 512, ctxlT, 4096, 512);
    transpose_bf16_ld<<<dim3(16, 128), 256, 0, stream>>>(ctx_p, 512, ctxpT, 4096, 512);

    // 6. mutual = (awl @ awp^T) / 8  (fp8, scale 1/(32*32*8))
    gemm_bt8<128, false><<<dim3(32, 32), 256, 0, stream>>>(
        awl8, 8192, 0, awp8, 8192, mutual, 4096, 8192, 0.125f / 1024.0f);
    // awl8/awp8 dead: overlays live
    transpose_bf16_ld<<<dim3(128, 128), 256, 0, stream>>>(mutual, 4096, mutualT, 4096, 4096);

    // 7. fin_l -> cat_l[:,512:]; fin_p -> cat_p[:,:512]
    gemm_bt<64, false, true, false, false><<<dim3(8, 32), 256, 0, stream>>>(
        mutual, 4096, ctxpT, 4096, cat_l + 512, 1024, ctx_l, 512, nullptr, 4096, 1.0f);
    gemm_bt<64, false, true, false, false><<<dim3(8, 32), 256, 0, stream>>>(
        mutualT, 4096, ctxlT, 4096, cat_p, 1024, ctx_p, 512, nullptr, 4096, 1.0f);

    // 8. final projections (fp32) + LayerNorm -> d_out
    gemm_bt<64, true, false, false, true><<<dim3(4, 32), 256, 0, stream>>>(
        cat_l, 1024, WmlT, 1024, tmp1, 256, nullptr, 0, bml_c, 1024, 1.0f);
    gemm_bt<64, true, false, false, true><<<dim3(4, 32), 256, 0, stream>>>(
        cat_p, 1024, WmpT, 1024, tmp2, 256, nullptr, 0, bmp_c, 1024, 1.0f);

    ln_rows<<<dim3(1024), 256, 0, stream>>>(tmp1, g1c, be1c, d_out, 0, L, flag);
    ln_rows<<<dim3(1024), 256, 0, stream>>>(tmp2, g2c, be2c, d_out, (size_t)L, P, flag);
}

// Round 4
// 933.142 us; speedup vs baseline: 1.4920x; 1.1906x over previous
//
#include <hip/hip_runtime.h>
#include <hip/hip_bf16.h>

using bf16 = __hip_bfloat16;
typedef __attribute__((ext_vector_type(8))) short short8;
typedef __attribute__((ext_vector_type(4))) float floatx4;
typedef __attribute__((ext_vector_type(8))) unsigned short ushort8;

__device__ __forceinline__ float b2f(unsigned short u) {
    union { unsigned int i; float f; } x; x.i = ((unsigned int)u) << 16; return x.f;
}

__device__ __forceinline__ void async16(const void* g, void* l) {
    __builtin_amdgcn_global_load_lds((const __attribute__((address_space(1))) void*)g,
                                     (__attribute__((address_space(3))) void*)l,
                                     16, 0, 0);
}

// float -> OCP e4m3fn, RNE, signed, |f| clamped to 448.
__device__ __forceinline__ unsigned char f2e4m3(float f) {
    unsigned s = (__float_as_uint(f) >> 24) & 0x80u;
    f = fminf(fabsf(f), 448.f);
    if (f < 0.015625f) {                       // denormal target: ulp 2^-9
        int d = (int)rintf(f * 512.f);         // 0..8 (8 -> min normal 2^-6)
        return (unsigned char)(s | (unsigned)d);
    }
    int E = (int)((__float_as_uint(f) >> 23) & 255u) - 127;
    float ulp_inv = __uint_as_float((unsigned)(127 + 3 - E) << 23); // 2^(3-E)
    int m = (int)rintf(f * ulp_inv);           // 8..16
    int n = (m == 16) ? ((E + 8) << 3) : (((E + 7) << 3) + (m - 8));
    if (n > 0x7E) n = 0x7E;
    return (unsigned char)(s | (unsigned)n);
}

// ---------------------------------------------------------------------------
// Dtype sniffer: fp32 data read as bf16 decodes ~44% wild exponents.
// ---------------------------------------------------------------------------
__global__ void sniff_dtype(const unsigned short* p, int* flag) {
    int wild = 0;
    for (int i = threadIdx.x; i < 256; i += 64) {
        float a = fabsf(b2f(p[i]));
        if (!(a <= 1e4f)) wild++;
    }
#pragma unroll
    for (int o = 1; o < 64; o <<= 1) wild += __shfl_xor(wild, o);
    if (threadIdx.x == 0) *flag = (wild > 16) ? 1 : 0;
}

// ---------------------------------------------------------------------------
// Convert float inputs (fp32 or bf16 per flag) to canonical bf16 mirrors.
// ---------------------------------------------------------------------------
struct Cvt { const void* src; bf16* dst; int n; };
struct CvtTable { Cvt e[18]; };

__global__ __launch_bounds__(256) void convert_inputs(CvtTable t, const int* flag) {
    const Cvt c = t.e[blockIdx.y];
    const bool f32 = (*flag != 0);
    const int stride = gridDim.x * 256 * 8;
    for (int i = (blockIdx.x * 256 + threadIdx.x) * 8; i < c.n; i += stride) {
        if (f32) {
            const float* s = (const float*)c.src + i;
#pragma unroll
            for (int j = 0; j < 8; ++j) c.dst[i + j] = __float2bfloat16(s[j]);
        } else {
            *(ushort8*)((unsigned short*)c.dst + i) =
                *(const ushort8*)((const unsigned short*)c.src + i);
        }
    }
}

// ---------------------------------------------------------------------------
// Batched 512x512 dtype-aware transpose for the 9 square weights.
// ---------------------------------------------------------------------------
struct TT9 { const void* src[9]; bf16* dst[9]; };

__global__ __launch_bounds__(256) void transpose_sq9(TT9 t, const int* flag) {
    __shared__ bf16 tile[32][33];
    const void* in = t.src[blockIdx.z];
    bf16* out = t.dst[blockIdx.z];
    const bool f32 = (*flag != 0);
    const int tx = threadIdx.x & 31;
    const int ty = threadIdx.x >> 5;
    const int bc = blockIdx.x * 32;
    const int br = blockIdx.y * 32;
#pragma unroll
    for (int i = 0; i < 32; i += 8) {
        const size_t idx = (size_t)(br + ty + i) * 512 + bc + tx;
        tile[ty + i][tx] = f32 ? __float2bfloat16(((const float*)in)[idx])
                               : ((const bf16*)in)[idx];
    }
    __syncthreads();
#pragma unroll
    for (int i = 0; i < 32; i += 8)
        out[(size_t)(bc + ty + i) * 512 + br + tx] = tile[tx][ty + i];
}

// ---------------------------------------------------------------------------
// Dtype-aware rectangular transpose (for Wml/Wmp). out[C,R] = in[R,C]^T.
// ---------------------------------------------------------------------------
__global__ __launch_bounds__(256) void transpose_any_ld(
    const void* __restrict__ in, int ils, bf16* __restrict__ out,
    int R, int C, const int* __restrict__ flag)
{
    __shared__ bf16 tile[32][33];
    const bool f32 = (*flag != 0);
    const int tx = threadIdx.x & 31;
    const int ty = threadIdx.x >> 5;
    const int bc = blockIdx.x * 32;
    const int br = blockIdx.y * 32;
#pragma unroll
    for (int i = 0; i < 32; i += 8) {
        const size_t idx = (size_t)(br + ty + i) * ils + bc + tx;
        tile[ty + i][tx] = f32 ? __float2bfloat16(((const float*)in)[idx])
                               : ((const bf16*)in)[idx];
    }
    __syncthreads();
#pragma unroll
    for (int i = 0; i < 32; i += 8)
        out[(size_t)(bc + ty + i) * R + br + tx] = tile[tx][ty + i];
}

// ---------------------------------------------------------------------------
// bf16 transpose with input ld (internal buffers). out[C,R] = in[R,C]^T.
// ---------------------------------------------------------------------------
__global__ __launch_bounds__(256) void transpose_bf16_ld(
    const bf16* __restrict__ in, int ils, bf16* __restrict__ out, int R, int C)
{
    __shared__ bf16 tile[32][33];
    const int tx = threadIdx.x & 31;
    const int ty = threadIdx.x >> 5;
    const int bc = blockIdx.x * 32;
    const int br = blockIdx.y * 32;
#pragma unroll
    for (int i = 0; i < 32; i += 8)
        tile[ty + i][tx] = in[(size_t)(br + ty + i) * ils + bc + tx];
    __syncthreads();
#pragma unroll
    for (int i = 0; i < 32; i += 8)
        out[(size_t)(bc + ty + i) * R + br + tx] = tile[tx][ty + i];
}

// ---------------------------------------------------------------------------
// Quantizing transpose: out[C,R] = e4m3(in[R,C]^T * vs).  (for V -> V8T)
// ---------------------------------------------------------------------------
__global__ __launch_bounds__(256) void transpose_q8(
    const bf16* __restrict__ in, int ils, unsigned char* __restrict__ out,
    int R, int C, float vs)
{
    __shared__ float tile[32][33];
    const int tx = threadIdx.x & 31;
    const int ty = threadIdx.x >> 5;
    const int bc = blockIdx.x * 32;
    const int br = blockIdx.y * 32;
#pragma unroll
    for (int i = 0; i < 32; i += 8)
        tile[ty + i][tx] =
            __bfloat162float(in[(size_t)(br + ty + i) * ils + bc + tx]) * vs;
    __syncthreads();
#pragma unroll
    for (int i = 0; i < 32; i += 8)
        out[(size_t)(bc + ty + i) * R + br + tx] = f2e4m3(tile[tx][ty + i]);
}

// ---------------------------------------------------------------------------
// Generic bf16 C = A * B^T GEMM (m97 structure). A:[M,K] lda, B:[N,K] ldb.
// ---------------------------------------------------------------------------
template <int BN, bool BIAS, bool ADDC0, bool RELU, bool F32OUT>
__global__ __launch_bounds__(256) void gemm_bt(
    const bf16* __restrict__ A, int lda,
    const bf16* __restrict__ B, int ldb,
    void* __restrict__ Cout, int ldc,
    const bf16* __restrict__ C0, int ldc0,
    const bf16* __restrict__ bias,
    int K, float scale)
{
    constexpr int BM = 128;
    constexpr int WN = BN / 2;
    constexpr int TM = 4;
    constexpr int TN = WN / 16;

    __align__(16) __shared__ bf16 As[BM * 32];
    __align__(16) __shared__ bf16 Bs[BN * 32];

    const int tid  = threadIdx.x;
    const int lane = tid & 63;
    const int wv   = tid >> 6;
    const int m_base = blockIdx.y * BM;
    const int n_base = blockIdx.x * BN;

    const int wm0 = (wv >> 1) * 64;
    const int wn0 = (wv & 1) * WN;

    floatx4 zero = {0.f, 0.f, 0.f, 0.f};
    floatx4 acc[TM][TN];
#pragma unroll
    for (int mt = 0; mt < TM; ++mt)
#pragma unroll
        for (int nt = 0; nt < TN; ++nt) acc[mt][nt] = zero;

    const int ar = lane >> 2;
    const int ac = (lane & 3) * 8;
    const int fr = lane & 15;
    const int fk = (lane >> 4) * 8;

    for (int k0 = 0; k0 < K; k0 += 32) {
#pragma unroll
        for (int cc = 0; cc < BM / 64; ++cc) {
            const int r0t = (wv + cc * 4) * 16;
            async16(A + (size_t)(m_base + r0t + ar) * lda + k0 + ac, &As[r0t * 32]);
        }
#pragma unroll
        for (int cc = 0; cc < BN / 64; ++cc) {
            const int r0t = (wv + cc * 4) * 16;
            async16(B + (size_t)(n_base + r0t + ar) * ldb + k0 + ac, &Bs[r0t * 32]);
        }
        __syncthreads();

        short8 af[TM], bfrag[TN];
#pragma unroll
        for (int mt = 0; mt < TM; ++mt)
            af[mt] = *(const short8*)&As[(wm0 + mt * 16 + fr) * 32 + fk];
#pragma unroll
        for (int nt = 0; nt < TN; ++nt)
            bfrag[nt] = *(const short8*)&Bs[(wn0 + nt * 16 + fr) * 32 + fk];
#pragma unroll
        for (int mt = 0; mt < TM; ++mt)
#pragma unroll
            for (int nt = 0; nt < TN; ++nt)
                acc[mt][nt] = __builtin_amdgcn_mfma_f32_16x16x32_bf16(
                    af[mt], bfrag[nt], acc[mt][nt], 0, 0, 0);
        __syncthreads();
    }

    const int er = lane >> 4;
    const int ec = lane & 15;
#pragma unroll
    for (int nt = 0; nt < TN; ++nt) {
        const int col = n_base + wn0 + nt * 16 + ec;
        float bv = 0.f;
        if constexpr (BIAS) bv = __bfloat162float(bias[col]);
#pragma unroll
        for (int mt = 0; mt < TM; ++mt) {
#pragma unroll
            for (int r = 0; r < 4; ++r) {
                const int row = m_base + wm0 + mt * 16 + er * 4 + r;
                float v = acc[mt][nt][r] * scale + bv;
                if constexpr (ADDC0) v += __bfloat162float(C0[(size_t)row * ldc0 + col]);
                if constexpr (RELU) v = fmaxf(v, 0.f);
                if constexpr (F32OUT)
                    ((float*)Cout)[(size_t)row * ldc + col] = v;
                else
                    ((bf16*)Cout)[(size_t)row * ldc + col] = __float2bfloat16(v);
            }
        }
    }
}

// ---------------------------------------------------------------------------
// fp8 C = A * B^T GEMM, BK=64, mfma_f32_16x16x32_fp8_fp8, 32 MFMA/barrier.
// XOR-swizzled LDS: chunk (row, cb) lives at slot row*4 + (cb ^ (row&3)).
// Staging lane loads global col ((lane&3)^(ar&3))*16 so DMA (base+lane*16)
// lands data at its swizzled slot; fragment reads XOR with fr&3. This puts
// the ds_read_b64 at the 4-dword/bank structural floor (was 8-way conflict).
// a_kshift: per-n-block byte shift of A (per-head ctx GEMM).
// ---------------------------------------------------------------------------
template <int BN, bool RELU>
__global__ __launch_bounds__(256) void gemm_bt8(
    const unsigned char* __restrict__ A, int lda, long long a_kshift,
    const unsigned char* __restrict__ B, int ldb,
    bf16* __restrict__ C, int ldc,
    int K, float scale)
{
    constexpr int BM = 128;
    constexpr int WN = BN / 2;
    constexpr int TM = 4;
    constexpr int TN = WN / 16;

    __align__(16) __shared__ unsigned char As[BM * 64];
    __align__(16) __shared__ unsigned char Bs[BN * 64];

    const int tid  = threadIdx.x;
    const int lane = tid & 63;
    const int wv   = tid >> 6;
    const int m_base = blockIdx.y * BM;
    const int n_base = blockIdx.x * BN;
    A += (long long)blockIdx.x * a_kshift;

    const int wm0 = (wv >> 1) * 64;
    const int wn0 = (wv & 1) * WN;

    floatx4 zero = {0.f, 0.f, 0.f, 0.f};
    floatx4 acc[TM][TN];
#pragma unroll
    for (int mt = 0; mt < TM; ++mt)
#pragma unroll
        for (int nt = 0; nt < TN; ++nt) acc[mt][nt] = zero;

    const int ar = lane >> 2;                          // 16 rows / staging instr
    const int ac = (((lane & 3) ^ (ar & 3)) * 16);     // swizzled 16B chunk
    const int fr = lane & 15;
    const int q  = lane >> 4;
    const int sw = fr & 3;                             // row&3 of fragment row

    for (int k0 = 0; k0 < K; k0 += 64) {
#pragma unroll
        for (int cc = 0; cc < BM / 16; cc += 4) {
            const int r0t = (wv + cc) * 16;
            async16(A + (size_t)(m_base + r0t + ar) * lda + k0 + ac, &As[r0t * 64]);
        }
#pragma unroll
        for (int cc = 0; cc < BN / 16; cc += 4) {
            const int r0t = (wv + cc) * 16;
            async16(B + (size_t)(n_base + r0t + ar) * ldb + k0 + ac, &Bs[r0t * 64]);
        }
        __syncthreads();

#pragma unroll
        for (int s = 0; s < 2; ++s) {
            // chunk cb = s*2 + (q>>1), swizzled by fr&3; low 8B select q&1
            const int boff = (((s * 2 + (q >> 1)) ^ sw) * 16) + (q & 1) * 8;
            long af[TM], bfr[TN];
#pragma unroll
            for (int mt = 0; mt < TM; ++mt)
                af[mt] = *(const long*)&As[(wm0 + mt * 16 + fr) * 64 + boff];
#pragma unroll
            for (int nt = 0; nt < TN; ++nt)
                bfr[nt] = *(const long*)&Bs[(wn0 + nt * 16 + fr) * 64 + boff];
#pragma unroll
            for (int mt = 0; mt < TM; ++mt)
#pragma unroll
                for (int nt = 0; nt < TN; ++nt)
                    acc[mt][nt] = __builtin_amdgcn_mfma_f32_16x16x32_fp8_fp8(
                        af[mt], bfr[nt], acc[mt][nt], 0, 0, 0);
        }
        __syncthreads();
    }

    const int er = lane >> 4;
    const int ec = lane & 15;
#pragma unroll
    for (int nt = 0; nt < TN; ++nt) {
        const int col = n_base + wn0 + nt * 16 + ec;
#pragma unroll
        for (int mt = 0; mt < TM; ++mt) {
#pragma unroll
            for (int r = 0; r < 4; ++r) {
                const int row = m_base + wm0 + mt * 16 + er * 4 + r;
                float v = acc[mt][nt][r] * scale;
                if constexpr (RELU) v = fmaxf(v, 0.f);
                C[(size_t)row * ldc + col] = __float2bfloat16(v);
            }
        }
    }
}

// ---------------------------------------------------------------------------
// MFMA fused scores + mask + softmax. Block = 16 Q-rows x 1024 cols, 1 head.
// Wave w covers cols [256w, 256w+256); scores stay in C-layout registers.
// Output: aw8 = e4m3(softmax * 32) at [row, h*1024 + col].
// ---------------------------------------------------------------------------
__global__ __launch_bounds__(256) void scores_mfma(
    const bf16* __restrict__ Q,          // [Nq, 512]
    const bf16* __restrict__ Kbase,      // [1024, ldk] (head cols at h*64)
    int ldk,
    const int* __restrict__ mask,        // [Nq, 1024]
    unsigned char* __restrict__ aw8,     // [Nq, 8192]
    float scale)
{
    __shared__ float wred[16][4];
    __shared__ float wsum[16][4];

    const int t    = threadIdx.x;
    const int lane = t & 63;
    const int w    = t >> 6;
    const int h    = blockIdx.y;
    const int r0   = blockIdx.x * 16;
    const int fr   = lane & 15;
    const int fq   = lane >> 4;
    const int cbase = w * 256;

    const short* Qs = (const short*)Q + (size_t)(r0 + fr) * 512 + h * 64 + fq * 8;
    short8 a0 = *(const short8*)(Qs);
    short8 a1 = *(const short8*)(Qs + 32);

    floatx4 accs[16];
    const short* Kb = (const short*)Kbase + h * 64 + fq * 8;
#pragma unroll
    for (int c = 0; c < 16; ++c) {
        const int krow = cbase + c * 16 + fr;
        short8 b0 = *(const short8*)(Kb + (size_t)krow * ldk);
        short8 b1 = *(const short8*)(Kb + (size_t)krow * ldk + 32);
        floatx4 acc = {0.f, 0.f, 0.f, 0.f};
        acc = __builtin_amdgcn_mfma_f32_16x16x32_bf16(a0, b0, acc, 0, 0, 0);
        acc = __builtin_amdgcn_mfma_f32_16x16x32_bf16(a1, b1, acc, 0, 0, 0);
        accs[c] = acc;
    }

    float mxr[4] = {-3e38f, -3e38f, -3e38f, -3e38f};
#pragma unroll
    for (int c = 0; c < 16; ++c) {
        const int col = cbase + c * 16 + fr;
#pragma unroll
        for (int r = 0; r < 4; ++r) {
            const int row = r0 + fq * 4 + r;
            float v = (mask[(size_t)row * 1024 + col] == 0) ? -1e9f
                                                            : accs[c][r] * scale;
            accs[c][r] = v;
            mxr[r] = fmaxf(mxr[r], v);
        }
    }
#pragma unroll
    for (int o = 1; o < 16; o <<= 1)
#pragma unroll
        for (int r = 0; r < 4; ++r) mxr[r] = fmaxf(mxr[r], __shfl_xor(mxr[r], o));
    if (fr == 0)
#pragma unroll
        for (int r = 0; r < 4; ++r) wred[fq * 4 + r][w] = mxr[r];
    __syncthreads();

    float mx[4], sm[4] = {0.f, 0.f, 0.f, 0.f};
#pragma unroll
    for (int r = 0; r < 4; ++r) {
        const int row = fq * 4 + r;
        mx[r] = fmaxf(fmaxf(wred[row][0], wred[row][1]),
                      fmaxf(wred[row][2], wred[row][3]));
    }
#pragma unroll
    for (int c = 0; c < 16; ++c)
#pragma unroll
        for (int r = 0; r < 4; ++r) {
            float e = __expf(accs[c][r] - mx[r]);
            accs[c][r] = e;
            sm[r] += e;
        }
#pragma unroll
    for (int o = 1; o < 16; o <<= 1)
#pragma unroll
        for (int r = 0; r < 4; ++r) sm[r] += __shfl_xor(sm[r], o);
    if (fr == 0)
#pragma unroll
        for (int r = 0; r < 4; ++r) wsum[fq * 4 + r][w] = sm[r];
    __syncthreads();

    float inv[4];
#pragma unroll
    for (int r = 0; r < 4; ++r) {
        const int row = fq * 4 + r;
        inv[r] = 32.0f / (wsum[row][0] + wsum[row][1] + wsum[row][2] + wsum[row][3]);
    }
#pragma unroll
    for (int c = 0; c < 16; ++c) {
        const int col = cbase + c * 16 + fr;
#pragma unroll
        for (int r = 0; r < 4; ++r) {
            const int row = r0 + fq * 4 + r;
            aw8[(size_t)row * 8192 + h * 1024 + col] = f2e4m3(accs[c][r] * inv[r]);
        }
    }
}

// ---------------------------------------------------------------------------
// LayerNorm over 256 cols, fp32 in -> bf16/fp32 out per flag. 4 rows/block.
// ---------------------------------------------------------------------------
__global__ __launch_bounds__(256) void ln_rows(
    const float* __restrict__ X, const bf16* __restrict__ g,
    const bf16* __restrict__ b, void* __restrict__ out, size_t row0, int rows,
    const int* __restrict__ flag)
{
    const bool f32 = (*flag != 0);
    const int lane = threadIdx.x & 63;
    const int wv   = threadIdx.x >> 6;
    const int row  = blockIdx.x * 4 + wv;
    if (row >= rows) return;
    const float* x = X + (size_t)row * 256;
    float v[4], s = 0.f, s2 = 0.f;
#pragma unroll
    for (int i = 0; i < 4; ++i) {
        v[i] = x[lane + 64 * i];
        s += v[i]; s2 += v[i] * v[i];
    }
#pragma unroll
    for (int o = 1; o < 64; o <<= 1) { s += __shfl_xor(s, o); s2 += __shfl_xor(s2, o); }
    const float mu  = s * (1.0f / 256.0f);
    const float var = fmaxf(s2 * (1.0f / 256.0f) - mu * mu, 0.0f);
    const float inv = rsqrtf(var + 1e-5f);
#pragma unroll
    for (int i = 0; i < 4; ++i) {
        const int c = lane + 64 * i;
        const float y = (v[i] - mu) * inv * __bfloat162float(g[c]) + __bfloat162float(b[c]);
        if (f32) ((float*)out)[(row0 + row) * 256 + c] = y;
        else     ((bf16*)out)[(row0 + row) * 256 + c] = __float2bfloat16(y);
    }
}

// ---------------------------------------------------------------------------
extern "C" void kernel_launch(void* const* d_in, const int* in_sizes, int n_in,
                              void* d_out, int out_size, void* d_ws, size_t ws_size,
                              hipStream_t stream)
{
    const int L = 4096, Mm = 1024, P = 4096;

    const int* mask_l = (const int*)d_in[3];
    const int* mask_p = (const int*)d_in[4];

    char* ws = (char*)d_ws;
    size_t off = 0;
    auto alloc = [&](size_t bytes) {
        void* p = ws + off; off += (bytes + 255) & ~(size_t)255; return p;
    };

    int*  flag   = (int*)alloc(256);
    // weight slots: 0:Wl 1:Wm 2:Wp 3:Wql 4:Wqp 5:Wkl 6:Wvl 7:Wkp 8:Wvp
    bf16* wt_all = (bf16*)alloc((size_t)9 * 512 * 512 * 2);
    bf16* WmlT   = (bf16*)alloc(1024 * 256 * 2);
    bf16* WmpT   = (bf16*)alloc(1024 * 256 * 2);
    bf16* b_l    = (bf16*)alloc(512 * 2);
    bf16* b_m    = (bf16*)alloc(512 * 2);
    bf16* b_p    = (bf16*)alloc(512 * 2);
    bf16* b_ql   = (bf16*)alloc(512 * 2);
    bf16* b_qp   = (bf16*)alloc(512 * 2);
    bf16* bcat   = (bf16*)alloc(2048 * 2);     // [bkl|bvl|bkp|bvp]
    bf16* bml_c  = (bf16*)alloc(256 * 2);
    bf16* bmp_c  = (bf16*)alloc(256 * 2);
    bf16* g1c    = (bf16*)alloc(256 * 2);
    bf16* be1c   = (bf16*)alloc(256 * 2);
    bf16* g2c    = (bf16*)alloc(256 * 2);
    bf16* be2c   = (bf16*)alloc(256 * 2);
    bf16* embl   = (bf16*)alloc((size_t)L * 512 * 2);
    bf16* embm   = (bf16*)alloc((size_t)Mm * 512 * 2);
    bf16* embp   = (bf16*)alloc((size_t)P * 512 * 2);
    bf16* cat_l  = (bf16*)alloc((size_t)L * 1024 * 2);   // [lt | fin_l]
    bf16* cat_p  = (bf16*)alloc((size_t)P * 1024 * 2);   // [fin_p | pt]
    bf16* mt     = (bf16*)alloc((size_t)Mm * 512 * 2);
    bf16* Ql     = (bf16*)alloc((size_t)L * 512 * 2);
    bf16* Qp     = (bf16*)alloc((size_t)P * 512 * 2);
    bf16* kvcat  = (bf16*)alloc((size_t)Mm * 2048 * 2);  // [Kl|Vl|Kp|Vp]
    unsigned char* V8lT = (unsigned char*)alloc((size_t)512 * Mm);
    unsigned char* V8pT = (unsigned char*)alloc((size_t)512 * Mm);
    bf16* ctx_l  = (bf16*)alloc((size_t)L * 512 * 2);
    bf16* ctx_p  = (bf16*)alloc((size_t)P * 512 * 2);
    bf16* ctxlT  = (bf16*)alloc((size_t)512 * L * 2);
    bf16* ctxpT  = (bf16*)alloc((size_t)512 * P * 2);
    bf16* mutual = (bf16*)alloc((size_t)L * P * 2);
    unsigned char* awl8 = (unsigned char*)alloc((size_t)L * 8192);
    unsigned char* awp8 = (unsigned char*)alloc((size_t)P * 8192);
    // overlays: awl8/awp8 dead after the mutual GEMM
    bf16*  mutualT = (bf16*)awl8;
    float* tmp1    = (float*)awp8;
    float* tmp2    = (float*)awp8 + (size_t)L * 256;

    // 0. dtype sniff + canonicalize
    sniff_dtype<<<1, 64, 0, stream>>>((const unsigned short*)d_in[0], flag);

    CvtTable tab;
    tab.e[0]  = { d_in[0],  embl, L * 512 };
    tab.e[1]  = { d_in[1],  embm, Mm * 512 };
    tab.e[2]  = { d_in[2],  embp, P * 512 };
    tab.e[3]  = { d_in[6],  b_l,  512 };
    tab.e[4]  = { d_in[8],  b_m,  512 };
    tab.e[5]  = { d_in[10], b_p,  512 };
    tab.e[6]  = { d_in[12], b_ql, 512 };
    tab.e[7]  = { d_in[18], b_qp, 512 };
    tab.e[8]  = { d_in[14], bcat,        512 };   // bkl
    tab.e[9]  = { d_in[16], bcat + 512,  512 };   // bvl
    tab.e[10] = { d_in[20], bcat + 1024, 512 };   // bkp
    tab.e[11] = { d_in[22], bcat + 1536, 512 };   // bvp
    tab.e[12] = { d_in[24], bml_c, 256 };
    tab.e[13] = { d_in[26], bmp_c, 256 };
    tab.e[14] = { d_in[27], g1c,  256 };
    tab.e[15] = { d_in[28], be1c, 256 };
    tab.e[16] = { d_in[29], g2c,  256 };
    tab.e[17] = { d_in[30], be2c, 256 };
    convert_inputs<<<dim3(256, 18), 256, 0, stream>>>(tab, flag);

    // 1. weight transposes
    TT9 tt;
    const int slot_of[9] = {0, 1, 2, 3, 5, 6, 4, 7, 8};  // input order -> slot
    for (int i = 0; i < 9; ++i) {
        tt.src[i] = d_in[5 + 2 * i];
        tt.dst[i] = wt_all + (size_t)slot_of[i] * 512 * 512;
    }
    transpose_sq9<<<dim3(16, 16, 9), 256, 0, stream>>>(tt, flag);
    transpose_any_ld<<<dim3(8, 32), 256, 0, stream>>>(d_in[23], 256, WmlT, 1024, 256, flag);
    transpose_any_ld<<<dim3(8, 32), 256, 0, stream>>>(d_in[25], 256, WmpT, 1024, 256, flag);

    bf16* WlT  = wt_all;
    bf16* WmT  = wt_all + (size_t)1 * 512 * 512;
    bf16* WpT  = wt_all + (size_t)2 * 512 * 512;
    bf16* WqlT = wt_all + (size_t)3 * 512 * 512;
    bf16* WqpT = wt_all + (size_t)4 * 512 * 512;
    bf16* WkvT = wt_all + (size_t)5 * 512 * 512;  // [2048, 512]

    // 2. input projections
    gemm_bt<64, true, false, false, false><<<dim3(8, 32), 256, 0, stream>>>(
        embl, 512, WlT, 512, cat_l, 1024, nullptr, 0, b_l, 512, 1.0f);
    gemm_bt<64, true, false, false, false><<<dim3(8, 8), 256, 0, stream>>>(
        embm, 512, WmT, 512, mt, 512, nullptr, 0, b_m, 512, 1.0f);
    gemm_bt<64, true, false, false, false><<<dim3(8, 32), 256, 0, stream>>>(
        embp, 512, WpT, 512, cat_p + 512, 1024, nullptr, 0, b_p, 512, 1.0f);

    // 3. Q projections + fused K/V projection  kvcat = mt @ [Wkl|Wvl|Wkp|Wvp]
    gemm_bt<64, true, false, false, false><<<dim3(8, 32), 256, 0, stream>>>(
        cat_l, 1024, WqlT, 512, Ql, 512, nullptr, 0, b_ql, 512, 1.0f);
    gemm_bt<64, true, false, false, false><<<dim3(8, 32), 256, 0, stream>>>(
        cat_p + 512, 1024, WqpT, 512, Qp, 512, nullptr, 0, b_qp, 512, 1.0f);
    gemm_bt<64, true, false, false, false><<<dim3(32, 8), 256, 0, stream>>>(
        mt, 512, WkvT, 512, kvcat, 2048, nullptr, 0, bcat, 512, 1.0f);

    // V8T = e4m3(V^T * 4)
    transpose_q8<<<dim3(16, 32), 256, 0, stream>>>(kvcat + 512,  2048, V8lT, 1024, 512, 4.0f);
    transpose_q8<<<dim3(16, 32), 256, 0, stream>>>(kvcat + 1536, 2048, V8pT, 1024, 512, 4.0f);

    // 4. fused MFMA scores + mask + softmax -> aw8 (= softmax * 32 in e4m3)
    scores_mfma<<<dim3(256, 8), 256, 0, stream>>>(Ql, kvcat,        2048, mask_l, awl8, 0.125f);
    scores_mfma<<<dim3(256, 8), 256, 0, stream>>>(Qp, kvcat + 1024, 2048, mask_p, awp8, 0.125f);

    // 5. ctx = relu(aw @ V) per head (fp8), scale 1/(32*4)
    gemm_bt8<64, true><<<dim3(8, 32), 256, 0, stream>>>(
        awl8, 8192, 1024, V8lT, 1024, ctx_l, 512, 1024, 1.0f / 128.0f);
    gemm_bt8<64, true><<<dim3(8, 32), 256, 0, stream>>>(
        awp8, 8192, 1024, V8pT, 1024, ctx_p, 512, 1024, 1.0f / 128.0f);

    transpose_bf16_ld<<<dim3(16, 128), 256, 0, stream>>>(ctx_l, 512, ctxlT, 4096, 512);
    transpose_bf16_ld<<<dim3(16, 128), 256, 0, stream>>>(ctx_p, 512, ctxpT, 4096, 512);

    // 6. mutual = (awl @ awp^T) / 8  (fp8, scale 1/(32*32*8))
    gemm_bt8<128, false><<<dim3(32, 32), 256, 0, stream>>>(
        awl8, 8192, 0, awp8, 8192, mutual, 4096, 8192, 0.125f / 1024.0f);
    // awl8/awp8 dead: overlays live
    transpose_bf16_ld<<<dim3(128, 128), 256, 0, stream>>>(mutual, 4096, mutualT, 4096, 4096);

    // 7. fin_l -> cat_l[:,512:]; fin_p -> cat_p[:,:512]
    gemm_bt<64, false, true, false, false><<<dim3(8, 32), 256, 0, stream>>>(
        mutual, 4096, ctxpT, 4096, cat_l + 512, 1024, ctx_l, 512, nullptr, 4096, 1.0f);
    gemm_bt<64, false, true, false, false><<<dim3(8, 32), 256, 0, stream>>>(
        mutualT, 4096, ctxlT, 4096, cat_p, 1024, ctx_p, 512, nullptr, 4096, 1.0f);

    // 8. final projections (fp32) + LayerNorm -> d_out
    gemm_bt<64, true, false, false, true><<<dim3(4, 32), 256, 0, stream>>>(
        cat_l, 1024, WmlT, 1024, tmp1, 256, nullptr, 0, bml_c, 1024, 1.0f);
    gemm_bt<64, true, false, false, true><<<dim3(4, 32), 256, 0, stream>>>(
        cat_p, 1024, WmpT, 1024, tmp2, 256, nullptr, 0, bmp_c, 1024, 1.0f);

    ln_rows<<<dim3(1024), 256, 0, stream>>>(tmp1, g1c, be1c, d_out, 0, L, flag);
    ln_rows<<<dim3(1024), 256, 0, stream>>>(tmp2, g2c, be2c, d_out, (size_t)L, P, flag);
}

// Round 5
// 734.344 us; speedup vs baseline: 1.8959x; 1.2707x over previous
//
#include <hip/hip_runtime.h>
#include <hip/hip_bf16.h>

using bf16 = __hip_bfloat16;
typedef __attribute__((ext_vector_type(8))) short short8;
typedef __attribute__((ext_vector_type(4))) float floatx4;
typedef __attribute__((ext_vector_type(8))) unsigned short ushort8;
typedef __attribute__((ext_vector_type(4))) int i32x4;
typedef __attribute__((ext_vector_type(8))) int i32x8;

__device__ __forceinline__ float b2f(unsigned short u) {
    union { unsigned int i; float f; } x; x.i = ((unsigned int)u) << 16; return x.f;
}

__device__ __forceinline__ void async16(const void* g, void* l) {
    __builtin_amdgcn_global_load_lds((const __attribute__((address_space(1))) void*)g,
                                     (__attribute__((address_space(3))) void*)l,
                                     16, 0, 0);
}

// float -> OCP e4m3fn, RNE, signed, |f| clamped to 448.
__device__ __forceinline__ unsigned char f2e4m3(float f) {
    unsigned s = (__float_as_uint(f) >> 24) & 0x80u;
    f = fminf(fabsf(f), 448.f);
    if (f < 0.015625f) {                       // denormal target: ulp 2^-9
        int d = (int)rintf(f * 512.f);         // 0..8 (8 -> min normal 2^-6)
        return (unsigned char)(s | (unsigned)d);
    }
    int E = (int)((__float_as_uint(f) >> 23) & 255u) - 127;
    float ulp_inv = __uint_as_float((unsigned)(127 + 3 - E) << 23); // 2^(3-E)
    int m = (int)rintf(f * ulp_inv);           // 8..16
    int n = (m == 16) ? ((E + 8) << 3) : (((E + 7) << 3) + (m - 8));
    if (n > 0x7E) n = 0x7E;
    return (unsigned char)(s | (unsigned)n);
}

// ---------------------------------------------------------------------------
// Dtype sniffer: fp32 data read as bf16 decodes ~44% wild exponents.
// ---------------------------------------------------------------------------
__global__ void sniff_dtype(const unsigned short* p, int* flag) {
    int wild = 0;
    for (int i = threadIdx.x; i < 256; i += 64) {
        float a = fabsf(b2f(p[i]));
        if (!(a <= 1e4f)) wild++;
    }
#pragma unroll
    for (int o = 1; o < 64; o <<= 1) wild += __shfl_xor(wild, o);
    if (threadIdx.x == 0) *flag = (wild > 16) ? 1 : 0;
}

// ---------------------------------------------------------------------------
// Convert float inputs (fp32 or bf16 per flag) to canonical bf16 mirrors.
// ---------------------------------------------------------------------------
struct Cvt { const void* src; bf16* dst; int n; };
struct CvtTable { Cvt e[18]; };

__global__ __launch_bounds__(256) void convert_inputs(CvtTable t, const int* flag) {
    const Cvt c = t.e[blockIdx.y];
    const bool f32 = (*flag != 0);
    const int stride = gridDim.x * 256 * 8;
    for (int i = (blockIdx.x * 256 + threadIdx.x) * 8; i < c.n; i += stride) {
        if (f32) {
            const float* s = (const float*)c.src + i;
#pragma unroll
            for (int j = 0; j < 8; ++j) c.dst[i + j] = __float2bfloat16(s[j]);
        } else {
            *(ushort8*)((unsigned short*)c.dst + i) =
                *(const ushort8*)((const unsigned short*)c.src + i);
        }
    }
}

// ---------------------------------------------------------------------------
// Batched 512x512 dtype-aware transpose for the 9 square weights.
// ---------------------------------------------------------------------------
struct TT9 { const void* src[9]; bf16* dst[9]; };

__global__ __launch_bounds__(256) void transpose_sq9(TT9 t, const int* flag) {
    __shared__ bf16 tile[32][33];
    const void* in = t.src[blockIdx.z];
    bf16* out = t.dst[blockIdx.z];
    const bool f32 = (*flag != 0);
    const int tx = threadIdx.x & 31;
    const int ty = threadIdx.x >> 5;
    const int bc = blockIdx.x * 32;
    const int br = blockIdx.y * 32;
#pragma unroll
    for (int i = 0; i < 32; i += 8) {
        const size_t idx = (size_t)(br + ty + i) * 512 + bc + tx;
        tile[ty + i][tx] = f32 ? __float2bfloat16(((const float*)in)[idx])
                               : ((const bf16*)in)[idx];
    }
    __syncthreads();
#pragma unroll
    for (int i = 0; i < 32; i += 8)
        out[(size_t)(bc + ty + i) * 512 + br + tx] = tile[tx][ty + i];
}

// ---------------------------------------------------------------------------
// Dtype-aware rectangular transpose (for Wml/Wmp). out[C,R] = in[R,C]^T.
// ---------------------------------------------------------------------------
__global__ __launch_bounds__(256) void transpose_any_ld(
    const void* __restrict__ in, int ils, bf16* __restrict__ out,
    int R, int C, const int* __restrict__ flag)
{
    __shared__ bf16 tile[32][33];
    const bool f32 = (*flag != 0);
    const int tx = threadIdx.x & 31;
    const int ty = threadIdx.x >> 5;
    const int bc = blockIdx.x * 32;
    const int br = blockIdx.y * 32;
#pragma unroll
    for (int i = 0; i < 32; i += 8) {
        const size_t idx = (size_t)(br + ty + i) * ils + bc + tx;
        tile[ty + i][tx] = f32 ? __float2bfloat16(((const float*)in)[idx])
                               : ((const bf16*)in)[idx];
    }
    __syncthreads();
#pragma unroll
    for (int i = 0; i < 32; i += 8)
        out[(size_t)(bc + ty + i) * R + br + tx] = tile[tx][ty + i];
}

// ---------------------------------------------------------------------------
// bf16 transpose with input ld (internal buffers). out[C,R] = in[R,C]^T.
// ---------------------------------------------------------------------------
__global__ __launch_bounds__(256) void transpose_bf16_ld(
    const bf16* __restrict__ in, int ils, bf16* __restrict__ out, int R, int C)
{
    __shared__ bf16 tile[32][33];
    const int tx = threadIdx.x & 31;
    const int ty = threadIdx.x >> 5;
    const int bc = blockIdx.x * 32;
    const int br = blockIdx.y * 32;
#pragma unroll
    for (int i = 0; i < 32; i += 8)
        tile[ty + i][tx] = in[(size_t)(br + ty + i) * ils + bc + tx];
    __syncthreads();
#pragma unroll
    for (int i = 0; i < 32; i += 8)
        out[(size_t)(bc + ty + i) * R + br + tx] = tile[tx][ty + i];
}

// ---------------------------------------------------------------------------
// Quantizing transpose: out[C,R] = e4m3(in[R,C]^T * vs).  (for V -> V8T)
// ---------------------------------------------------------------------------
__global__ __launch_bounds__(256) void transpose_q8(
    const bf16* __restrict__ in, int ils, unsigned char* __restrict__ out,
    int R, int C, float vs)
{
    __shared__ float tile[32][33];
    const int tx = threadIdx.x & 31;
    const int ty = threadIdx.x >> 5;
    const int bc = blockIdx.x * 32;
    const int br = blockIdx.y * 32;
#pragma unroll
    for (int i = 0; i < 32; i += 8)
        tile[ty + i][tx] =
            __bfloat162float(in[(size_t)(br + ty + i) * ils + bc + tx]) * vs;
    __syncthreads();
#pragma unroll
    for (int i = 0; i < 32; i += 8)
        out[(size_t)(bc + ty + i) * R + br + tx] = f2e4m3(tile[tx][ty + i]);
}

// ---------------------------------------------------------------------------
// Generic bf16 C = A * B^T GEMM (m97 structure). A:[M,K] lda, B:[N,K] ldb.
// ---------------------------------------------------------------------------
template <int BN, bool BIAS, bool ADDC0, bool RELU, bool F32OUT>
__global__ __launch_bounds__(256) void gemm_bt(
    const bf16* __restrict__ A, int lda,
    const bf16* __restrict__ B, int ldb,
    void* __restrict__ Cout, int ldc,
    const bf16* __restrict__ C0, int ldc0,
    const bf16* __restrict__ bias,
    int K, float scale)
{
    constexpr int BM = 128;
    constexpr int WN = BN / 2;
    constexpr int TM = 4;
    constexpr int TN = WN / 16;

    __align__(16) __shared__ bf16 As[BM * 32];
    __align__(16) __shared__ bf16 Bs[BN * 32];

    const int tid  = threadIdx.x;
    const int lane = tid & 63;
    const int wv   = tid >> 6;
    const int m_base = blockIdx.y * BM;
    const int n_base = blockIdx.x * BN;

    const int wm0 = (wv >> 1) * 64;
    const int wn0 = (wv & 1) * WN;

    floatx4 zero = {0.f, 0.f, 0.f, 0.f};
    floatx4 acc[TM][TN];
#pragma unroll
    for (int mt = 0; mt < TM; ++mt)
#pragma unroll
        for (int nt = 0; nt < TN; ++nt) acc[mt][nt] = zero;

    const int ar = lane >> 2;
    const int ac = (lane & 3) * 8;
    const int fr = lane & 15;
    const int fk = (lane >> 4) * 8;

    for (int k0 = 0; k0 < K; k0 += 32) {
#pragma unroll
        for (int cc = 0; cc < BM / 64; ++cc) {
            const int r0t = (wv + cc * 4) * 16;
            async16(A + (size_t)(m_base + r0t + ar) * lda + k0 + ac, &As[r0t * 32]);
        }
#pragma unroll
        for (int cc = 0; cc < BN / 64; ++cc) {
            const int r0t = (wv + cc * 4) * 16;
            async16(B + (size_t)(n_base + r0t + ar) * ldb + k0 + ac, &Bs[r0t * 32]);
        }
        __syncthreads();

        short8 af[TM], bfrag[TN];
#pragma unroll
        for (int mt = 0; mt < TM; ++mt)
            af[mt] = *(const short8*)&As[(wm0 + mt * 16 + fr) * 32 + fk];
#pragma unroll
        for (int nt = 0; nt < TN; ++nt)
            bfrag[nt] = *(const short8*)&Bs[(wn0 + nt * 16 + fr) * 32 + fk];
#pragma unroll
        for (int mt = 0; mt < TM; ++mt)
#pragma unroll
            for (int nt = 0; nt < TN; ++nt)
                acc[mt][nt] = __builtin_amdgcn_mfma_f32_16x16x32_bf16(
                    af[mt], bfrag[nt], acc[mt][nt], 0, 0, 0);
        __syncthreads();
    }

    const int er = lane >> 4;
    const int ec = lane & 15;
#pragma unroll
    for (int nt = 0; nt < TN; ++nt) {
        const int col = n_base + wn0 + nt * 16 + ec;
        float bv = 0.f;
        if constexpr (BIAS) bv = __bfloat162float(bias[col]);
#pragma unroll
        for (int mt = 0; mt < TM; ++mt) {
#pragma unroll
            for (int r = 0; r < 4; ++r) {
                const int row = m_base + wm0 + mt * 16 + er * 4 + r;
                float v = acc[mt][nt][r] * scale + bv;
                if constexpr (ADDC0) v += __bfloat162float(C0[(size_t)row * ldc0 + col]);
                if constexpr (RELU) v = fmaxf(v, 0.f);
                if constexpr (F32OUT)
                    ((float*)Cout)[(size_t)row * ldc + col] = v;
                else
                    ((bf16*)Cout)[(size_t)row * ldc + col] = __float2bfloat16(v);
            }
        }
    }
}

// ---------------------------------------------------------------------------
// fp8 C = A * B^T GEMM, BK=64, mfma_f32_16x16x32_fp8_fp8 (kept for ctx).
// XOR-swizzled LDS (round-4): ~4 extra cyc/read residual (quarter-phase
// parity limit) — acceptable for the small ctx GEMMs.
// ---------------------------------------------------------------------------
template <int BN, bool RELU>
__global__ __launch_bounds__(256) void gemm_bt8(
    const unsigned char* __restrict__ A, int lda, long long a_kshift,
    const unsigned char* __restrict__ B, int ldb,
    bf16* __restrict__ C, int ldc,
    int K, float scale)
{
    constexpr int BM = 128;
    constexpr int WN = BN / 2;
    constexpr int TM = 4;
    constexpr int TN = WN / 16;

    __align__(16) __shared__ unsigned char As[BM * 64];
    __align__(16) __shared__ unsigned char Bs[BN * 64];

    const int tid  = threadIdx.x;
    const int lane = tid & 63;
    const int wv   = tid >> 6;
    const int m_base = blockIdx.y * BM;
    const int n_base = blockIdx.x * BN;
    A += (long long)blockIdx.x * a_kshift;

    const int wm0 = (wv >> 1) * 64;
    const int wn0 = (wv & 1) * WN;

    floatx4 zero = {0.f, 0.f, 0.f, 0.f};
    floatx4 acc[TM][TN];
#pragma unroll
    for (int mt = 0; mt < TM; ++mt)
#pragma unroll
        for (int nt = 0; nt < TN; ++nt) acc[mt][nt] = zero;

    const int ar = lane >> 2;
    const int ac = (((lane & 3) ^ (ar & 3)) * 16);
    const int fr = lane & 15;
    const int q  = lane >> 4;
    const int sw = fr & 3;

    for (int k0 = 0; k0 < K; k0 += 64) {
#pragma unroll
        for (int cc = 0; cc < BM / 16; cc += 4) {
            const int r0t = (wv + cc) * 16;
            async16(A + (size_t)(m_base + r0t + ar) * lda + k0 + ac, &As[r0t * 64]);
        }
#pragma unroll
        for (int cc = 0; cc < BN / 16; cc += 4) {
            const int r0t = (wv + cc) * 16;
            async16(B + (size_t)(n_base + r0t + ar) * ldb + k0 + ac, &Bs[r0t * 64]);
        }
        __syncthreads();

#pragma unroll
        for (int s = 0; s < 2; ++s) {
            const int boff = (((s * 2 + (q >> 1)) ^ sw) * 16) + (q & 1) * 8;
            long af[TM], bfr[TN];
#pragma unroll
            for (int mt = 0; mt < TM; ++mt)
                af[mt] = *(const long*)&As[(wm0 + mt * 16 + fr) * 64 + boff];
#pragma unroll
            for (int nt = 0; nt < TN; ++nt)
                bfr[nt] = *(const long*)&Bs[(wn0 + nt * 16 + fr) * 64 + boff];
#pragma unroll
            for (int mt = 0; mt < TM; ++mt)
#pragma unroll
                for (int nt = 0; nt < TN; ++nt)
                    acc[mt][nt] = __builtin_amdgcn_mfma_f32_16x16x32_fp8_fp8(
                        af[mt], bfr[nt], acc[mt][nt], 0, 0, 0);
        }
        __syncthreads();
    }

    const int er = lane >> 4;
    const int ec = lane & 15;
#pragma unroll
    for (int nt = 0; nt < TN; ++nt) {
        const int col = n_base + wn0 + nt * 16 + ec;
#pragma unroll
        for (int mt = 0; mt < TM; ++mt) {
#pragma unroll
            for (int r = 0; r < 4; ++r) {
                const int row = m_base + wm0 + mt * 16 + er * 4 + r;
                float v = acc[mt][nt][r] * scale;
                if constexpr (RELU) v = fmaxf(v, 0.f);
                C[(size_t)row * ldc + col] = __float2bfloat16(v);
            }
        }
    }
}

// ---------------------------------------------------------------------------
// MX-scaled fp8 C = A * B^T GEMM, BK=128, mfma_scale_f32_16x16x128_f8f6f4
// with unit e8m0 scales (0x7F) => plain fp8 GEMM at 2x rate (m148 path).
// Row stride 128B; chunk swizzle slot = chunk ^ (row&7) puts the b128
// fragment reads at the quarter-phase bank floor (fr*32 drops out mod 32,
// 8-slot XOR covers all 32 banks). Staging: 1KB async16 per 8 rows with
// source-chunk permutation ((lane&7)^(lane>>3))*16.
// ---------------------------------------------------------------------------
template <int BN>
__global__ __launch_bounds__(256) void gemm_bt8mx(
    const unsigned char* __restrict__ A, int lda,
    const unsigned char* __restrict__ B, int ldb,
    bf16* __restrict__ C, int ldc,
    int K, float scale)
{
    constexpr int BM = 128;
    constexpr int WN = BN / 2;
    constexpr int TM = 4;
    constexpr int TN = WN / 16;

    __align__(16) __shared__ unsigned char As[BM * 128];
    __align__(16) __shared__ unsigned char Bs[BN * 128];

    const int tid  = threadIdx.x;
    const int lane = tid & 63;
    const int wv   = tid >> 6;
    const int m_base = blockIdx.y * BM;
    const int n_base = blockIdx.x * BN;

    const int wm0 = (wv >> 1) * 64;
    const int wn0 = (wv & 1) * WN;

    floatx4 zero = {0.f, 0.f, 0.f, 0.f};
    floatx4 acc[TM][TN];
#pragma unroll
    for (int mt = 0; mt < TM; ++mt)
#pragma unroll
        for (int nt = 0; nt < TN; ++nt) acc[mt][nt] = zero;

    const int sr = lane >> 3;                    // staging row within 8-row group
    const int sc = ((lane & 7) ^ sr) * 16;       // swizzled source chunk
    const int fr = lane & 15;
    const int q  = lane >> 4;                    // k-quarter: k = q*32 .. +32
    const int sw = fr & 7;

    for (int k0 = 0; k0 < K; k0 += 128) {
#pragma unroll
        for (int cc = 0; cc < BM / 32; ++cc) {   // 16 instrs total, 4/wave
            const int r0t = (wv + cc * 4) * 8;
            async16(A + (size_t)(m_base + r0t + sr) * lda + k0 + sc, &As[r0t * 128]);
        }
#pragma unroll
        for (int cc = 0; cc < BN / 32; ++cc) {
            const int r0t = (wv + cc * 4) * 8;
            async16(B + (size_t)(n_base + r0t + sr) * ldb + k0 + sc, &Bs[r0t * 128]);
        }
        __syncthreads();

        i32x8 af[TM], bf8[TN];
#pragma unroll
        for (int mt = 0; mt < TM; ++mt) {
            const unsigned char* rp = &As[(wm0 + mt * 16 + fr) * 128];
            i32x4 lo = *(const i32x4*)(rp + (((q * 2 + 0) ^ sw) * 16));
            i32x4 hi = *(const i32x4*)(rp + (((q * 2 + 1) ^ sw) * 16));
            af[mt] = __builtin_shufflevector(lo, hi, 0, 1, 2, 3, 4, 5, 6, 7);
        }
#pragma unroll
        for (int nt = 0; nt < TN; ++nt) {
            const unsigned char* rp = &Bs[(wn0 + nt * 16 + fr) * 128];
            i32x4 lo = *(const i32x4*)(rp + (((q * 2 + 0) ^ sw) * 16));
            i32x4 hi = *(const i32x4*)(rp + (((q * 2 + 1) ^ sw) * 16));
            bf8[nt] = __builtin_shufflevector(lo, hi, 0, 1, 2, 3, 4, 5, 6, 7);
        }
#pragma unroll
        for (int mt = 0; mt < TM; ++mt)
#pragma unroll
            for (int nt = 0; nt < TN; ++nt)
                acc[mt][nt] = __builtin_amdgcn_mfma_scale_f32_16x16x128_f8f6f4(
                    af[mt], bf8[nt], acc[mt][nt],
                    0 /*cbsz: fp8*/, 0 /*blgp: fp8*/,
                    0, 127 /*opsel_a, scale_a = 2^0*/,
                    0, 127 /*opsel_b, scale_b = 2^0*/);
        __syncthreads();
    }

    const int er = lane >> 4;
    const int ec = lane & 15;
#pragma unroll
    for (int nt = 0; nt < TN; ++nt) {
        const int col = n_base + wn0 + nt * 16 + ec;
#pragma unroll
        for (int mt = 0; mt < TM; ++mt) {
#pragma unroll
            for (int r = 0; r < 4; ++r) {
                const int row = m_base + wm0 + mt * 16 + er * 4 + r;
                C[(size_t)row * ldc + col] = __float2bfloat16(acc[mt][nt][r] * scale);
            }
        }
    }
}

// ---------------------------------------------------------------------------
// MFMA fused scores + mask + softmax. Block = 16 Q-rows x 1024 cols, 1 head.
// Output: aw8 = e4m3(softmax * 32) at [row, h*1024 + col].
// ---------------------------------------------------------------------------
__global__ __launch_bounds__(256) void scores_mfma(
    const bf16* __restrict__ Q,          // [Nq, 512]
    const bf16* __restrict__ Kbase,      // [1024, ldk] (head cols at h*64)
    int ldk,
    const int* __restrict__ mask,        // [Nq, 1024]
    unsigned char* __restrict__ aw8,     // [Nq, 8192]
    float scale)
{
    __shared__ float wred[16][4];
    __shared__ float wsum[16][4];

    const int t    = threadIdx.x;
    const int lane = t & 63;
    const int w    = t >> 6;
    const int h    = blockIdx.y;
    const int r0   = blockIdx.x * 16;
    const int fr   = lane & 15;
    const int fq   = lane >> 4;
    const int cbase = w * 256;

    const short* Qs = (const short*)Q + (size_t)(r0 + fr) * 512 + h * 64 + fq * 8;
    short8 a0 = *(const short8*)(Qs);
    short8 a1 = *(const short8*)(Qs + 32);

    floatx4 accs[16];
    const short* Kb = (const short*)Kbase + h * 64 + fq * 8;
#pragma unroll
    for (int c = 0; c < 16; ++c) {
        const int krow = cbase + c * 16 + fr;
        short8 b0 = *(const short8*)(Kb + (size_t)krow * ldk);
        short8 b1 = *(const short8*)(Kb + (size_t)krow * ldk + 32);
        floatx4 acc = {0.f, 0.f, 0.f, 0.f};
        acc = __builtin_amdgcn_mfma_f32_16x16x32_bf16(a0, b0, acc, 0, 0, 0);
        acc = __builtin_amdgcn_mfma_f32_16x16x32_bf16(a1, b1, acc, 0, 0, 0);
        accs[c] = acc;
    }

    float mxr[4] = {-3e38f, -3e38f, -3e38f, -3e38f};
#pragma unroll
    for (int c = 0; c < 16; ++c) {
        const int col = cbase + c * 16 + fr;
#pragma unroll
        for (int r = 0; r < 4; ++r) {
            const int row = r0 + fq * 4 + r;
            float v = (mask[(size_t)row * 1024 + col] == 0) ? -1e9f
                                                            : accs[c][r] * scale;
            accs[c][r] = v;
            mxr[r] = fmaxf(mxr[r], v);
        }
    }
#pragma unroll
    for (int o = 1; o < 16; o <<= 1)
#pragma unroll
        for (int r = 0; r < 4; ++r) mxr[r] = fmaxf(mxr[r], __shfl_xor(mxr[r], o));
    if (fr == 0)
#pragma unroll
        for (int r = 0; r < 4; ++r) wred[fq * 4 + r][w] = mxr[r];
    __syncthreads();

    float mx[4], sm[4] = {0.f, 0.f, 0.f, 0.f};
#pragma unroll
    for (int r = 0; r < 4; ++r) {
        const int row = fq * 4 + r;
        mx[r] = fmaxf(fmaxf(wred[row][0], wred[row][1]),
                      fmaxf(wred[row][2], wred[row][3]));
    }
#pragma unroll
    for (int c = 0; c < 16; ++c)
#pragma unroll
        for (int r = 0; r < 4; ++r) {
            float e = __expf(accs[c][r] - mx[r]);
            accs[c][r] = e;
            sm[r] += e;
        }
#pragma unroll
    for (int o = 1; o < 16; o <<= 1)
#pragma unroll
        for (int r = 0; r < 4; ++r) sm[r] += __shfl_xor(sm[r], o);
    if (fr == 0)
#pragma unroll
        for (int r = 0; r < 4; ++r) wsum[fq * 4 + r][w] = sm[r];
    __syncthreads();

    float inv[4];
#pragma unroll
    for (int r = 0; r < 4; ++r) {
        const int row = fq * 4 + r;
        inv[r] = 32.0f / (wsum[row][0] + wsum[row][1] + wsum[row][2] + wsum[row][3]);
    }
#pragma unroll
    for (int c = 0; c < 16; ++c) {
        const int col = cbase + c * 16 + fr;
#pragma unroll
        for (int r = 0; r < 4; ++r) {
            const int row = r0 + fq * 4 + r;
            aw8[(size_t)row * 8192 + h * 1024 + col] = f2e4m3(accs[c][r] * inv[r]);
        }
    }
}

// ---------------------------------------------------------------------------
// LayerNorm over 256 cols, fp32 in -> bf16/fp32 out per flag. 4 rows/block.
// ---------------------------------------------------------------------------
__global__ __launch_bounds__(256) void ln_rows(
    const float* __restrict__ X, const bf16* __restrict__ g,
    const bf16* __restrict__ b, void* __restrict__ out, size_t row0, int rows,
    const int* __restrict__ flag)
{
    const bool f32 = (*flag != 0);
    const int lane = threadIdx.x & 63;
    const int wv   = threadIdx.x >> 6;
    const int row  = blockIdx.x * 4 + wv;
    if (row >= rows) return;
    const float* x = X + (size_t)row * 256;
    float v[4], s = 0.f, s2 = 0.f;
#pragma unroll
    for (int i = 0; i < 4; ++i) {
        v[i] = x[lane + 64 * i];
        s += v[i]; s2 += v[i] * v[i];
    }
#pragma unroll
    for (int o = 1; o < 64; o <<= 1) { s += __shfl_xor(s, o); s2 += __shfl_xor(s2, o); }
    const float mu  = s * (1.0f / 256.0f);
    const float var = fmaxf(s2 * (1.0f / 256.0f) - mu * mu, 0.0f);
    const float inv = rsqrtf(var + 1e-5f);
#pragma unroll
    for (int i = 0; i < 4; ++i) {
        const int c = lane + 64 * i;
        const float y = (v[i] - mu) * inv * __bfloat162float(g[c]) + __bfloat162float(b[c]);
        if (f32) ((float*)out)[(row0 + row) * 256 + c] = y;
        else     ((bf16*)out)[(row0 + row) * 256 + c] = __float2bfloat16(y);
    }
}

// ---------------------------------------------------------------------------
extern "C" void kernel_launch(void* const* d_in, const int* in_sizes, int n_in,
                              void* d_out, int out_size, void* d_ws, size_t ws_size,
                              hipStream_t stream)
{
    const int L = 4096, Mm = 1024, P = 4096;

    const int* mask_l = (const int*)d_in[3];
    const int* mask_p = (const int*)d_in[4];

    char* ws = (char*)d_ws;
    size_t off = 0;
    auto alloc = [&](size_t bytes) {
        void* p = ws + off; off += (bytes + 255) & ~(size_t)255; return p;
    };

    int*  flag   = (int*)alloc(256);
    // weight slots: 0:Wl 1:Wm 2:Wp 3:Wql 4:Wqp 5:Wkl 6:Wvl 7:Wkp 8:Wvp
    bf16* wt_all = (bf16*)alloc((size_t)9 * 512 * 512 * 2);
    bf16* WmlT   = (bf16*)alloc(1024 * 256 * 2);
    bf16* WmpT   = (bf16*)alloc(1024 * 256 * 2);
    bf16* b_l    = (bf16*)alloc(512 * 2);
    bf16* b_m    = (bf16*)alloc(512 * 2);
    bf16* b_p    = (bf16*)alloc(512 * 2);
    bf16* b_ql   = (bf16*)alloc(512 * 2);
    bf16* b_qp   = (bf16*)alloc(512 * 2);
    bf16* bcat   = (bf16*)alloc(2048 * 2);     // [bkl|bvl|bkp|bvp]
    bf16* bml_c  = (bf16*)alloc(256 * 2);
    bf16* bmp_c  = (bf16*)alloc(256 * 2);
    bf16* g1c    = (bf16*)alloc(256 * 2);
    bf16* be1c   = (bf16*)alloc(256 * 2);
    bf16* g2c    = (bf16*)alloc(256 * 2);
    bf16* be2c   = (bf16*)alloc(256 * 2);
    bf16* embl   = (bf16*)alloc((size_t)L * 512 * 2);
    bf16* embm   = (bf16*)alloc((size_t)Mm * 512 * 2);
    bf16* embp   = (bf16*)alloc((size_t)P * 512 * 2);
    bf16* cat_l  = (bf16*)alloc((size_t)L * 1024 * 2);   // [lt | fin_l]
    bf16* cat_p  = (bf16*)alloc((size_t)P * 1024 * 2);   // [fin_p | pt]
    bf16* mt     = (bf16*)alloc((size_t)Mm * 512 * 2);
    bf16* Ql     = (bf16*)alloc((size_t)L * 512 * 2);
    bf16* Qp     = (bf16*)alloc((size_t)P * 512 * 2);
    bf16* kvcat  = (bf16*)alloc((size_t)Mm * 2048 * 2);  // [Kl|Vl|Kp|Vp]
    unsigned char* V8lT = (unsigned char*)alloc((size_t)512 * Mm);
    unsigned char* V8pT = (unsigned char*)alloc((size_t)512 * Mm);
    bf16* ctx_l  = (bf16*)alloc((size_t)L * 512 * 2);
    bf16* ctx_p  = (bf16*)alloc((size_t)P * 512 * 2);
    bf16* ctxlT  = (bf16*)alloc((size_t)512 * L * 2);
    bf16* ctxpT  = (bf16*)alloc((size_t)512 * P * 2);
    bf16* mutual = (bf16*)alloc((size_t)L * P * 2);
    unsigned char* awl8 = (unsigned char*)alloc((size_t)L * 8192);
    unsigned char* awp8 = (unsigned char*)alloc((size_t)P * 8192);
    // overlays: awl8/awp8 dead after the mutual GEMM
    bf16*  mutualT = (bf16*)awl8;
    float* tmp1    = (float*)awp8;
    float* tmp2    = (float*)awp8 + (size_t)L * 256;

    // 0. dtype sniff + canonicalize
    sniff_dtype<<<1, 64, 0, stream>>>((const unsigned short*)d_in[0], flag);

    CvtTable tab;
    tab.e[0]  = { d_in[0],  embl, L * 512 };
    tab.e[1]  = { d_in[1],  embm, Mm * 512 };
    tab.e[2]  = { d_in[2],  embp, P * 512 };
    tab.e[3]  = { d_in[6],  b_l,  512 };
    tab.e[4]  = { d_in[8],  b_m,  512 };
    tab.e[5]  = { d_in[10], b_p,  512 };
    tab.e[6]  = { d_in[12], b_ql, 512 };
    tab.e[7]  = { d_in[18], b_qp, 512 };
    tab.e[8]  = { d_in[14], bcat,        512 };   // bkl
    tab.e[9]  = { d_in[16], bcat + 512,  512 };   // bvl
    tab.e[10] = { d_in[20], bcat + 1024, 512 };   // bkp
    tab.e[11] = { d_in[22], bcat + 1536, 512 };   // bvp
    tab.e[12] = { d_in[24], bml_c, 256 };
    tab.e[13] = { d_in[26], bmp_c, 256 };
    tab.e[14] = { d_in[27], g1c,  256 };
    tab.e[15] = { d_in[28], be1c, 256 };
    tab.e[16] = { d_in[29], g2c,  256 };
    tab.e[17] = { d_in[30], be2c, 256 };
    convert_inputs<<<dim3(256, 18), 256, 0, stream>>>(tab, flag);

    // 1. weight transposes
    TT9 tt;
    const int slot_of[9] = {0, 1, 2, 3, 5, 6, 4, 7, 8};  // input order -> slot
    for (int i = 0; i < 9; ++i) {
        tt.src[i] = d_in[5 + 2 * i];
        tt.dst[i] = wt_all + (size_t)slot_of[i] * 512 * 512;
    }
    transpose_sq9<<<dim3(16, 16, 9), 256, 0, stream>>>(tt, flag);
    transpose_any_ld<<<dim3(8, 32), 256, 0, stream>>>(d_in[23], 256, WmlT, 1024, 256, flag);
    transpose_any_ld<<<dim3(8, 32), 256, 0, stream>>>(d_in[25], 256, WmpT, 1024, 256, flag);

    bf16* WlT  = wt_all;
    bf16* WmT  = wt_all + (size_t)1 * 512 * 512;
    bf16* WpT  = wt_all + (size_t)2 * 512 * 512;
    bf16* WqlT = wt_all + (size_t)3 * 512 * 512;
    bf16* WqpT = wt_all + (size_t)4 * 512 * 512;
    bf16* WkvT = wt_all + (size_t)5 * 512 * 512;  // [2048, 512]

    // 2. input projections
    gemm_bt<64, true, false, false, false><<<dim3(8, 32), 256, 0, stream>>>(
        embl, 512, WlT, 512, cat_l, 1024, nullptr, 0, b_l, 512, 1.0f);
    gemm_bt<64, true, false, false, false><<<dim3(8, 8), 256, 0, stream>>>(
        embm, 512, WmT, 512, mt, 512, nullptr, 0, b_m, 512, 1.0f);
    gemm_bt<64, true, false, false, false><<<dim3(8, 32), 256, 0, stream>>>(
        embp, 512, WpT, 512, cat_p + 512, 1024, nullptr, 0, b_p, 512, 1.0f);

    // 3. Q projections + fused K/V projection  kvcat = mt @ [Wkl|Wvl|Wkp|Wvp]
    gemm_bt<64, true, false, false, false><<<dim3(8, 32), 256, 0, stream>>>(
        cat_l, 1024, WqlT, 512, Ql, 512, nullptr, 0, b_ql, 512, 1.0f);
    gemm_bt<64, true, false, false, false><<<dim3(8, 32), 256, 0, stream>>>(
        cat_p + 512, 1024, WqpT, 512, Qp, 512, nullptr, 0, b_qp, 512, 1.0f);
    gemm_bt<64, true, false, false, false><<<dim3(32, 8), 256, 0, stream>>>(
        mt, 512, WkvT, 512, kvcat, 2048, nullptr, 0, bcat, 512, 1.0f);

    // V8T = e4m3(V^T * 4)
    transpose_q8<<<dim3(16, 32), 256, 0, stream>>>(kvcat + 512,  2048, V8lT, 1024, 512, 4.0f);
    transpose_q8<<<dim3(16, 32), 256, 0, stream>>>(kvcat + 1536, 2048, V8pT, 1024, 512, 4.0f);

    // 4. fused MFMA scores + mask + softmax -> aw8 (= softmax * 32 in e4m3)
    scores_mfma<<<dim3(256, 8), 256, 0, stream>>>(Ql, kvcat,        2048, mask_l, awl8, 0.125f);
    scores_mfma<<<dim3(256, 8), 256, 0, stream>>>(Qp, kvcat + 1024, 2048, mask_p, awp8, 0.125f);

    // 5. ctx = relu(aw @ V) per head (fp8), scale 1/(32*4)
    gemm_bt8<64, true><<<dim3(8, 32), 256, 0, stream>>>(
        awl8, 8192, 1024, V8lT, 1024, ctx_l, 512, 1024, 1.0f / 128.0f);
    gemm_bt8<64, true><<<dim3(8, 32), 256, 0, stream>>>(
        awp8, 8192, 1024, V8pT, 1024, ctx_p, 512, 1024, 1.0f / 128.0f);

    transpose_bf16_ld<<<dim3(16, 128), 256, 0, stream>>>(ctx_l, 512, ctxlT, 4096, 512);
    transpose_bf16_ld<<<dim3(16, 128), 256, 0, stream>>>(ctx_p, 512, ctxpT, 4096, 512);

    // 6. mutual = (awl @ awp^T) / 8  (MX fp8, BK=128, scale 1/(32*32*8))
    gemm_bt8mx<128><<<dim3(32, 32), 256, 0, stream>>>(
        awl8, 8192, awp8, 8192, mutual, 4096, 8192, 0.125f / 1024.0f);
    // awl8/awp8 dead: overlays live
    transpose_bf16_ld<<<dim3(128, 128), 256, 0, stream>>>(mutual, 4096, mutualT, 4096, 4096);

    // 7. fin_l -> cat_l[:,512:]; fin_p -> cat_p[:,:512]
    gemm_bt<64, false, true, false, false><<<dim3(8, 32), 256, 0, stream>>>(
        mutual, 4096, ctxpT, 4096, cat_l + 512, 1024, ctx_l, 512, nullptr, 4096, 1.0f);
    gemm_bt<64, false, true, false, false><<<dim3(8, 32), 256, 0, stream>>>(
        mutualT, 4096, ctxlT, 4096, cat_p, 1024, ctx_p, 512, nullptr, 4096, 1.0f);

    // 8. final projections (fp32) + LayerNorm -> d_out
    gemm_bt<64, true, false, false, true><<<dim3(4, 32), 256, 0, stream>>>(
        cat_l, 1024, WmlT, 1024, tmp1, 256, nullptr, 0, bml_c, 1024, 1.0f);
    gemm_bt<64, true, false, false, true><<<dim3(4, 32), 256, 0, stream>>>(
        cat_p, 1024, WmpT, 1024, tmp2, 256, nullptr, 0, bmp_c, 1024, 1.0f);

    ln_rows<<<dim3(1024), 256, 0, stream>>>(tmp1, g1c, be1c, d_out, 0, L, flag);
    ln_rows<<<dim3(1024), 256, 0, stream>>>(tmp2, g2c, be2c, d_out, (size_t)L, P, flag);
}

// Round 6
// 626.995 us; speedup vs baseline: 2.2205x; 1.1712x over previous
//
#include <hip/hip_runtime.h>
#include <hip/hip_bf16.h>

using bf16 = __hip_bfloat16;
typedef __attribute__((ext_vector_type(8))) short short8;
typedef __attribute__((ext_vector_type(4))) float floatx4;
typedef __attribute__((ext_vector_type(8))) unsigned short ushort8;
typedef __attribute__((ext_vector_type(4))) int i32x4;
typedef __attribute__((ext_vector_type(8))) int i32x8;

__device__ __forceinline__ float b2f(unsigned short u) {
    union { unsigned int i; float f; } x; x.i = ((unsigned int)u) << 16; return x.f;
}

__device__ __forceinline__ void async16(const void* g, void* l) {
    __builtin_amdgcn_global_load_lds((const __attribute__((address_space(1))) void*)g,
                                     (__attribute__((address_space(3))) void*)l,
                                     16, 0, 0);
}

// float -> OCP e4m3fn, RNE, signed, |f| clamped to 448.
__device__ __forceinline__ unsigned char f2e4m3(float f) {
    unsigned s = (__float_as_uint(f) >> 24) & 0x80u;
    f = fminf(fabsf(f), 448.f);
    if (f < 0.015625f) {                       // denormal target: ulp 2^-9
        int d = (int)rintf(f * 512.f);         // 0..8 (8 -> min normal 2^-6)
        return (unsigned char)(s | (unsigned)d);
    }
    int E = (int)((__float_as_uint(f) >> 23) & 255u) - 127;
    float ulp_inv = __uint_as_float((unsigned)(127 + 3 - E) << 23); // 2^(3-E)
    int m = (int)rintf(f * ulp_inv);           // 8..16
    int n = (m == 16) ? ((E + 8) << 3) : (((E + 7) << 3) + (m - 8));
    if (n > 0x7E) n = 0x7E;
    return (unsigned char)(s | (unsigned)n);
}

// ---------------------------------------------------------------------------
// Dtype sniffer: fp32 data read as bf16 decodes ~44% wild exponents.
// ---------------------------------------------------------------------------
__global__ void sniff_dtype(const unsigned short* p, int* flag) {
    int wild = 0;
    for (int i = threadIdx.x; i < 256; i += 64) {
        float a = fabsf(b2f(p[i]));
        if (!(a <= 1e4f)) wild++;
    }
#pragma unroll
    for (int o = 1; o < 64; o <<= 1) wild += __shfl_xor(wild, o);
    if (threadIdx.x == 0) *flag = (wild > 16) ? 1 : 0;
}

// ---------------------------------------------------------------------------
// Convert float inputs (fp32 or bf16 per flag) to canonical bf16 mirrors.
// ---------------------------------------------------------------------------
struct Cvt { const void* src; bf16* dst; int n; };
struct CvtTable { Cvt e[18]; };

__global__ __launch_bounds__(256) void convert_inputs(CvtTable t, const int* flag) {
    const Cvt c = t.e[blockIdx.y];
    const bool f32 = (*flag != 0);
    const int stride = gridDim.x * 256 * 8;
    for (int i = (blockIdx.x * 256 + threadIdx.x) * 8; i < c.n; i += stride) {
        if (f32) {
            const float* s = (const float*)c.src + i;
#pragma unroll
            for (int j = 0; j < 8; ++j) c.dst[i + j] = __float2bfloat16(s[j]);
        } else {
            *(ushort8*)((unsigned short*)c.dst + i) =
                *(const ushort8*)((const unsigned short*)c.src + i);
        }
    }
}

// ---------------------------------------------------------------------------
// Batched 512x512 dtype-aware transpose for the 9 square weights.
// ---------------------------------------------------------------------------
struct TT9 { const void* src[9]; bf16* dst[9]; };

__global__ __launch_bounds__(256) void transpose_sq9(TT9 t, const int* flag) {
    __shared__ bf16 tile[32][33];
    const void* in = t.src[blockIdx.z];
    bf16* out = t.dst[blockIdx.z];
    const bool f32 = (*flag != 0);
    const int tx = threadIdx.x & 31;
    const int ty = threadIdx.x >> 5;
    const int bc = blockIdx.x * 32;
    const int br = blockIdx.y * 32;
#pragma unroll
    for (int i = 0; i < 32; i += 8) {
        const size_t idx = (size_t)(br + ty + i) * 512 + bc + tx;
        tile[ty + i][tx] = f32 ? __float2bfloat16(((const float*)in)[idx])
                               : ((const bf16*)in)[idx];
    }
    __syncthreads();
#pragma unroll
    for (int i = 0; i < 32; i += 8)
        out[(size_t)(bc + ty + i) * 512 + br + tx] = tile[tx][ty + i];
}

// ---------------------------------------------------------------------------
// Dtype-aware rectangular transpose (for Wml/Wmp). out[C,R] = in[R,C]^T.
// ---------------------------------------------------------------------------
__global__ __launch_bounds__(256) void transpose_any_ld(
    const void* __restrict__ in, int ils, bf16* __restrict__ out,
    int R, int C, const int* __restrict__ flag)
{
    __shared__ bf16 tile[32][33];
    const bool f32 = (*flag != 0);
    const int tx = threadIdx.x & 31;
    const int ty = threadIdx.x >> 5;
    const int bc = blockIdx.x * 32;
    const int br = blockIdx.y * 32;
#pragma unroll
    for (int i = 0; i < 32; i += 8) {
        const size_t idx = (size_t)(br + ty + i) * ils + bc + tx;
        tile[ty + i][tx] = f32 ? __float2bfloat16(((const float*)in)[idx])
                               : ((const bf16*)in)[idx];
    }
    __syncthreads();
#pragma unroll
    for (int i = 0; i < 32; i += 8)
        out[(size_t)(bc + ty + i) * R + br + tx] = tile[tx][ty + i];
}

// ---------------------------------------------------------------------------
// Quantizing transpose: out[C,R] = e4m3(in[R,C]^T * vs).
// ---------------------------------------------------------------------------
__global__ __launch_bounds__(256) void transpose_q8(
    const bf16* __restrict__ in, int ils, unsigned char* __restrict__ out,
    int R, int C, float vs)
{
    __shared__ float tile[32][33];
    const int tx = threadIdx.x & 31;
    const int ty = threadIdx.x >> 5;
    const int bc = blockIdx.x * 32;
    const int br = blockIdx.y * 32;
#pragma unroll
    for (int i = 0; i < 32; i += 8)
        tile[ty + i][tx] =
            __bfloat162float(in[(size_t)(br + ty + i) * ils + bc + tx]) * vs;
    __syncthreads();
#pragma unroll
    for (int i = 0; i < 32; i += 8)
        out[(size_t)(bc + ty + i) * R + br + tx] = f2e4m3(tile[tx][ty + i]);
}

// ---------------------------------------------------------------------------
// Byte transpose (for mutual8 -> mutual8T). R,C multiples of 64.
// ---------------------------------------------------------------------------
__global__ __launch_bounds__(256) void transpose_b8(
    const unsigned char* __restrict__ in, unsigned char* __restrict__ out,
    int R, int C)
{
    __align__(16) __shared__ unsigned char tile[64][80];
    const int t  = threadIdx.x;
    const int r  = t & 63;
    const int cq = t >> 6;                 // 0..3, 16B chunk
    const int br = blockIdx.y * 64;
    const int bc = blockIdx.x * 64;
    *(i32x4*)&tile[r][cq * 16] =
        *(const i32x4*)(in + (size_t)(br + r) * C + bc + cq * 16);
    __syncthreads();
    unsigned char v[16];
#pragma unroll
    for (int j = 0; j < 16; ++j) v[j] = tile[cq * 16 + j][r];
    *(i32x4*)(out + (size_t)(bc + r) * R + br + cq * 16) = *(i32x4*)v;
}

// ---------------------------------------------------------------------------
// Generic bf16 C = A * B^T GEMM (m97 structure). A:[M,K] lda, B:[N,K] ldb.
// BM=64 variant gives 2x the blocks (2/CU) for latency-bound small GEMMs.
// ---------------------------------------------------------------------------
template <int BM, int BN, bool BIAS, bool ADDC0, bool RELU, bool F32OUT>
__global__ __launch_bounds__(256) void gemm_bt(
    const bf16* __restrict__ A, int lda,
    const bf16* __restrict__ B, int ldb,
    void* __restrict__ Cout, int ldc,
    const bf16* __restrict__ C0, int ldc0,
    const bf16* __restrict__ bias,
    int K, float scale)
{
    constexpr int WM = BM / 2;
    constexpr int WN = BN / 2;
    constexpr int TM = WM / 16;
    constexpr int TN = WN / 16;

    __align__(16) __shared__ bf16 As[BM * 32];
    __align__(16) __shared__ bf16 Bs[BN * 32];

    const int tid  = threadIdx.x;
    const int lane = tid & 63;
    const int wv   = tid >> 6;
    const int m_base = blockIdx.y * BM;
    const int n_base = blockIdx.x * BN;

    const int wm0 = (wv >> 1) * WM;
    const int wn0 = (wv & 1) * WN;

    floatx4 zero = {0.f, 0.f, 0.f, 0.f};
    floatx4 acc[TM][TN];
#pragma unroll
    for (int mt = 0; mt < TM; ++mt)
#pragma unroll
        for (int nt = 0; nt < TN; ++nt) acc[mt][nt] = zero;

    const int ar = lane >> 2;
    const int ac = (lane & 3) * 8;
    const int fr = lane & 15;
    const int fk = (lane >> 4) * 8;

    for (int k0 = 0; k0 < K; k0 += 32) {
#pragma unroll
        for (int cc = 0; cc < BM / 64; ++cc) {
            const int r0t = (wv + cc * 4) * 16;
            async16(A + (size_t)(m_base + r0t + ar) * lda + k0 + ac, &As[r0t * 32]);
        }
#pragma unroll
        for (int cc = 0; cc < BN / 64; ++cc) {
            const int r0t = (wv + cc * 4) * 16;
            async16(B + (size_t)(n_base + r0t + ar) * ldb + k0 + ac, &Bs[r0t * 32]);
        }
        __syncthreads();

        short8 af[TM], bfrag[TN];
#pragma unroll
        for (int mt = 0; mt < TM; ++mt)
            af[mt] = *(const short8*)&As[(wm0 + mt * 16 + fr) * 32 + fk];
#pragma unroll
        for (int nt = 0; nt < TN; ++nt)
            bfrag[nt] = *(const short8*)&Bs[(wn0 + nt * 16 + fr) * 32 + fk];
#pragma unroll
        for (int mt = 0; mt < TM; ++mt)
#pragma unroll
            for (int nt = 0; nt < TN; ++nt)
                acc[mt][nt] = __builtin_amdgcn_mfma_f32_16x16x32_bf16(
                    af[mt], bfrag[nt], acc[mt][nt], 0, 0, 0);
        __syncthreads();
    }

    const int er = lane >> 4;
    const int ec = lane & 15;
#pragma unroll
    for (int nt = 0; nt < TN; ++nt) {
        const int col = n_base + wn0 + nt * 16 + ec;
        float bv = 0.f;
        if constexpr (BIAS) bv = __bfloat162float(bias[col]);
#pragma unroll
        for (int mt = 0; mt < TM; ++mt) {
#pragma unroll
            for (int r = 0; r < 4; ++r) {
                const int row = m_base + wm0 + mt * 16 + er * 4 + r;
                float v = acc[mt][nt][r] * scale + bv;
                if constexpr (ADDC0) v += __bfloat162float(C0[(size_t)row * ldc0 + col]);
                if constexpr (RELU) v = fmaxf(v, 0.f);
                if constexpr (F32OUT)
                    ((float*)Cout)[(size_t)row * ldc + col] = v;
                else
                    ((bf16*)Cout)[(size_t)row * ldc + col] = __float2bfloat16(v);
            }
        }
    }
}

// ---------------------------------------------------------------------------
// fp8 C = A * B^T GEMM, BK=64, mfma_f32_16x16x32_fp8_fp8 (ctx GEMMs).
// XOR-swizzled LDS (round-4). a_kshift: per-n-block byte shift of A.
// ---------------------------------------------------------------------------
template <int BM, int BN, bool RELU>
__global__ __launch_bounds__(256) void gemm_bt8(
    const unsigned char* __restrict__ A, int lda, long long a_kshift,
    const unsigned char* __restrict__ B, int ldb,
    bf16* __restrict__ C, int ldc,
    int K, float scale)
{
    constexpr int WM = BM / 2;
    constexpr int WN = BN / 2;
    constexpr int TM = WM / 16;
    constexpr int TN = WN / 16;

    __align__(16) __shared__ unsigned char As[BM * 64];
    __align__(16) __shared__ unsigned char Bs[BN * 64];

    const int tid  = threadIdx.x;
    const int lane = tid & 63;
    const int wv   = tid >> 6;
    const int m_base = blockIdx.y * BM;
    const int n_base = blockIdx.x * BN;
    A += (long long)blockIdx.x * a_kshift;

    const int wm0 = (wv >> 1) * WM;
    const int wn0 = (wv & 1) * WN;

    floatx4 zero = {0.f, 0.f, 0.f, 0.f};
    floatx4 acc[TM][TN];
#pragma unroll
    for (int mt = 0; mt < TM; ++mt)
#pragma unroll
        for (int nt = 0; nt < TN; ++nt) acc[mt][nt] = zero;

    const int ar = lane >> 2;
    const int ac = (((lane & 3) ^ (ar & 3)) * 16);
    const int fr = lane & 15;
    const int q  = lane >> 4;
    const int sw = fr & 3;

    for (int k0 = 0; k0 < K; k0 += 64) {
#pragma unroll
        for (int cc = 0; cc < BM / 16; cc += 4) {
            const int r0t = (wv + cc) * 16;
            async16(A + (size_t)(m_base + r0t + ar) * lda + k0 + ac, &As[r0t * 64]);
        }
#pragma unroll
        for (int cc = 0; cc < BN / 16; cc += 4) {
            const int r0t = (wv + cc) * 16;
            async16(B + (size_t)(n_base + r0t + ar) * ldb + k0 + ac, &Bs[r0t * 64]);
        }
        __syncthreads();

#pragma unroll
        for (int s = 0; s < 2; ++s) {
            const int boff = (((s * 2 + (q >> 1)) ^ sw) * 16) + (q & 1) * 8;
            long af[TM], bfr[TN];
#pragma unroll
            for (int mt = 0; mt < TM; ++mt)
                af[mt] = *(const long*)&As[(wm0 + mt * 16 + fr) * 64 + boff];
#pragma unroll
            for (int nt = 0; nt < TN; ++nt)
                bfr[nt] = *(const long*)&Bs[(wn0 + nt * 16 + fr) * 64 + boff];
#pragma unroll
            for (int mt = 0; mt < TM; ++mt)
#pragma unroll
                for (int nt = 0; nt < TN; ++nt)
                    acc[mt][nt] = __builtin_amdgcn_mfma_f32_16x16x32_fp8_fp8(
                        af[mt], bfr[nt], acc[mt][nt], 0, 0, 0);
        }
        __syncthreads();
    }

    const int er = lane >> 4;
    const int ec = lane & 15;
#pragma unroll
    for (int nt = 0; nt < TN; ++nt) {
        const int col = n_base + wn0 + nt * 16 + ec;
#pragma unroll
        for (int mt = 0; mt < TM; ++mt) {
#pragma unroll
            for (int r = 0; r < 4; ++r) {
                const int row = m_base + wm0 + mt * 16 + er * 4 + r;
                float v = acc[mt][nt][r] * scale;
                if constexpr (RELU) v = fmaxf(v, 0.f);
                C[(size_t)row * ldc + col] = __float2bfloat16(v);
            }
        }
    }
}

// ---------------------------------------------------------------------------
// MX-scaled fp8 C = A * B^T GEMM, BK=128, mfma_scale_f32_16x16x128_f8f6f4
// with unit e8m0 scales (127) => plain fp8 GEMM at 2x rate.
// FP8OUT: write e4m3(acc*scale); ADDC0: add bf16 C0 before store.
// ---------------------------------------------------------------------------
template <int BM, int BN, bool ADDC0, bool FP8OUT>
__global__ __launch_bounds__(256) void gemm_bt8mx(
    const unsigned char* __restrict__ A, int lda,
    const unsigned char* __restrict__ B, int ldb,
    void* __restrict__ Cout, int ldc,
    const bf16* __restrict__ C0, int ldc0,
    int K, float scale)
{
    constexpr int WM = BM / 2;
    constexpr int WN = BN / 2;
    constexpr int TM = WM / 16;
    constexpr int TN = WN / 16;

    __align__(16) __shared__ unsigned char As[BM * 128];
    __align__(16) __shared__ unsigned char Bs[BN * 128];

    const int tid  = threadIdx.x;
    const int lane = tid & 63;
    const int wv   = tid >> 6;
    const int m_base = blockIdx.y * BM;
    const int n_base = blockIdx.x * BN;

    const int wm0 = (wv >> 1) * WM;
    const int wn0 = (wv & 1) * WN;

    floatx4 zero = {0.f, 0.f, 0.f, 0.f};
    floatx4 acc[TM][TN];
#pragma unroll
    for (int mt = 0; mt < TM; ++mt)
#pragma unroll
        for (int nt = 0; nt < TN; ++nt) acc[mt][nt] = zero;

    const int sr = lane >> 3;                    // staging row within 8-row group
    const int sc = ((lane & 7) ^ sr) * 16;       // swizzled source chunk
    const int fr = lane & 15;
    const int q  = lane >> 4;                    // k-quarter
    const int sw = fr & 7;

    for (int k0 = 0; k0 < K; k0 += 128) {
#pragma unroll
        for (int cc = 0; cc < BM / 32; ++cc) {
            const int r0t = (wv + cc * 4) * 8;
            async16(A + (size_t)(m_base + r0t + sr) * lda + k0 + sc, &As[r0t * 128]);
        }
#pragma unroll
        for (int cc = 0; cc < BN / 32; ++cc) {
            const int r0t = (wv + cc * 4) * 8;
            async16(B + (size_t)(n_base + r0t + sr) * ldb + k0 + sc, &Bs[r0t * 128]);
        }
        __syncthreads();

        i32x8 af[TM], bf8[TN];
#pragma unroll
        for (int mt = 0; mt < TM; ++mt) {
            const unsigned char* rp = &As[(wm0 + mt * 16 + fr) * 128];
            i32x4 lo = *(const i32x4*)(rp + (((q * 2 + 0) ^ sw) * 16));
            i32x4 hi = *(const i32x4*)(rp + (((q * 2 + 1) ^ sw) * 16));
            af[mt] = __builtin_shufflevector(lo, hi, 0, 1, 2, 3, 4, 5, 6, 7);
        }
#pragma unroll
        for (int nt = 0; nt < TN; ++nt) {
            const unsigned char* rp = &Bs[(wn0 + nt * 16 + fr) * 128];
            i32x4 lo = *(const i32x4*)(rp + (((q * 2 + 0) ^ sw) * 16));
            i32x4 hi = *(const i32x4*)(rp + (((q * 2 + 1) ^ sw) * 16));
            bf8[nt] = __builtin_shufflevector(lo, hi, 0, 1, 2, 3, 4, 5, 6, 7);
        }
#pragma unroll
        for (int mt = 0; mt < TM; ++mt)
#pragma unroll
            for (int nt = 0; nt < TN; ++nt)
                acc[mt][nt] = __builtin_amdgcn_mfma_scale_f32_16x16x128_f8f6f4(
                    af[mt], bf8[nt], acc[mt][nt],
                    0, 0, 0, 127, 0, 127);
        __syncthreads();
    }

    const int er = lane >> 4;
    const int ec = lane & 15;
#pragma unroll
    for (int nt = 0; nt < TN; ++nt) {
        const int col = n_base + wn0 + nt * 16 + ec;
#pragma unroll
        for (int mt = 0; mt < TM; ++mt) {
#pragma unroll
            for (int r = 0; r < 4; ++r) {
                const int row = m_base + wm0 + mt * 16 + er * 4 + r;
                float v = acc[mt][nt][r] * scale;
                if constexpr (ADDC0) v += __bfloat162float(C0[(size_t)row * ldc0 + col]);
                if constexpr (FP8OUT)
                    ((unsigned char*)Cout)[(size_t)row * ldc + col] = f2e4m3(v);
                else
                    ((bf16*)Cout)[(size_t)row * ldc + col] = __float2bfloat16(v);
            }
        }
    }
}

// ---------------------------------------------------------------------------
// MFMA fused scores + mask + softmax. Block = 16 Q-rows x 1024 cols, 1 head.
// Output: aw8 = e4m3(softmax * 32) at [row, h*1024 + col].
// ---------------------------------------------------------------------------
__global__ __launch_bounds__(256) void scores_mfma(
    const bf16* __restrict__ Q,          // [Nq, 512]
    const bf16* __restrict__ Kbase,      // [1024, ldk] (head cols at h*64)
    int ldk,
    const int* __restrict__ mask,        // [Nq, 1024]
    unsigned char* __restrict__ aw8,     // [Nq, 8192]
    float scale)
{
    __shared__ float wred[16][4];
    __shared__ float wsum[16][4];

    const int t    = threadIdx.x;
    const int lane = t & 63;
    const int w    = t >> 6;
    const int h    = blockIdx.y;
    const int r0   = blockIdx.x * 16;
    const int fr   = lane & 15;
    const int fq   = lane >> 4;
    const int cbase = w * 256;

    const short* Qs = (const short*)Q + (size_t)(r0 + fr) * 512 + h * 64 + fq * 8;
    short8 a0 = *(const short8*)(Qs);
    short8 a1 = *(const short8*)(Qs + 32);

    floatx4 accs[16];
    const short* Kb = (const short*)Kbase + h * 64 + fq * 8;
#pragma unroll
    for (int c = 0; c < 16; ++c) {
        const int krow = cbase + c * 16 + fr;
        short8 b0 = *(const short8*)(Kb + (size_t)krow * ldk);
        short8 b1 = *(const short8*)(Kb + (size_t)krow * ldk + 32);
        floatx4 acc = {0.f, 0.f, 0.f, 0.f};
        acc = __builtin_amdgcn_mfma_f32_16x16x32_bf16(a0, b0, acc, 0, 0, 0);
        acc = __builtin_amdgcn_mfma_f32_16x16x32_bf16(a1, b1, acc, 0, 0, 0);
        accs[c] = acc;
    }

    float mxr[4] = {-3e38f, -3e38f, -3e38f, -3e38f};
#pragma unroll
    for (int c = 0; c < 16; ++c) {
        const int col = cbase + c * 16 + fr;
#pragma unroll
        for (int r = 0; r < 4; ++r) {
            const int row = r0 + fq * 4 + r;
            float v = (mask[(size_t)row * 1024 + col] == 0) ? -1e9f
                                                            : accs[c][r] * scale;
            accs[c][r] = v;
            mxr[r] = fmaxf(mxr[r], v);
        }
    }
#pragma unroll
    for (int o = 1; o < 16; o <<= 1)
#pragma unroll
        for (int r = 0; r < 4; ++r) mxr[r] = fmaxf(mxr[r], __shfl_xor(mxr[r], o));
    if (fr == 0)
#pragma unroll
        for (int r = 0; r < 4; ++r) wred[fq * 4 + r][w] = mxr[r];
    __syncthreads();

    float mx[4], sm[4] = {0.f, 0.f, 0.f, 0.f};
#pragma unroll
    for (int r = 0; r < 4; ++r) {
        const int row = fq * 4 + r;
        mx[r] = fmaxf(fmaxf(wred[row][0], wred[row][1]),
                      fmaxf(wred[row][2], wred[row][3]));
    }
#pragma unroll
    for (int c = 0; c < 16; ++c)
#pragma unroll
        for (int r = 0; r < 4; ++r) {
            float e = __expf(accs[c][r] - mx[r]);
            accs[c][r] = e;
            sm[r] += e;
        }
#pragma unroll
    for (int o = 1; o < 16; o <<= 1)
#pragma unroll
        for (int r = 0; r < 4; ++r) sm[r] += __shfl_xor(sm[r], o);
    if (fr == 0)
#pragma unroll
        for (int r = 0; r < 4; ++r) wsum[fq * 4 + r][w] = sm[r];
    __syncthreads();

    float inv[4];
#pragma unroll
    for (int r = 0; r < 4; ++r) {
        const int row = fq * 4 + r;
        inv[r] = 32.0f / (wsum[row][0] + wsum[row][1] + wsum[row][2] + wsum[row][3]);
    }
#pragma unroll
    for (int c = 0; c < 16; ++c) {
        const int col = cbase + c * 16 + fr;
#pragma unroll
        for (int r = 0; r < 4; ++r) {
            const int row = r0 + fq * 4 + r;
            aw8[(size_t)row * 8192 + h * 1024 + col] = f2e4m3(accs[c][r] * inv[r]);
        }
    }
}

// ---------------------------------------------------------------------------
// LayerNorm over 256 cols, fp32 in -> bf16/fp32 out per flag. 4 rows/block.
// ---------------------------------------------------------------------------
__global__ __launch_bounds__(256) void ln_rows(
    const float* __restrict__ X, const bf16* __restrict__ g,
    const bf16* __restrict__ b, void* __restrict__ out, size_t row0, int rows,
    const int* __restrict__ flag)
{
    const bool f32 = (*flag != 0);
    const int lane = threadIdx.x & 63;
    const int wv   = threadIdx.x >> 6;
    const int row  = blockIdx.x * 4 + wv;
    if (row >= rows) return;
    const float* x = X + (size_t)row * 256;
    float v[4], s = 0.f, s2 = 0.f;
#pragma unroll
    for (int i = 0; i < 4; ++i) {
        v[i] = x[lane + 64 * i];
        s += v[i]; s2 += v[i] * v[i];
    }
#pragma unroll
    for (int o = 1; o < 64; o <<= 1) { s += __shfl_xor(s, o); s2 += __shfl_xor(s2, o); }
    const float mu  = s * (1.0f / 256.0f);
    const float var = fmaxf(s2 * (1.0f / 256.0f) - mu * mu, 0.0f);
    const float inv = rsqrtf(var + 1e-5f);
#pragma unroll
    for (int i = 0; i < 4; ++i) {
        const int c = lane + 64 * i;
        const float y = (v[i] - mu) * inv * __bfloat162float(g[c]) + __bfloat162float(b[c]);
        if (f32) ((float*)out)[(row0 + row) * 256 + c] = y;
        else     ((bf16*)out)[(row0 + row) * 256 + c] = __float2bfloat16(y);
    }
}

// ---------------------------------------------------------------------------
extern "C" void kernel_launch(void* const* d_in, const int* in_sizes, int n_in,
                              void* d_out, int out_size, void* d_ws, size_t ws_size,
                              hipStream_t stream)
{
    const int L = 4096, Mm = 1024, P = 4096;

    const int* mask_l = (const int*)d_in[3];
    const int* mask_p = (const int*)d_in[4];

    char* ws = (char*)d_ws;
    size_t off = 0;
    auto alloc = [&](size_t bytes) {
        void* p = ws + off; off += (bytes + 255) & ~(size_t)255; return p;
    };

    int*  flag   = (int*)alloc(256);
    // weight slots: 0:Wl 1:Wm 2:Wp 3:Wql 4:Wqp 5:Wkl 6:Wvl 7:Wkp 8:Wvp
    bf16* wt_all = (bf16*)alloc((size_t)9 * 512 * 512 * 2);
    bf16* WmlT   = (bf16*)alloc(1024 * 256 * 2);
    bf16* WmpT   = (bf16*)alloc(1024 * 256 * 2);
    bf16* b_l    = (bf16*)alloc(512 * 2);
    bf16* b_m    = (bf16*)alloc(512 * 2);
    bf16* b_p    = (bf16*)alloc(512 * 2);
    bf16* b_ql   = (bf16*)alloc(512 * 2);
    bf16* b_qp   = (bf16*)alloc(512 * 2);
    bf16* bcat   = (bf16*)alloc(2048 * 2);     // [bkl|bvl|bkp|bvp]
    bf16* bml_c  = (bf16*)alloc(256 * 2);
    bf16* bmp_c  = (bf16*)alloc(256 * 2);
    bf16* g1c    = (bf16*)alloc(256 * 2);
    bf16* be1c   = (bf16*)alloc(256 * 2);
    bf16* g2c    = (bf16*)alloc(256 * 2);
    bf16* be2c   = (bf16*)alloc(256 * 2);
    bf16* embl   = (bf16*)alloc((size_t)L * 512 * 2);
    bf16* embm   = (bf16*)alloc((size_t)Mm * 512 * 2);
    bf16* embp   = (bf16*)alloc((size_t)P * 512 * 2);
    bf16* cat_l  = (bf16*)alloc((size_t)L * 1024 * 2);   // [lt | fin_l]
    bf16* cat_p  = (bf16*)alloc((size_t)P * 1024 * 2);   // [fin_p | pt]
    bf16* mt     = (bf16*)alloc((size_t)Mm * 512 * 2);
    bf16* Ql     = (bf16*)alloc((size_t)L * 512 * 2);
    bf16* Qp     = (bf16*)alloc((size_t)P * 512 * 2);
    bf16* kvcat  = (bf16*)alloc((size_t)Mm * 2048 * 2);  // [Kl|Vl|Kp|Vp]
    unsigned char* V8lT = (unsigned char*)alloc((size_t)512 * Mm);
    unsigned char* V8pT = (unsigned char*)alloc((size_t)512 * Mm);
    bf16* ctx_l  = (bf16*)alloc((size_t)L * 512 * 2);
    bf16* ctx_p  = (bf16*)alloc((size_t)P * 512 * 2);
    unsigned char* ctx8lT = (unsigned char*)alloc((size_t)512 * L);
    unsigned char* ctx8pT = (unsigned char*)alloc((size_t)512 * P);
    unsigned char* mutual8 = (unsigned char*)alloc((size_t)L * P);
    unsigned char* awl8 = (unsigned char*)alloc((size_t)L * 8192);
    unsigned char* awp8 = (unsigned char*)alloc((size_t)P * 8192);
    // overlays: awl8/awp8 dead after the mutual GEMM
    unsigned char* mutual8T = awl8;
    float* tmp1 = (float*)awp8;
    float* tmp2 = (float*)awp8 + (size_t)L * 256;

    // 0. dtype sniff + canonicalize
    sniff_dtype<<<1, 64, 0, stream>>>((const unsigned short*)d_in[0], flag);

    CvtTable tab;
    tab.e[0]  = { d_in[0],  embl, L * 512 };
    tab.e[1]  = { d_in[1],  embm, Mm * 512 };
    tab.e[2]  = { d_in[2],  embp, P * 512 };
    tab.e[3]  = { d_in[6],  b_l,  512 };
    tab.e[4]  = { d_in[8],  b_m,  512 };
    tab.e[5]  = { d_in[10], b_p,  512 };
    tab.e[6]  = { d_in[12], b_ql, 512 };
    tab.e[7]  = { d_in[18], b_qp, 512 };
    tab.e[8]  = { d_in[14], bcat,        512 };   // bkl
    tab.e[9]  = { d_in[16], bcat + 512,  512 };   // bvl
    tab.e[10] = { d_in[20], bcat + 1024, 512 };   // bkp
    tab.e[11] = { d_in[22], bcat + 1536, 512 };   // bvp
    tab.e[12] = { d_in[24], bml_c, 256 };
    tab.e[13] = { d_in[26], bmp_c, 256 };
    tab.e[14] = { d_in[27], g1c,  256 };
    tab.e[15] = { d_in[28], be1c, 256 };
    tab.e[16] = { d_in[29], g2c,  256 };
    tab.e[17] = { d_in[30], be2c, 256 };
    convert_inputs<<<dim3(256, 18), 256, 0, stream>>>(tab, flag);

    // 1. weight transposes
    TT9 tt;
    const int slot_of[9] = {0, 1, 2, 3, 5, 6, 4, 7, 8};  // input order -> slot
    for (int i = 0; i < 9; ++i) {
        tt.src[i] = d_in[5 + 2 * i];
        tt.dst[i] = wt_all + (size_t)slot_of[i] * 512 * 512;
    }
    transpose_sq9<<<dim3(16, 16, 9), 256, 0, stream>>>(tt, flag);
    transpose_any_ld<<<dim3(8, 32), 256, 0, stream>>>(d_in[23], 256, WmlT, 1024, 256, flag);
    transpose_any_ld<<<dim3(8, 32), 256, 0, stream>>>(d_in[25], 256, WmpT, 1024, 256, flag);

    bf16* WlT  = wt_all;
    bf16* WmT  = wt_all + (size_t)1 * 512 * 512;
    bf16* WpT  = wt_all + (size_t)2 * 512 * 512;
    bf16* WqlT = wt_all + (size_t)3 * 512 * 512;
    bf16* WqpT = wt_all + (size_t)4 * 512 * 512;
    bf16* WkvT = wt_all + (size_t)5 * 512 * 512;  // [2048, 512]

    // 2. input projections (BM=64 -> 2 blocks/CU)
    gemm_bt<64, 64, true, false, false, false><<<dim3(8, 64), 256, 0, stream>>>(
        embl, 512, WlT, 512, cat_l, 1024, nullptr, 0, b_l, 512, 1.0f);
    gemm_bt<64, 64, true, false, false, false><<<dim3(8, 16), 256, 0, stream>>>(
        embm, 512, WmT, 512, mt, 512, nullptr, 0, b_m, 512, 1.0f);
    gemm_bt<64, 64, true, false, false, false><<<dim3(8, 64), 256, 0, stream>>>(
        embp, 512, WpT, 512, cat_p + 512, 1024, nullptr, 0, b_p, 512, 1.0f);

    // 3. Q projections + fused K/V projection
    gemm_bt<64, 64, true, false, false, false><<<dim3(8, 64), 256, 0, stream>>>(
        cat_l, 1024, WqlT, 512, Ql, 512, nullptr, 0, b_ql, 512, 1.0f);
    gemm_bt<64, 64, true, false, false, false><<<dim3(8, 64), 256, 0, stream>>>(
        cat_p + 512, 1024, WqpT, 512, Qp, 512, nullptr, 0, b_qp, 512, 1.0f);
    gemm_bt<64, 64, true, false, false, false><<<dim3(32, 16), 256, 0, stream>>>(
        mt, 512, WkvT, 512, kvcat, 2048, nullptr, 0, bcat, 512, 1.0f);

    // V8T = e4m3(V^T * 4)
    transpose_q8<<<dim3(16, 32), 256, 0, stream>>>(kvcat + 512,  2048, V8lT, 1024, 512, 4.0f);
    transpose_q8<<<dim3(16, 32), 256, 0, stream>>>(kvcat + 1536, 2048, V8pT, 1024, 512, 4.0f);

    // 4. fused MFMA scores + mask + softmax -> aw8 (= softmax * 32 in e4m3)
    scores_mfma<<<dim3(256, 8), 256, 0, stream>>>(Ql, kvcat,        2048, mask_l, awl8, 0.125f);
    scores_mfma<<<dim3(256, 8), 256, 0, stream>>>(Qp, kvcat + 1024, 2048, mask_p, awp8, 0.125f);

    // 5. ctx = relu(aw @ V) per head (fp8), scale 1/(32*4); BM=64 -> 512 blocks
    gemm_bt8<64, 64, true><<<dim3(8, 64), 256, 0, stream>>>(
        awl8, 8192, 1024, V8lT, 1024, ctx_l, 512, 1024, 1.0f / 128.0f);
    gemm_bt8<64, 64, true><<<dim3(8, 64), 256, 0, stream>>>(
        awp8, 8192, 1024, V8pT, 1024, ctx_p, 512, 1024, 1.0f / 128.0f);

    // ctx8T = e4m3(ctx^T * 16) for the fp8 fin GEMMs
    transpose_q8<<<dim3(16, 128), 256, 0, stream>>>(ctx_l, 512, ctx8lT, 4096, 512, 16.0f);
    transpose_q8<<<dim3(16, 128), 256, 0, stream>>>(ctx_p, 512, ctx8pT, 4096, 512, 16.0f);

    // 6. mutual8 = e4m3( (awl @ awp^T)/8 * 256 )  (MX fp8, BK=128)
    //    acc*0.125/1024 = mutual; *256 for fp8 range -> scale 0.03125
    gemm_bt8mx<128, 128, false, true><<<dim3(32, 32), 256, 0, stream>>>(
        awl8, 8192, awp8, 8192, mutual8, 4096, nullptr, 0, 8192, 0.03125f);
    // awl8/awp8 dead: overlays live
    transpose_b8<<<dim3(64, 64), 256, 0, stream>>>(mutual8, mutual8T, 4096, 4096);

    // 7. fin (MX fp8, K=4096): scale 1/(256*16) per K-term -> 1/4096
    gemm_bt8mx<64, 64, true, false><<<dim3(8, 64), 256, 0, stream>>>(
        mutual8, 4096, ctx8pT, 4096, cat_l + 512, 1024, ctx_l, 512, 4096, 1.0f / 4096.0f);
    gemm_bt8mx<64, 64, true, false><<<dim3(8, 64), 256, 0, stream>>>(
        mutual8T, 4096, ctx8lT, 4096, cat_p, 1024, ctx_p, 512, 4096, 1.0f / 4096.0f);

    // 8. final projections (fp32) + LayerNorm -> d_out
    gemm_bt<64, 64, true, false, false, true><<<dim3(4, 64), 256, 0, stream>>>(
        cat_l, 1024, WmlT, 1024, tmp1, 256, nullptr, 0, bml_c, 1024, 1.0f);
    gemm_bt<64, 64, true, false, false, true><<<dim3(4, 64), 256, 0, stream>>>(
        cat_p, 1024, WmpT, 1024, tmp2, 256, nullptr, 0, bmp_c, 1024, 1.0f);

    ln_rows<<<dim3(1024), 256, 0, stream>>>(tmp1, g1c, be1c, d_out, 0, L, flag);
    ln_rows<<<dim3(1024), 256, 0, stream>>>(tmp2, g2c, be2c, d_out, (size_t)L, P, flag);
}

// Round 7
// 563.881 us; speedup vs baseline: 2.4691x; 1.1119x over previous
//
#include <hip/hip_runtime.h>
#include <hip/hip_bf16.h>

using bf16 = __hip_bfloat16;
typedef __attribute__((ext_vector_type(8))) short short8;
typedef __attribute__((ext_vector_type(4))) float floatx4;
typedef __attribute__((ext_vector_type(8))) unsigned short ushort8;
typedef __attribute__((ext_vector_type(4))) int i32x4;
typedef __attribute__((ext_vector_type(8))) int i32x8;

__device__ __forceinline__ float b2f(unsigned short u) {
    union { unsigned int i; float f; } x; x.i = ((unsigned int)u) << 16; return x.f;
}

__device__ __forceinline__ void async16(const void* g, void* l) {
    __builtin_amdgcn_global_load_lds((const __attribute__((address_space(1))) void*)g,
                                     (__attribute__((address_space(3))) void*)l,
                                     16, 0, 0);
}

// float -> OCP e4m3fn, RNE, signed, |f| clamped to 448.
__device__ __forceinline__ unsigned char f2e4m3(float f) {
    unsigned s = (__float_as_uint(f) >> 24) & 0x80u;
    f = fminf(fabsf(f), 448.f);
    if (f < 0.015625f) {
        int d = (int)rintf(f * 512.f);
        return (unsigned char)(s | (unsigned)d);
    }
    int E = (int)((__float_as_uint(f) >> 23) & 255u) - 127;
    float ulp_inv = __uint_as_float((unsigned)(127 + 3 - E) << 23);
    int m = (int)rintf(f * ulp_inv);
    int n = (m == 16) ? ((E + 8) << 3) : (((E + 7) << 3) + (m - 8));
    if (n > 0x7E) n = 0x7E;
    return (unsigned char)(s | (unsigned)n);
}

// ---------------------------------------------------------------------------
__global__ void sniff_dtype(const unsigned short* p, int* flag) {
    int wild = 0;
    for (int i = threadIdx.x; i < 256; i += 64) {
        float a = fabsf(b2f(p[i]));
        if (!(a <= 1e4f)) wild++;
    }
#pragma unroll
    for (int o = 1; o < 64; o <<= 1) wild += __shfl_xor(wild, o);
    if (threadIdx.x == 0) *flag = (wild > 16) ? 1 : 0;
}

// ---------------------------------------------------------------------------
struct Cvt { const void* src; bf16* dst; int n; };
struct CvtTable { Cvt e[18]; };

__global__ __launch_bounds__(256) void convert_inputs(CvtTable t, const int* flag) {
    const Cvt c = t.e[blockIdx.y];
    const bool f32 = (*flag != 0);
    const int stride = gridDim.x * 256 * 8;
    for (int i = (blockIdx.x * 256 + threadIdx.x) * 8; i < c.n; i += stride) {
        if (f32) {
            const float* s = (const float*)c.src + i;
#pragma unroll
            for (int j = 0; j < 8; ++j) c.dst[i + j] = __float2bfloat16(s[j]);
        } else {
            *(ushort8*)((unsigned short*)c.dst + i) =
                *(const ushort8*)((const unsigned short*)c.src + i);
        }
    }
}

// ---------------------------------------------------------------------------
struct TT9 { const void* src[9]; bf16* dst[9]; };

__global__ __launch_bounds__(256) void transpose_sq9(TT9 t, const int* flag) {
    __shared__ bf16 tile[32][33];
    const void* in = t.src[blockIdx.z];
    bf16* out = t.dst[blockIdx.z];
    const bool f32 = (*flag != 0);
    const int tx = threadIdx.x & 31;
    const int ty = threadIdx.x >> 5;
    const int bc = blockIdx.x * 32;
    const int br = blockIdx.y * 32;
#pragma unroll
    for (int i = 0; i < 32; i += 8) {
        const size_t idx = (size_t)(br + ty + i) * 512 + bc + tx;
        tile[ty + i][tx] = f32 ? __float2bfloat16(((const float*)in)[idx])
                               : ((const bf16*)in)[idx];
    }
    __syncthreads();
#pragma unroll
    for (int i = 0; i < 32; i += 8)
        out[(size_t)(bc + ty + i) * 512 + br + tx] = tile[tx][ty + i];
}

// ---------------------------------------------------------------------------
// Dtype-aware rectangular transpose pair (Wml/Wmp). out[C,R] = in[R,C]^T.
// ---------------------------------------------------------------------------
struct TaPair { const void* in[2]; bf16* out[2]; };

__global__ __launch_bounds__(256) void transpose_any_pair(
    TaPair P, int ils, int R, int C, const int* __restrict__ flag)
{
    __shared__ bf16 tile[32][33];
    const void* in = P.in[blockIdx.z];
    bf16* out = P.out[blockIdx.z];
    const bool f32 = (*flag != 0);
    const int tx = threadIdx.x & 31;
    const int ty = threadIdx.x >> 5;
    const int bc = blockIdx.x * 32;
    const int br = blockIdx.y * 32;
#pragma unroll
    for (int i = 0; i < 32; i += 8) {
        const size_t idx = (size_t)(br + ty + i) * ils + bc + tx;
        tile[ty + i][tx] = f32 ? __float2bfloat16(((const float*)in)[idx])
                               : ((const bf16*)in)[idx];
    }
    __syncthreads();
#pragma unroll
    for (int i = 0; i < 32; i += 8)
        out[(size_t)(bc + ty + i) * R + br + tx] = tile[tx][ty + i];
}

// ---------------------------------------------------------------------------
// Quantizing transpose pair: out[C,R] = e4m3(in[R,C]^T * vs).
// ---------------------------------------------------------------------------
struct TqPair { const bf16* in[2]; unsigned char* out[2]; };

__global__ __launch_bounds__(256) void transpose_q8_pair(
    TqPair P, int ils, int R, int C, float vs)
{
    __shared__ float tile[32][33];
    const bf16* in = P.in[blockIdx.z];
    unsigned char* out = P.out[blockIdx.z];
    const int tx = threadIdx.x & 31;
    const int ty = threadIdx.x >> 5;
    const int bc = blockIdx.x * 32;
    const int br = blockIdx.y * 32;
#pragma unroll
    for (int i = 0; i < 32; i += 8)
        tile[ty + i][tx] =
            __bfloat162float(in[(size_t)(br + ty + i) * ils + bc + tx]) * vs;
    __syncthreads();
#pragma unroll
    for (int i = 0; i < 32; i += 8)
        out[(size_t)(bc + ty + i) * R + br + tx] = f2e4m3(tile[tx][ty + i]);
}

// ---------------------------------------------------------------------------
// Byte transpose (mutual8 -> mutual8T).
// ---------------------------------------------------------------------------
__global__ __launch_bounds__(256) void transpose_b8(
    const unsigned char* __restrict__ in, unsigned char* __restrict__ out,
    int R, int C)
{
    __align__(16) __shared__ unsigned char tile[64][80];
    const int t  = threadIdx.x;
    const int r  = t & 63;
    const int cq = t >> 6;
    const int br = blockIdx.y * 64;
    const int bc = blockIdx.x * 64;
    *(i32x4*)&tile[r][cq * 16] =
        *(const i32x4*)(in + (size_t)(br + r) * C + bc + cq * 16);
    __syncthreads();
    unsigned char v[16];
#pragma unroll
    for (int j = 0; j < 16; ++j) v[j] = tile[cq * 16 + j][r];
    *(i32x4*)(out + (size_t)(bc + r) * R + br + cq * 16) = *(i32x4*)v;
}

// ---------------------------------------------------------------------------
// bf16 C = A * B^T GEMM, BK=64 (128B rows, XOR-swizzled LDS like the MX
// kernel: slot = chunk ^ (row&7)). 8 MFMA/barrier at BM=BN=64.
// Pair-capable via blockIdx.z.
// ---------------------------------------------------------------------------
struct BtArgs { const bf16* A; const bf16* B; void* C; const bf16* bias; };
struct BtPair { BtArgs s[2]; };

template <int BM, int BN, bool BIAS, bool F32OUT>
__global__ __launch_bounds__(256) void gemm_bt(
    BtPair P, int lda, int ldb, int ldc, int K, float scale)
{
    constexpr int WM = BM / 2;
    constexpr int WN = BN / 2;
    constexpr int TM = WM / 16;
    constexpr int TN = WN / 16;

    __align__(16) __shared__ bf16 As[BM * 64];
    __align__(16) __shared__ bf16 Bs[BN * 64];

    const BtArgs g = P.s[blockIdx.z];
    const int lane = threadIdx.x & 63;
    const int wv   = threadIdx.x >> 6;
    const int m_base = blockIdx.y * BM;
    const int n_base = blockIdx.x * BN;
    const int wm0 = (wv >> 1) * WM;
    const int wn0 = (wv & 1) * WN;

    floatx4 zero = {0.f, 0.f, 0.f, 0.f};
    floatx4 acc[TM][TN];
#pragma unroll
    for (int mt = 0; mt < TM; ++mt)
#pragma unroll
        for (int nt = 0; nt < TN; ++nt) acc[mt][nt] = zero;

    const int sr  = lane >> 3;                  // row in 8-row staging group
    const int sce = ((lane & 7) ^ sr) * 8;      // swizzled chunk, elements
    const int fr  = lane & 15;
    const int q   = lane >> 4;
    const int sw  = fr & 7;

    for (int k0 = 0; k0 < K; k0 += 64) {
#pragma unroll
        for (int cc = 0; cc < BM / 32; ++cc) {
            const int r0t = (wv + cc * 4) * 8;
            async16(g.A + (size_t)(m_base + r0t + sr) * lda + k0 + sce, &As[r0t * 64]);
        }
#pragma unroll
        for (int cc = 0; cc < BN / 32; ++cc) {
            const int r0t = (wv + cc * 4) * 8;
            async16(g.B + (size_t)(n_base + r0t + sr) * ldb + k0 + sce, &Bs[r0t * 64]);
        }
        __syncthreads();

#pragma unroll
        for (int s = 0; s < 2; ++s) {
            const int off = ((s * 4 + q) ^ sw) * 8;   // element offset in row
            short8 af[TM], bfr[TN];
#pragma unroll
            for (int mt = 0; mt < TM; ++mt)
                af[mt] = *(const short8*)&As[(wm0 + mt * 16 + fr) * 64 + off];
#pragma unroll
            for (int nt = 0; nt < TN; ++nt)
                bfr[nt] = *(const short8*)&Bs[(wn0 + nt * 16 + fr) * 64 + off];
#pragma unroll
            for (int mt = 0; mt < TM; ++mt)
#pragma unroll
                for (int nt = 0; nt < TN; ++nt)
                    acc[mt][nt] = __builtin_amdgcn_mfma_f32_16x16x32_bf16(
                        af[mt], bfr[nt], acc[mt][nt], 0, 0, 0);
        }
        __syncthreads();
    }

    const int er = lane >> 4;
    const int ec = lane & 15;
#pragma unroll
    for (int nt = 0; nt < TN; ++nt) {
        const int col = n_base + wn0 + nt * 16 + ec;
        float bv = 0.f;
        if constexpr (BIAS) bv = __bfloat162float(g.bias[col]);
#pragma unroll
        for (int mt = 0; mt < TM; ++mt) {
#pragma unroll
            for (int r = 0; r < 4; ++r) {
                const int row = m_base + wm0 + mt * 16 + er * 4 + r;
                float v = acc[mt][nt][r] * scale + bv;
                if constexpr (F32OUT)
                    ((float*)g.C)[(size_t)row * ldc + col] = v;
                else
                    ((bf16*)g.C)[(size_t)row * ldc + col] = __float2bfloat16(v);
            }
        }
    }
}

// ---------------------------------------------------------------------------
// Segment-table bf16 GEMM for the 3 embedding projections in one launch.
// A = contiguous [9216, 512]; seg by row: [0,4096) l, [4096,5120) m, rest p.
// ---------------------------------------------------------------------------
struct SegTab { const bf16* W[3]; const bf16* bias[3]; bf16* C[3]; int ldc[3]; int rs[3]; };

__global__ __launch_bounds__(256) void gemm_bt_seg(
    const bf16* __restrict__ A, SegTab T, int K)
{
    constexpr int BM = 64, BN = 64, TM = 2, TN = 2;
    __align__(16) __shared__ bf16 As[BM * 64];
    __align__(16) __shared__ bf16 Bs[BN * 64];

    const int lane = threadIdx.x & 63;
    const int wv   = threadIdx.x >> 6;
    const int gm   = blockIdx.y * BM;                 // global row in [0,9216)
    const int seg  = (gm >= 5120) ? 2 : ((gm >= 4096) ? 1 : 0);
    const bf16* B  = T.W[seg];
    const bf16* bias = T.bias[seg];
    bf16* C        = T.C[seg];
    const int ldc  = T.ldc[seg];
    const int m_base = gm - T.rs[seg];
    const int n_base = blockIdx.x * BN;
    const int wm0 = (wv >> 1) * 32;
    const int wn0 = (wv & 1) * 32;

    floatx4 zero = {0.f, 0.f, 0.f, 0.f};
    floatx4 acc[TM][TN];
#pragma unroll
    for (int mt = 0; mt < TM; ++mt)
#pragma unroll
        for (int nt = 0; nt < TN; ++nt) acc[mt][nt] = zero;

    const int sr  = lane >> 3;
    const int sce = ((lane & 7) ^ sr) * 8;
    const int fr  = lane & 15;
    const int q   = lane >> 4;
    const int sw  = fr & 7;

    for (int k0 = 0; k0 < K; k0 += 64) {
#pragma unroll
        for (int cc = 0; cc < 2; ++cc) {
            const int r0t = (wv + cc * 4) * 8;
            async16(A + (size_t)(gm + r0t + sr) * 512 + k0 + sce, &As[r0t * 64]);
            async16(B + (size_t)(n_base + r0t + sr) * 512 + k0 + sce, &Bs[r0t * 64]);
        }
        __syncthreads();
#pragma unroll
        for (int s = 0; s < 2; ++s) {
            const int off = ((s * 4 + q) ^ sw) * 8;
            short8 af[TM], bfr[TN];
#pragma unroll
            for (int mt = 0; mt < TM; ++mt)
                af[mt] = *(const short8*)&As[(wm0 + mt * 16 + fr) * 64 + off];
#pragma unroll
            for (int nt = 0; nt < TN; ++nt)
                bfr[nt] = *(const short8*)&Bs[(wn0 + nt * 16 + fr) * 64 + off];
#pragma unroll
            for (int mt = 0; mt < TM; ++mt)
#pragma unroll
                for (int nt = 0; nt < TN; ++nt)
                    acc[mt][nt] = __builtin_amdgcn_mfma_f32_16x16x32_bf16(
                        af[mt], bfr[nt], acc[mt][nt], 0, 0, 0);
        }
        __syncthreads();
    }

    const int er = lane >> 4;
    const int ec = lane & 15;
#pragma unroll
    for (int nt = 0; nt < TN; ++nt) {
        const int col = n_base + wn0 + nt * 16 + ec;
        const float bv = __bfloat162float(bias[col]);
#pragma unroll
        for (int mt = 0; mt < TM; ++mt) {
#pragma unroll
            for (int r = 0; r < 4; ++r) {
                const int row = m_base + wm0 + mt * 16 + er * 4 + r;
                C[(size_t)row * ldc + col] =
                    __float2bfloat16(acc[mt][nt][r] + bv);
            }
        }
    }
}

// ---------------------------------------------------------------------------
// fp8 C = A * B^T, BK=64, mfma_f32_16x16x32_fp8_fp8 (ctx GEMMs), pair +
// per-n-block head shift. XOR-swizzled LDS (round-4).
// ---------------------------------------------------------------------------
struct B8Args { const unsigned char* A; const unsigned char* B; bf16* C; };
struct B8Pair { B8Args s[2]; };

template <int BM, int BN, bool RELU>
__global__ __launch_bounds__(256) void gemm_bt8(
    B8Pair P, int lda, long long a_kshift, int ldb, int ldc, int K, float scale)
{
    constexpr int WM = BM / 2;
    constexpr int WN = BN / 2;
    constexpr int TM = WM / 16;
    constexpr int TN = WN / 16;

    __align__(16) __shared__ unsigned char As[BM * 64];
    __align__(16) __shared__ unsigned char Bs[BN * 64];

    const B8Args g = P.s[blockIdx.z];
    const int lane = threadIdx.x & 63;
    const int wv   = threadIdx.x >> 6;
    const int m_base = blockIdx.y * BM;
    const int n_base = blockIdx.x * BN;
    const unsigned char* A = g.A + (long long)blockIdx.x * a_kshift;

    const int wm0 = (wv >> 1) * WM;
    const int wn0 = (wv & 1) * WN;

    floatx4 zero = {0.f, 0.f, 0.f, 0.f};
    floatx4 acc[TM][TN];
#pragma unroll
    for (int mt = 0; mt < TM; ++mt)
#pragma unroll
        for (int nt = 0; nt < TN; ++nt) acc[mt][nt] = zero;

    const int ar = lane >> 2;
    const int ac = (((lane & 3) ^ (ar & 3)) * 16);
    const int fr = lane & 15;
    const int q  = lane >> 4;
    const int sw = fr & 3;

    for (int k0 = 0; k0 < K; k0 += 64) {
#pragma unroll
        for (int cc = 0; cc < BM / 16; cc += 4) {
            const int r0t = (wv + cc) * 16;
            async16(A + (size_t)(m_base + r0t + ar) * lda + k0 + ac, &As[r0t * 64]);
        }
#pragma unroll
        for (int cc = 0; cc < BN / 16; cc += 4) {
            const int r0t = (wv + cc) * 16;
            async16(g.B + (size_t)(n_base + r0t + ar) * ldb + k0 + ac, &Bs[r0t * 64]);
        }
        __syncthreads();

#pragma unroll
        for (int s = 0; s < 2; ++s) {
            const int boff = (((s * 2 + (q >> 1)) ^ sw) * 16) + (q & 1) * 8;
            long af[TM], bfr[TN];
#pragma unroll
            for (int mt = 0; mt < TM; ++mt)
                af[mt] = *(const long*)&As[(wm0 + mt * 16 + fr) * 64 + boff];
#pragma unroll
            for (int nt = 0; nt < TN; ++nt)
                bfr[nt] = *(const long*)&Bs[(wn0 + nt * 16 + fr) * 64 + boff];
#pragma unroll
            for (int mt = 0; mt < TM; ++mt)
#pragma unroll
                for (int nt = 0; nt < TN; ++nt)
                    acc[mt][nt] = __builtin_amdgcn_mfma_f32_16x16x32_fp8_fp8(
                        af[mt], bfr[nt], acc[mt][nt], 0, 0, 0);
        }
        __syncthreads();
    }

    const int er = lane >> 4;
    const int ec = lane & 15;
#pragma unroll
    for (int nt = 0; nt < TN; ++nt) {
        const int col = n_base + wn0 + nt * 16 + ec;
#pragma unroll
        for (int mt = 0; mt < TM; ++mt) {
#pragma unroll
            for (int r = 0; r < 4; ++r) {
                const int row = m_base + wm0 + mt * 16 + er * 4 + r;
                float v = acc[mt][nt][r] * scale;
                if constexpr (RELU) v = fmaxf(v, 0.f);
                g.C[(size_t)row * ldc + col] = __float2bfloat16(v);
            }
        }
    }
}

// ---------------------------------------------------------------------------
// MX-scaled fp8 C = A * B^T, BK=128, unit e8m0 scales. Pair-capable.
// FP8OUT: e4m3(acc*scale); ADDC0: add bf16 C0 before store.
// ---------------------------------------------------------------------------
struct MxArgs { const unsigned char* A; const unsigned char* B; void* C; const bf16* Cz; };
struct MxPair { MxArgs s[2]; };

template <int BM, int BN, bool ADDC0, bool FP8OUT>
__global__ __launch_bounds__(256) void gemm_bt8mx(
    MxPair P, int lda, int ldb, int ldc, int ldc0, int K, float scale)
{
    constexpr int WM = BM / 2;
    constexpr int WN = BN / 2;
    constexpr int TM = WM / 16;
    constexpr int TN = WN / 16;

    __align__(16) __shared__ unsigned char As[BM * 128];
    __align__(16) __shared__ unsigned char Bs[BN * 128];

    const MxArgs g = P.s[blockIdx.z];
    const int lane = threadIdx.x & 63;
    const int wv   = threadIdx.x >> 6;
    const int m_base = blockIdx.y * BM;
    const int n_base = blockIdx.x * BN;

    const int wm0 = (wv >> 1) * WM;
    const int wn0 = (wv & 1) * WN;

    floatx4 zero = {0.f, 0.f, 0.f, 0.f};
    floatx4 acc[TM][TN];
#pragma unroll
    for (int mt = 0; mt < TM; ++mt)
#pragma unroll
        for (int nt = 0; nt < TN; ++nt) acc[mt][nt] = zero;

    const int sr = lane >> 3;
    const int sc = ((lane & 7) ^ sr) * 16;
    const int fr = lane & 15;
    const int q  = lane >> 4;
    const int sw = fr & 7;

    for (int k0 = 0; k0 < K; k0 += 128) {
#pragma unroll
        for (int cc = 0; cc < BM / 32; ++cc) {
            const int r0t = (wv + cc * 4) * 8;
            async16(g.A + (size_t)(m_base + r0t + sr) * lda + k0 + sc, &As[r0t * 128]);
        }
#pragma unroll
        for (int cc = 0; cc < BN / 32; ++cc) {
            const int r0t = (wv + cc * 4) * 8;
            async16(g.B + (size_t)(n_base + r0t + sr) * ldb + k0 + sc, &Bs[r0t * 128]);
        }
        __syncthreads();

        i32x8 af[TM], bf8[TN];
#pragma unroll
        for (int mt = 0; mt < TM; ++mt) {
            const unsigned char* rp = &As[(wm0 + mt * 16 + fr) * 128];
            i32x4 lo = *(const i32x4*)(rp + (((q * 2 + 0) ^ sw) * 16));
            i32x4 hi = *(const i32x4*)(rp + (((q * 2 + 1) ^ sw) * 16));
            af[mt] = __builtin_shufflevector(lo, hi, 0, 1, 2, 3, 4, 5, 6, 7);
        }
#pragma unroll
        for (int nt = 0; nt < TN; ++nt) {
            const unsigned char* rp = &Bs[(wn0 + nt * 16 + fr) * 128];
            i32x4 lo = *(const i32x4*)(rp + (((q * 2 + 0) ^ sw) * 16));
            i32x4 hi = *(const i32x4*)(rp + (((q * 2 + 1) ^ sw) * 16));
            bf8[nt] = __builtin_shufflevector(lo, hi, 0, 1, 2, 3, 4, 5, 6, 7);
        }
#pragma unroll
        for (int mt = 0; mt < TM; ++mt)
#pragma unroll
            for (int nt = 0; nt < TN; ++nt)
                acc[mt][nt] = __builtin_amdgcn_mfma_scale_f32_16x16x128_f8f6f4(
                    af[mt], bf8[nt], acc[mt][nt],
                    0, 0, 0, 127, 0, 127);
        __syncthreads();
    }

    const int er = lane >> 4;
    const int ec = lane & 15;
#pragma unroll
    for (int nt = 0; nt < TN; ++nt) {
        const int col = n_base + wn0 + nt * 16 + ec;
#pragma unroll
        for (int mt = 0; mt < TM; ++mt) {
#pragma unroll
            for (int r = 0; r < 4; ++r) {
                const int row = m_base + wm0 + mt * 16 + er * 4 + r;
                float v = acc[mt][nt][r] * scale;
                if constexpr (ADDC0) v += __bfloat162float(g.Cz[(size_t)row * ldc0 + col]);
                if constexpr (FP8OUT)
                    ((unsigned char*)g.C)[(size_t)row * ldc + col] = f2e4m3(v);
                else
                    ((bf16*)g.C)[(size_t)row * ldc + col] = __float2bfloat16(v);
            }
        }
    }
}

// ---------------------------------------------------------------------------
// MFMA fused scores + mask + softmax, pair-merged (z = side).
// Output: aw8 = e4m3(softmax * 32).
// ---------------------------------------------------------------------------
struct ScArgs { const bf16* Q; const bf16* K; const int* mask; unsigned char* aw; };
struct ScPair { ScArgs s[2]; };

__global__ __launch_bounds__(256) void scores_mfma(
    ScPair P, int ldk, float scale)
{
    __shared__ float wred[16][4];
    __shared__ float wsum[16][4];

    const ScArgs g = P.s[blockIdx.z];
    const int t    = threadIdx.x;
    const int lane = t & 63;
    const int w    = t >> 6;
    const int h    = blockIdx.y;
    const int r0   = blockIdx.x * 16;
    const int fr   = lane & 15;
    const int fq   = lane >> 4;
    const int cbase = w * 256;

    const short* Qs = (const short*)g.Q + (size_t)(r0 + fr) * 512 + h * 64 + fq * 8;
    short8 a0 = *(const short8*)(Qs);
    short8 a1 = *(const short8*)(Qs + 32);

    floatx4 accs[16];
    const short* Kb = (const short*)g.K + h * 64 + fq * 8;
#pragma unroll
    for (int c = 0; c < 16; ++c) {
        const int krow = cbase + c * 16 + fr;
        short8 b0 = *(const short8*)(Kb + (size_t)krow * ldk);
        short8 b1 = *(const short8*)(Kb + (size_t)krow * ldk + 32);
        floatx4 acc = {0.f, 0.f, 0.f, 0.f};
        acc = __builtin_amdgcn_mfma_f32_16x16x32_bf16(a0, b0, acc, 0, 0, 0);
        acc = __builtin_amdgcn_mfma_f32_16x16x32_bf16(a1, b1, acc, 0, 0, 0);
        accs[c] = acc;
    }

    float mxr[4] = {-3e38f, -3e38f, -3e38f, -3e38f};
#pragma unroll
    for (int c = 0; c < 16; ++c) {
        const int col = cbase + c * 16 + fr;
#pragma unroll
        for (int r = 0; r < 4; ++r) {
            const int row = r0 + fq * 4 + r;
            float v = (g.mask[(size_t)row * 1024 + col] == 0) ? -1e9f
                                                              : accs[c][r] * scale;
            accs[c][r] = v;
            mxr[r] = fmaxf(mxr[r], v);
        }
    }
#pragma unroll
    for (int o = 1; o < 16; o <<= 1)
#pragma unroll
        for (int r = 0; r < 4; ++r) mxr[r] = fmaxf(mxr[r], __shfl_xor(mxr[r], o));
    if (fr == 0)
#pragma unroll
        for (int r = 0; r < 4; ++r) wred[fq * 4 + r][w] = mxr[r];
    __syncthreads();

    float mx[4], sm[4] = {0.f, 0.f, 0.f, 0.f};
#pragma unroll
    for (int r = 0; r < 4; ++r) {
        const int row = fq * 4 + r;
        mx[r] = fmaxf(fmaxf(wred[row][0], wred[row][1]),
                      fmaxf(wred[row][2], wred[row][3]));
    }
#pragma unroll
    for (int c = 0; c < 16; ++c)
#pragma unroll
        for (int r = 0; r < 4; ++r) {
            float e = __expf(accs[c][r] - mx[r]);
            accs[c][r] = e;
            sm[r] += e;
        }
#pragma unroll
    for (int o = 1; o < 16; o <<= 1)
#pragma unroll
        for (int r = 0; r < 4; ++r) sm[r] += __shfl_xor(sm[r], o);
    if (fr == 0)
#pragma unroll
        for (int r = 0; r < 4; ++r) wsum[fq * 4 + r][w] = sm[r];
    __syncthreads();

    float inv[4];
#pragma unroll
    for (int r = 0; r < 4; ++r) {
        const int row = fq * 4 + r;
        inv[r] = 32.0f / (wsum[row][0] + wsum[row][1] + wsum[row][2] + wsum[row][3]);
    }
#pragma unroll
    for (int c = 0; c < 16; ++c) {
        const int col = cbase + c * 16 + fr;
#pragma unroll
        for (int r = 0; r < 4; ++r) {
            const int row = r0 + fq * 4 + r;
            g.aw[(size_t)row * 8192 + h * 1024 + col] = f2e4m3(accs[c][r] * inv[r]);
        }
    }
}

// ---------------------------------------------------------------------------
// Merged LayerNorm: rows [0,8192), gains selected by side. X contiguous.
// ---------------------------------------------------------------------------
__global__ __launch_bounds__(256) void ln_all(
    const float* __restrict__ X,
    const bf16* __restrict__ g1, const bf16* __restrict__ be1,
    const bf16* __restrict__ g2, const bf16* __restrict__ be2,
    void* __restrict__ out, const int* __restrict__ flag)
{
    const bool f32 = (*flag != 0);
    const int lane = threadIdx.x & 63;
    const int wv   = threadIdx.x >> 6;
    const int row  = blockIdx.x * 4 + wv;
    const bf16* gg = (row >= 4096) ? g2 : g1;
    const bf16* bb = (row >= 4096) ? be2 : be1;
    const float* x = X + (size_t)row * 256;
    float v[4], s = 0.f, s2 = 0.f;
#pragma unroll
    for (int i = 0; i < 4; ++i) {
        v[i] = x[lane + 64 * i];
        s += v[i]; s2 += v[i] * v[i];
    }
#pragma unroll
    for (int o = 1; o < 64; o <<= 1) { s += __shfl_xor(s, o); s2 += __shfl_xor(s2, o); }
    const float mu  = s * (1.0f / 256.0f);
    const float var = fmaxf(s2 * (1.0f / 256.0f) - mu * mu, 0.0f);
    const float inv = rsqrtf(var + 1e-5f);
#pragma unroll
    for (int i = 0; i < 4; ++i) {
        const int c = lane + 64 * i;
        const float y = (v[i] - mu) * inv * __bfloat162float(gg[c]) + __bfloat162float(bb[c]);
        if (f32) ((float*)out)[(size_t)row * 256 + c] = y;
        else     ((bf16*)out)[(size_t)row * 256 + c] = __float2bfloat16(y);
    }
}

// ---------------------------------------------------------------------------
extern "C" void kernel_launch(void* const* d_in, const int* in_sizes, int n_in,
                              void* d_out, int out_size, void* d_ws, size_t ws_size,
                              hipStream_t stream)
{
    const int L = 4096, Mm = 1024, P = 4096;

    const int* mask_l = (const int*)d_in[3];
    const int* mask_p = (const int*)d_in[4];

    char* ws = (char*)d_ws;
    size_t off = 0;
    auto alloc = [&](size_t bytes) {
        void* p = ws + off; off += (bytes + 255) & ~(size_t)255; return p;
    };

    int*  flag   = (int*)alloc(256);
    // weight slots: 0:Wl 1:Wm 2:Wp 3:Wql 4:Wqp 5:Wkl 6:Wvl 7:Wkp 8:Wvp
    bf16* wt_all = (bf16*)alloc((size_t)9 * 512 * 512 * 2);
    bf16* WmlT   = (bf16*)alloc(1024 * 256 * 2);
    bf16* WmpT   = (bf16*)alloc(1024 * 256 * 2);
    bf16* b_l    = (bf16*)alloc(512 * 2);
    bf16* b_m    = (bf16*)alloc(512 * 2);
    bf16* b_p    = (bf16*)alloc(512 * 2);
    bf16* b_ql   = (bf16*)alloc(512 * 2);
    bf16* b_qp   = (bf16*)alloc(512 * 2);
    bf16* bcat   = (bf16*)alloc(2048 * 2);     // [bkl|bvl|bkp|bvp]
    bf16* bml_c  = (bf16*)alloc(256 * 2);
    bf16* bmp_c  = (bf16*)alloc(256 * 2);
    bf16* g1c    = (bf16*)alloc(256 * 2);
    bf16* be1c   = (bf16*)alloc(256 * 2);
    bf16* g2c    = (bf16*)alloc(256 * 2);
    bf16* be2c   = (bf16*)alloc(256 * 2);
    bf16* emb_all = (bf16*)alloc((size_t)(L + Mm + P) * 512 * 2);  // [l|m|p]
    bf16* embl   = emb_all;
    bf16* embm   = emb_all + (size_t)L * 512;
    bf16* embp   = embm + (size_t)Mm * 512;
    bf16* cat_l  = (bf16*)alloc((size_t)L * 1024 * 2);   // [lt | fin_l]
    bf16* cat_p  = (bf16*)alloc((size_t)P * 1024 * 2);   // [fin_p | pt]
    bf16* mt     = (bf16*)alloc((size_t)Mm * 512 * 2);
    bf16* Ql     = (bf16*)alloc((size_t)L * 512 * 2);
    bf16* Qp     = (bf16*)alloc((size_t)P * 512 * 2);
    bf16* kvcat  = (bf16*)alloc((size_t)Mm * 2048 * 2);  // [Kl|Vl|Kp|Vp]
    unsigned char* V8lT = (unsigned char*)alloc((size_t)512 * Mm);
    unsigned char* V8pT = (unsigned char*)alloc((size_t)512 * Mm);
    bf16* ctx_l  = (bf16*)alloc((size_t)L * 512 * 2);
    bf16* ctx_p  = (bf16*)alloc((size_t)P * 512 * 2);
    unsigned char* ctx8lT = (unsigned char*)alloc((size_t)512 * L);
    unsigned char* ctx8pT = (unsigned char*)alloc((size_t)512 * P);
    unsigned char* mutual8 = (unsigned char*)alloc((size_t)L * P);
    unsigned char* awl8 = (unsigned char*)alloc((size_t)L * 8192);
    unsigned char* awp8 = (unsigned char*)alloc((size_t)P * 8192);
    // overlays: awl8/awp8 dead after the mutual GEMM
    unsigned char* mutual8T = awl8;
    float* tmp1 = (float*)awp8;                          // [8192, 256] fp32

    // 0. dtype sniff + canonicalize
    sniff_dtype<<<1, 64, 0, stream>>>((const unsigned short*)d_in[0], flag);

    CvtTable tab;
    tab.e[0]  = { d_in[0],  embl, L * 512 };
    tab.e[1]  = { d_in[1],  embm, Mm * 512 };
    tab.e[2]  = { d_in[2],  embp, P * 512 };
    tab.e[3]  = { d_in[6],  b_l,  512 };
    tab.e[4]  = { d_in[8],  b_m,  512 };
    tab.e[5]  = { d_in[10], b_p,  512 };
    tab.e[6]  = { d_in[12], b_ql, 512 };
    tab.e[7]  = { d_in[18], b_qp, 512 };
    tab.e[8]  = { d_in[14], bcat,        512 };
    tab.e[9]  = { d_in[16], bcat + 512,  512 };
    tab.e[10] = { d_in[20], bcat + 1024, 512 };
    tab.e[11] = { d_in[22], bcat + 1536, 512 };
    tab.e[12] = { d_in[24], bml_c, 256 };
    tab.e[13] = { d_in[26], bmp_c, 256 };
    tab.e[14] = { d_in[27], g1c,  256 };
    tab.e[15] = { d_in[28], be1c, 256 };
    tab.e[16] = { d_in[29], g2c,  256 };
    tab.e[17] = { d_in[30], be2c, 256 };
    convert_inputs<<<dim3(256, 18), 256, 0, stream>>>(tab, flag);

    // 1. weight transposes
    TT9 tt;
    const int slot_of[9] = {0, 1, 2, 3, 5, 6, 4, 7, 8};
    for (int i = 0; i < 9; ++i) {
        tt.src[i] = d_in[5 + 2 * i];
        tt.dst[i] = wt_all + (size_t)slot_of[i] * 512 * 512;
    }
    transpose_sq9<<<dim3(16, 16, 9), 256, 0, stream>>>(tt, flag);
    TaPair tw = { { d_in[23], d_in[25] }, { WmlT, WmpT } };
    transpose_any_pair<<<dim3(8, 32, 2), 256, 0, stream>>>(tw, 256, 1024, 256, flag);

    bf16* WlT  = wt_all;
    bf16* WmT  = wt_all + (size_t)1 * 512 * 512;
    bf16* WpT  = wt_all + (size_t)2 * 512 * 512;
    bf16* WqlT = wt_all + (size_t)3 * 512 * 512;
    bf16* WqpT = wt_all + (size_t)4 * 512 * 512;
    bf16* WkvT = wt_all + (size_t)5 * 512 * 512;  // [2048, 512]

    // 2. all three input projections in one launch (segment table)
    SegTab st;
    st.W[0] = WlT;  st.bias[0] = b_l; st.C[0] = cat_l;       st.ldc[0] = 1024; st.rs[0] = 0;
    st.W[1] = WmT;  st.bias[1] = b_m; st.C[1] = mt;          st.ldc[1] = 512;  st.rs[1] = 4096;
    st.W[2] = WpT;  st.bias[2] = b_p; st.C[2] = cat_p + 512; st.ldc[2] = 1024; st.rs[2] = 5120;
    gemm_bt_seg<<<dim3(8, 144), 256, 0, stream>>>(emb_all, st, 512);

    // 3. Q projections (pair) + fused K/V projection
    BtPair qp = { { { cat_l,       WqlT, Ql, b_ql },
                    { cat_p + 512, WqpT, Qp, b_qp } } };
    gemm_bt<64, 64, true, false><<<dim3(8, 64, 2), 256, 0, stream>>>(
        qp, 1024, 512, 512, 512, 1.0f);
    BtPair kv = { { { mt, WkvT, kvcat, bcat }, { mt, WkvT, kvcat, bcat } } };
    gemm_bt<64, 64, true, false><<<dim3(32, 16, 1), 256, 0, stream>>>(
        kv, 512, 512, 2048, 512, 1.0f);

    // V8T = e4m3(V^T * 4)
    TqPair v8 = { { kvcat + 512, kvcat + 1536 }, { V8lT, V8pT } };
    transpose_q8_pair<<<dim3(16, 32, 2), 256, 0, stream>>>(v8, 2048, 1024, 512, 4.0f);

    // 4. fused MFMA scores + mask + softmax (pair) -> aw8 = e4m3(softmax*32)
    ScPair sc = { { { Ql, kvcat,        mask_l, awl8 },
                    { Qp, kvcat + 1024, mask_p, awp8 } } };
    scores_mfma<<<dim3(256, 8, 2), 256, 0, stream>>>(sc, 2048, 0.125f);

    // 5. ctx = relu(aw @ V) per head (fp8 pair), scale 1/(32*4)
    B8Pair cx = { { { awl8, V8lT, ctx_l }, { awp8, V8pT, ctx_p } } };
    gemm_bt8<64, 64, true><<<dim3(8, 64, 2), 256, 0, stream>>>(
        cx, 8192, 1024, 1024, 512, 1024, 1.0f / 128.0f);

    // ctx8T = e4m3(ctx^T * 16)
    TqPair c8 = { { ctx_l, ctx_p }, { ctx8lT, ctx8pT } };
    transpose_q8_pair<<<dim3(16, 128, 2), 256, 0, stream>>>(c8, 512, 4096, 512, 16.0f);

    // 6. mutual8 = e4m3( (awl @ awp^T)/8 * 256 )  (MX fp8, BK=128)
    MxPair mu = { { { awl8, awp8, mutual8, nullptr },
                    { awl8, awp8, mutual8, nullptr } } };
    gemm_bt8mx<128, 128, false, true><<<dim3(32, 32, 1), 256, 0, stream>>>(
        mu, 8192, 8192, 4096, 0, 8192, 0.03125f);
    transpose_b8<<<dim3(64, 64), 256, 0, stream>>>(mutual8, mutual8T, 4096, 4096);

    // 7. fin (MX fp8 pair, K=4096): scale 1/(256*16) = 1/4096
    MxPair fn = { { { mutual8,  ctx8pT, cat_l + 512, ctx_l },
                    { mutual8T, ctx8lT, cat_p,       ctx_p } } };
    gemm_bt8mx<64, 64, true, false><<<dim3(8, 64, 2), 256, 0, stream>>>(
        fn, 4096, 4096, 1024, 512, 4096, 1.0f / 4096.0f);

    // 8. final projections (pair, fp32 out) + merged LayerNorm -> d_out
    BtPair fp = { { { cat_l, WmlT, tmp1,                    bml_c },
                    { cat_p, WmpT, tmp1 + (size_t)L * 256,  bmp_c } } };
    gemm_bt<64, 64, true, true><<<dim3(4, 64, 2), 256, 0, stream>>>(
        fp, 1024, 1024, 256, 1024, 1.0f);

    ln_all<<<dim3(2048), 256, 0, stream>>>(tmp1, g1c, be1c, g2c, be2c, d_out, flag);
}

// Round 9
// 500.005 us; speedup vs baseline: 2.7845x; 1.1278x over previous
//
#include <hip/hip_runtime.h>
#include <hip/hip_bf16.h>

using bf16 = __hip_bfloat16;
typedef __attribute__((ext_vector_type(8))) short short8;
typedef __attribute__((ext_vector_type(4))) float floatx4;
typedef __attribute__((ext_vector_type(8))) unsigned short ushort8;
typedef __attribute__((ext_vector_type(4))) int i32x4;
typedef __attribute__((ext_vector_type(8))) int i32x8;

__device__ __forceinline__ float b2f(unsigned short u) {
    union { unsigned int i; float f; } x; x.i = ((unsigned int)u) << 16; return x.f;
}

__device__ __forceinline__ void async16(const void* g, void* l) {
    __builtin_amdgcn_global_load_lds((const __attribute__((address_space(1))) void*)g,
                                     (__attribute__((address_space(3))) void*)l,
                                     16, 0, 0);
}

// float -> OCP e4m3fn, RNE, signed, |f| clamped to 448.
__device__ __forceinline__ unsigned char f2e4m3(float f) {
    unsigned s = (__float_as_uint(f) >> 24) & 0x80u;
    f = fminf(fabsf(f), 448.f);
    if (f < 0.015625f) {
        int d = (int)rintf(f * 512.f);
        return (unsigned char)(s | (unsigned)d);
    }
    int E = (int)((__float_as_uint(f) >> 23) & 255u) - 127;
    float ulp_inv = __uint_as_float((unsigned)(127 + 3 - E) << 23);
    int m = (int)rintf(f * ulp_inv);
    int n = (m == 16) ? ((E + 8) << 3) : (((E + 7) << 3) + (m - 8));
    if (n > 0x7E) n = 0x7E;
    return (unsigned char)(s | (unsigned)n);
}

// Inline dtype sniff: fp32 data read as bf16 -> ~44% wild exponents.
__device__ __forceinline__ bool sniff_wave(const unsigned short* p) {
    const int lane = threadIdx.x & 63;
    int wild = 0;
#pragma unroll
    for (int j = 0; j < 4; ++j) {
        float a = fabsf(b2f(p[lane * 4 + j]));
        wild += !(a <= 1e4f);
    }
#pragma unroll
    for (int o = 1; o < 64; o <<= 1) wild += __shfl_xor(wild, o);
    return wild > 16;
}

// ---------------------------------------------------------------------------
// Unified prep: y<18 -> dtype-convert segment y; y in [18,27) -> 512x512
// weight transpose (y-18); y in {27,28} -> 1024x256 rect transpose (Wml/Wmp).
// ---------------------------------------------------------------------------
struct Cvt { const void* src; bf16* dst; int n; };
struct PrepArgs {
    Cvt cv[18];
    const void* tsrc[11];
    bf16* tdst[11];
    const unsigned short* sn;
};

__global__ __launch_bounds__(256) void prep(PrepArgs a) {
    const bool f32 = sniff_wave(a.sn);
    const int y = blockIdx.y;
    __shared__ bf16 tile[32][33];

    if (y < 18) {
        const Cvt c = a.cv[y];
        const int stride = gridDim.x * 256 * 8;
        for (int i = (blockIdx.x * 256 + threadIdx.x) * 8; i < c.n; i += stride) {
            if (f32) {
                const float* s = (const float*)c.src + i;
#pragma unroll
                for (int j = 0; j < 8; ++j) c.dst[i + j] = __float2bfloat16(s[j]);
            } else {
                *(ushort8*)((unsigned short*)c.dst + i) =
                    *(const ushort8*)((const unsigned short*)c.src + i);
            }
        }
        return;
    }

    const int tx = threadIdx.x & 31;
    const int ty = threadIdx.x >> 5;
    if (y < 27) {                       // square 512x512, idx y-18
        const void* in = a.tsrc[y - 18];
        bf16* out = a.tdst[y - 18];
        const int bc = (blockIdx.x & 15) * 32;
        const int br = (blockIdx.x >> 4) * 32;
#pragma unroll
        for (int i = 0; i < 32; i += 8) {
            const size_t idx = (size_t)(br + ty + i) * 512 + bc + tx;
            tile[ty + i][tx] = f32 ? __float2bfloat16(((const float*)in)[idx])
                                   : ((const bf16*)in)[idx];
        }
        __syncthreads();
#pragma unroll
        for (int i = 0; i < 32; i += 8)
            out[(size_t)(bc + ty + i) * 512 + br + tx] = tile[tx][ty + i];
    } else {                            // rect 1024x256, idx y-27+9
        const void* in = a.tsrc[y - 27 + 9];
        bf16* out = a.tdst[y - 27 + 9];
        const int bc = (blockIdx.x & 7) * 32;     // < 256
        const int br = (blockIdx.x >> 3) * 32;    // < 1024
#pragma unroll
        for (int i = 0; i < 32; i += 8) {
            const size_t idx = (size_t)(br + ty + i) * 256 + bc + tx;
            tile[ty + i][tx] = f32 ? __float2bfloat16(((const float*)in)[idx])
                                   : ((const bf16*)in)[idx];
        }
        __syncthreads();
#pragma unroll
        for (int i = 0; i < 32; i += 8)
            out[(size_t)(bc + ty + i) * 1024 + br + tx] = tile[tx][ty + i];
    }
}

// ---------------------------------------------------------------------------
// Segment-table bf16 GEMM for the 3 embedding projections (BK=64, swizzled).
// ---------------------------------------------------------------------------
struct SegTab { const bf16* W[3]; const bf16* bias[3]; bf16* C[3]; int ldc[3]; int rs[3]; };

__global__ __launch_bounds__(256) void gemm_bt_seg(
    const bf16* __restrict__ A, SegTab T, int K)
{
    constexpr int TM = 2, TN = 2;
    __align__(16) __shared__ bf16 As[64 * 64];
    __align__(16) __shared__ bf16 Bs[64 * 64];

    const int lane = threadIdx.x & 63;
    const int wv   = threadIdx.x >> 6;
    const int gm   = blockIdx.y * 64;
    const int seg  = (gm >= 5120) ? 2 : ((gm >= 4096) ? 1 : 0);
    const bf16* B  = T.W[seg];
    const bf16* bias = T.bias[seg];
    bf16* C        = T.C[seg];
    const int ldc  = T.ldc[seg];
    const int m_base = gm - T.rs[seg];
    const int n_base = blockIdx.x * 64;
    const int wm0 = (wv >> 1) * 32;
    const int wn0 = (wv & 1) * 32;

    floatx4 zero = {0.f, 0.f, 0.f, 0.f};
    floatx4 acc[TM][TN];
#pragma unroll
    for (int mt = 0; mt < TM; ++mt)
#pragma unroll
        for (int nt = 0; nt < TN; ++nt) acc[mt][nt] = zero;

    const int sr  = lane >> 3;
    const int sce = ((lane & 7) ^ sr) * 8;
    const int fr  = lane & 15;
    const int q   = lane >> 4;
    const int sw  = fr & 7;

    for (int k0 = 0; k0 < K; k0 += 64) {
#pragma unroll
        for (int cc = 0; cc < 2; ++cc) {
            const int r0t = (wv + cc * 4) * 8;
            async16(A + (size_t)(gm + r0t + sr) * 512 + k0 + sce, &As[r0t * 64]);
            async16(B + (size_t)(n_base + r0t + sr) * 512 + k0 + sce, &Bs[r0t * 64]);
        }
        __syncthreads();
#pragma unroll
        for (int s = 0; s < 2; ++s) {
            const int off = ((s * 4 + q) ^ sw) * 8;
            short8 af[TM], bfr[TN];
#pragma unroll
            for (int mt = 0; mt < TM; ++mt)
                af[mt] = *(const short8*)&As[(wm0 + mt * 16 + fr) * 64 + off];
#pragma unroll
            for (int nt = 0; nt < TN; ++nt)
                bfr[nt] = *(const short8*)&Bs[(wn0 + nt * 16 + fr) * 64 + off];
#pragma unroll
            for (int mt = 0; mt < TM; ++mt)
#pragma unroll
                for (int nt = 0; nt < TN; ++nt)
                    acc[mt][nt] = __builtin_amdgcn_mfma_f32_16x16x32_bf16(
                        af[mt], bfr[nt], acc[mt][nt], 0, 0, 0);
        }
        __syncthreads();
    }

    const int er = lane >> 4;
    const int ec = lane & 15;
#pragma unroll
    for (int nt = 0; nt < TN; ++nt) {
        const int col = n_base + wn0 + nt * 16 + ec;
        const float bv = __bfloat162float(bias[col]);
#pragma unroll
        for (int mt = 0; mt < TM; ++mt)
#pragma unroll
            for (int r = 0; r < 4; ++r) {
                const int row = m_base + wm0 + mt * 16 + er * 4 + r;
                C[(size_t)row * ldc + col] = __float2bfloat16(acc[mt][nt][r] + bv);
            }
    }
}

// ---------------------------------------------------------------------------
// bf16 C = A*B^T, BK=64 swizzled, per-z args. REMAP2: z==2 remaps flat id to
// a (32,16) grid (the KV projection). BM=BN=64.
// ---------------------------------------------------------------------------
struct BtArgs { const bf16* A; const bf16* B; void* C; const bf16* bias;
                int lda, ldb, ldc; };
struct BtSet { BtArgs s[3]; };

template <bool F32OUT, bool REMAP2>
__global__ __launch_bounds__(256) void gemm_btx(BtSet P, int K, float scale)
{
    constexpr int TM = 2, TN = 2;
    __align__(16) __shared__ bf16 As[64 * 64];
    __align__(16) __shared__ bf16 Bs[64 * 64];

    const BtArgs g = P.s[blockIdx.z];
    int bx = blockIdx.x, by = blockIdx.y;
    if (REMAP2 && blockIdx.z == 2) {
        const int flat = by * gridDim.x + bx;      // 8*64 = 512
        bx = flat & 31; by = flat >> 5;            // -> (32,16)
    }
    const int lane = threadIdx.x & 63;
    const int wv   = threadIdx.x >> 6;
    const int m_base = by * 64;
    const int n_base = bx * 64;
    const int wm0 = (wv >> 1) * 32;
    const int wn0 = (wv & 1) * 32;

    floatx4 zero = {0.f, 0.f, 0.f, 0.f};
    floatx4 acc[TM][TN];
#pragma unroll
    for (int mt = 0; mt < TM; ++mt)
#pragma unroll
        for (int nt = 0; nt < TN; ++nt) acc[mt][nt] = zero;

    const int sr  = lane >> 3;
    const int sce = ((lane & 7) ^ sr) * 8;
    const int fr  = lane & 15;
    const int q   = lane >> 4;
    const int sw  = fr & 7;

    for (int k0 = 0; k0 < K; k0 += 64) {
#pragma unroll
        for (int cc = 0; cc < 2; ++cc) {
            const int r0t = (wv + cc * 4) * 8;
            async16(g.A + (size_t)(m_base + r0t + sr) * g.lda + k0 + sce, &As[r0t * 64]);
            async16(g.B + (size_t)(n_base + r0t + sr) * g.ldb + k0 + sce, &Bs[r0t * 64]);
        }
        __syncthreads();
#pragma unroll
        for (int s = 0; s < 2; ++s) {
            const int off = ((s * 4 + q) ^ sw) * 8;
            short8 af[TM], bfr[TN];
#pragma unroll
            for (int mt = 0; mt < TM; ++mt)
                af[mt] = *(const short8*)&As[(wm0 + mt * 16 + fr) * 64 + off];
#pragma unroll
            for (int nt = 0; nt < TN; ++nt)
                bfr[nt] = *(const short8*)&Bs[(wn0 + nt * 16 + fr) * 64 + off];
#pragma unroll
            for (int mt = 0; mt < TM; ++mt)
#pragma unroll
                for (int nt = 0; nt < TN; ++nt)
                    acc[mt][nt] = __builtin_amdgcn_mfma_f32_16x16x32_bf16(
                        af[mt], bfr[nt], acc[mt][nt], 0, 0, 0);
        }
        __syncthreads();
    }

    const int er = lane >> 4;
    const int ec = lane & 15;
#pragma unroll
    for (int nt = 0; nt < TN; ++nt) {
        const int col = n_base + wn0 + nt * 16 + ec;
        const float bv = __bfloat162float(g.bias[col]);
#pragma unroll
        for (int mt = 0; mt < TM; ++mt)
#pragma unroll
            for (int r = 0; r < 4; ++r) {
                const int row = m_base + wm0 + mt * 16 + er * 4 + r;
                const float v = acc[mt][nt][r] * scale + bv;
                if constexpr (F32OUT)
                    ((float*)g.C)[(size_t)row * g.ldc + col] = v;
                else
                    ((bf16*)g.C)[(size_t)row * g.ldc + col] = __float2bfloat16(v);
            }
    }
}

// ---------------------------------------------------------------------------
// Merged: z<2 -> MFMA scores+mask+softmax (side z); z==2 -> V quant-transpose
// for both sides (flat-id remap). aw8 = e4m3(softmax*32); V8T = e4m3(V^T*4).
// ---------------------------------------------------------------------------
struct ScArgs { const bf16* Q; const bf16* K; const int* mask; unsigned char* aw; };
struct ScSet { ScArgs s[2]; const bf16* vsrc[2]; unsigned char* vdst[2]; };

__global__ __launch_bounds__(256) void scores_v8(ScSet P, int ldk, float scale)
{
    __shared__ float wred[16][4];
    __shared__ float wsum[16][4];
    __shared__ float tile[32][33];

    if (blockIdx.z == 2) {                 // V8T transposes, 1024 blocks
        const int flat = blockIdx.y * 256 + blockIdx.x;   // < 2048
        if (flat >= 1024) return;
        const int side = flat >> 9;
        const int rem  = flat & 511;
        const bf16* in = P.vsrc[side];     // [1024, 2048] at V offset
        unsigned char* out = P.vdst[side];
        const int bc = (rem & 15) * 32;    // < 512
        const int br = (rem >> 4) * 32;    // < 1024
        const int tx = threadIdx.x & 31;
        const int ty = threadIdx.x >> 5;
#pragma unroll
        for (int i = 0; i < 32; i += 8)
            tile[ty + i][tx] =
                __bfloat162float(in[(size_t)(br + ty + i) * 2048 + bc + tx]) * 4.0f;
        __syncthreads();
#pragma unroll
        for (int i = 0; i < 32; i += 8)
            out[(size_t)(bc + ty + i) * 1024 + br + tx] = f2e4m3(tile[tx][ty + i]);
        return;
    }

    const ScArgs g = P.s[blockIdx.z];
    const int t    = threadIdx.x;
    const int lane = t & 63;
    const int w    = t >> 6;
    const int h    = blockIdx.y;
    const int r0   = blockIdx.x * 16;
    const int fr   = lane & 15;
    const int fq   = lane >> 4;
    const int cbase = w * 256;

    const short* Qs = (const short*)g.Q + (size_t)(r0 + fr) * 512 + h * 64 + fq * 8;
    short8 a0 = *(const short8*)(Qs);
    short8 a1 = *(const short8*)(Qs + 32);

    floatx4 accs[16];
    const short* Kb = (const short*)g.K + h * 64 + fq * 8;
#pragma unroll
    for (int c = 0; c < 16; ++c) {
        const int krow = cbase + c * 16 + fr;
        short8 b0 = *(const short8*)(Kb + (size_t)krow * ldk);
        short8 b1 = *(const short8*)(Kb + (size_t)krow * ldk + 32);
        floatx4 acc = {0.f, 0.f, 0.f, 0.f};
        acc = __builtin_amdgcn_mfma_f32_16x16x32_bf16(a0, b0, acc, 0, 0, 0);
        acc = __builtin_amdgcn_mfma_f32_16x16x32_bf16(a1, b1, acc, 0, 0, 0);
        accs[c] = acc;
    }

    float mxr[4] = {-3e38f, -3e38f, -3e38f, -3e38f};
#pragma unroll
    for (int c = 0; c < 16; ++c) {
        const int col = cbase + c * 16 + fr;
#pragma unroll
        for (int r = 0; r < 4; ++r) {
            const int row = r0 + fq * 4 + r;
            float v = (g.mask[(size_t)row * 1024 + col] == 0) ? -1e9f
                                                              : accs[c][r] * scale;
            accs[c][r] = v;
            mxr[r] = fmaxf(mxr[r], v);
        }
    }
#pragma unroll
    for (int o = 1; o < 16; o <<= 1)
#pragma unroll
        for (int r = 0; r < 4; ++r) mxr[r] = fmaxf(mxr[r], __shfl_xor(mxr[r], o));
    if (fr == 0)
#pragma unroll
        for (int r = 0; r < 4; ++r) wred[fq * 4 + r][w] = mxr[r];
    __syncthreads();

    float mx[4], sm[4] = {0.f, 0.f, 0.f, 0.f};
#pragma unroll
    for (int r = 0; r < 4; ++r) {
        const int row = fq * 4 + r;
        mx[r] = fmaxf(fmaxf(wred[row][0], wred[row][1]),
                      fmaxf(wred[row][2], wred[row][3]));
    }
#pragma unroll
    for (int c = 0; c < 16; ++c)
#pragma unroll
        for (int r = 0; r < 4; ++r) {
            float e = __expf(accs[c][r] - mx[r]);
            accs[c][r] = e;
            sm[r] += e;
        }
#pragma unroll
    for (int o = 1; o < 16; o <<= 1)
#pragma unroll
        for (int r = 0; r < 4; ++r) sm[r] += __shfl_xor(sm[r], o);
    if (fr == 0)
#pragma unroll
        for (int r = 0; r < 4; ++r) wsum[fq * 4 + r][w] = sm[r];
    __syncthreads();

    float inv[4];
#pragma unroll
    for (int r = 0; r < 4; ++r) {
        const int row = fq * 4 + r;
        inv[r] = 32.0f / (wsum[row][0] + wsum[row][1] + wsum[row][2] + wsum[row][3]);
    }
#pragma unroll
    for (int c = 0; c < 16; ++c) {
        const int col = cbase + c * 16 + fr;
#pragma unroll
        for (int r = 0; r < 4; ++r) {
            const int row = r0 + fq * 4 + r;
            g.aw[(size_t)row * 8192 + h * 1024 + col] = f2e4m3(accs[c][r] * inv[r]);
        }
    }
}

// ---------------------------------------------------------------------------
// fp8 ctx GEMM (BK=64, XOR swizzle) with fused bf16 C + quantized-transposed
// CT = e4m3(C*16) output (4 rows packed per u32 store). BM=BN=64.
// ---------------------------------------------------------------------------
struct B8Args { const unsigned char* A; const unsigned char* B; bf16* C;
                unsigned char* CT; };
struct B8Pair { B8Args s[2]; };

__global__ __launch_bounds__(256) void gemm_bt8_ctx(
    B8Pair P, int lda, long long a_kshift, int ldb, int ldc, int ldct,
    int K, float scale)
{
    constexpr int TM = 2, TN = 2;
    __align__(16) __shared__ unsigned char As[64 * 64];
    __align__(16) __shared__ unsigned char Bs[64 * 64];

    const B8Args g = P.s[blockIdx.z];
    const int lane = threadIdx.x & 63;
    const int wv   = threadIdx.x >> 6;
    const int m_base = blockIdx.y * 64;
    const int n_base = blockIdx.x * 64;
    const unsigned char* A = g.A + (long long)blockIdx.x * a_kshift;

    const int wm0 = (wv >> 1) * 32;
    const int wn0 = (wv & 1) * 32;

    floatx4 zero = {0.f, 0.f, 0.f, 0.f};
    floatx4 acc[TM][TN];
#pragma unroll
    for (int mt = 0; mt < TM; ++mt)
#pragma unroll
        for (int nt = 0; nt < TN; ++nt) acc[mt][nt] = zero;

    const int ar = lane >> 2;
    const int ac = (((lane & 3) ^ (ar & 3)) * 16);
    const int fr = lane & 15;
    const int q  = lane >> 4;
    const int sw = fr & 3;

    for (int k0 = 0; k0 < K; k0 += 64) {
        async16(A + (size_t)(m_base + wv * 16 + ar) * lda + k0 + ac, &As[wv * 16 * 64]);
        async16(g.B + (size_t)(n_base + wv * 16 + ar) * ldb + k0 + ac, &Bs[wv * 16 * 64]);
        __syncthreads();
#pragma unroll
        for (int s = 0; s < 2; ++s) {
            const int boff = (((s * 2 + (q >> 1)) ^ sw) * 16) + (q & 1) * 8;
            long af[TM], bfr[TN];
#pragma unroll
            for (int mt = 0; mt < TM; ++mt)
                af[mt] = *(const long*)&As[(wm0 + mt * 16 + fr) * 64 + boff];
#pragma unroll
            for (int nt = 0; nt < TN; ++nt)
                bfr[nt] = *(const long*)&Bs[(wn0 + nt * 16 + fr) * 64 + boff];
#pragma unroll
            for (int mt = 0; mt < TM; ++mt)
#pragma unroll
                for (int nt = 0; nt < TN; ++nt)
                    acc[mt][nt] = __builtin_amdgcn_mfma_f32_16x16x32_fp8_fp8(
                        af[mt], bfr[nt], acc[mt][nt], 0, 0, 0);
        }
        __syncthreads();
    }

    const int er = lane >> 4;
    const int ec = lane & 15;
#pragma unroll
    for (int nt = 0; nt < TN; ++nt) {
        const int col = n_base + wn0 + nt * 16 + ec;
#pragma unroll
        for (int mt = 0; mt < TM; ++mt) {
            const int rowb = m_base + wm0 + mt * 16 + er * 4;
            unsigned int pk = 0;
#pragma unroll
            for (int r = 0; r < 4; ++r) {
                float v = fmaxf(acc[mt][nt][r] * scale, 0.f);
                g.C[(size_t)(rowb + r) * ldc + col] = __float2bfloat16(v);
                pk |= (unsigned)f2e4m3(v * 16.0f) << (8 * r);
            }
            *(unsigned int*)(g.CT + (size_t)col * ldct + rowb) = pk;
        }
    }
}

// ---------------------------------------------------------------------------
// MX-scaled fp8 C = A*B^T, BK=128, unit e8m0 scales. ADDC0: +bf16 C0.
// FP8OUT: e4m3 row-major out; TOUT: also e4m3 transposed out (4-row u32).
// NOTE: with TOUT the CT buffer must NOT alias A or B (epilogue writes race
// with other blocks' K-loop reads — caught by replay validation in r8).
// ---------------------------------------------------------------------------
struct MxArgs { const unsigned char* A; const unsigned char* B; void* C;
                const bf16* Cz; unsigned char* CT; };
struct MxPair { MxArgs s[2]; };

template <int BM, int BN, bool ADDC0, bool FP8OUT, bool TOUT>
__global__ __launch_bounds__(256, 2) void gemm_bt8mx(
    MxPair P, int lda, int ldb, int ldc, int ldc0, int ldct, int K, float scale)
{
    constexpr int WM = BM / 2;
    constexpr int WN = BN / 2;
    constexpr int TM = WM / 16;
    constexpr int TN = WN / 16;

    __align__(16) __shared__ unsigned char As[BM * 128];
    __align__(16) __shared__ unsigned char Bs[BN * 128];

    const MxArgs g = P.s[blockIdx.z];
    const int lane = threadIdx.x & 63;
    const int wv   = threadIdx.x >> 6;
    const int m_base = blockIdx.y * BM;
    const int n_base = blockIdx.x * BN;

    const int wm0 = (wv >> 1) * WM;
    const int wn0 = (wv & 1) * WN;

    floatx4 zero = {0.f, 0.f, 0.f, 0.f};
    floatx4 acc[TM][TN];
#pragma unroll
    for (int mt = 0; mt < TM; ++mt)
#pragma unroll
        for (int nt = 0; nt < TN; ++nt) acc[mt][nt] = zero;

    const int sr = lane >> 3;
    const int sc = ((lane & 7) ^ sr) * 16;
    const int fr = lane & 15;
    const int q  = lane >> 4;
    const int sw = fr & 7;

    for (int k0 = 0; k0 < K; k0 += 128) {
#pragma unroll
        for (int cc = 0; cc < BM / 32; ++cc) {
            const int r0t = (wv + cc * 4) * 8;
            async16(g.A + (size_t)(m_base + r0t + sr) * lda + k0 + sc, &As[r0t * 128]);
        }
#pragma unroll
        for (int cc = 0; cc < BN / 32; ++cc) {
            const int r0t = (wv + cc * 4) * 8;
            async16(g.B + (size_t)(n_base + r0t + sr) * ldb + k0 + sc, &Bs[r0t * 128]);
        }
        __syncthreads();

        i32x8 af[TM];
#pragma unroll
        for (int mt = 0; mt < TM; ++mt) {
            const unsigned char* rp = &As[(wm0 + mt * 16 + fr) * 128];
            i32x4 lo = *(const i32x4*)(rp + (((q * 2 + 0) ^ sw) * 16));
            i32x4 hi = *(const i32x4*)(rp + (((q * 2 + 1) ^ sw) * 16));
            af[mt] = __builtin_shufflevector(lo, hi, 0, 1, 2, 3, 4, 5, 6, 7);
        }
#pragma unroll
        for (int nt = 0; nt < TN; ++nt) {
            const unsigned char* rp = &Bs[(wn0 + nt * 16 + fr) * 128];
            i32x4 lo = *(const i32x4*)(rp + (((q * 2 + 0) ^ sw) * 16));
            i32x4 hi = *(const i32x4*)(rp + (((q * 2 + 1) ^ sw) * 16));
            i32x8 bf8 = __builtin_shufflevector(lo, hi, 0, 1, 2, 3, 4, 5, 6, 7);
#pragma unroll
            for (int mt = 0; mt < TM; ++mt)
                acc[mt][nt] = __builtin_amdgcn_mfma_scale_f32_16x16x128_f8f6f4(
                    af[mt], bf8, acc[mt][nt], 0, 0, 0, 127, 0, 127);
        }
        __syncthreads();
    }

    const int er = lane >> 4;
    const int ec = lane & 15;
#pragma unroll
    for (int nt = 0; nt < TN; ++nt) {
        const int col = n_base + wn0 + nt * 16 + ec;
#pragma unroll
        for (int mt = 0; mt < TM; ++mt) {
            const int rowb = m_base + wm0 + mt * 16 + er * 4;
            unsigned int pk = 0;
#pragma unroll
            for (int r = 0; r < 4; ++r) {
                float v = acc[mt][nt][r] * scale;
                if constexpr (ADDC0)
                    v += __bfloat162float(g.Cz[(size_t)(rowb + r) * ldc0 + col]);
                if constexpr (FP8OUT) {
                    const unsigned char qv = f2e4m3(v);
                    ((unsigned char*)g.C)[(size_t)(rowb + r) * ldc + col] = qv;
                    if constexpr (TOUT) pk |= (unsigned)qv << (8 * r);
                } else {
                    ((bf16*)g.C)[(size_t)(rowb + r) * ldc + col] = __float2bfloat16(v);
                }
            }
            if constexpr (TOUT)
                *(unsigned int*)(g.CT + (size_t)col * ldct + rowb) = pk;
        }
    }
}

// ---------------------------------------------------------------------------
// Merged LayerNorm over 8192 rows x 256 cols; flag sniffed inline.
// ---------------------------------------------------------------------------
__global__ __launch_bounds__(256) void ln_all(
    const float* __restrict__ X,
    const bf16* __restrict__ g1, const bf16* __restrict__ be1,
    const bf16* __restrict__ g2, const bf16* __restrict__ be2,
    void* __restrict__ out, const unsigned short* __restrict__ sn)
{
    const bool f32 = sniff_wave(sn);
    const int lane = threadIdx.x & 63;
    const int wv   = threadIdx.x >> 6;
    const int row  = blockIdx.x * 4 + wv;
    const bf16* gg = (row >= 4096) ? g2 : g1;
    const bf16* bb = (row >= 4096) ? be2 : be1;
    const float* x = X + (size_t)row * 256;
    float v[4], s = 0.f, s2 = 0.f;
#pragma unroll
    for (int i = 0; i < 4; ++i) {
        v[i] = x[lane + 64 * i];
        s += v[i]; s2 += v[i] * v[i];
    }
#pragma unroll
    for (int o = 1; o < 64; o <<= 1) { s += __shfl_xor(s, o); s2 += __shfl_xor(s2, o); }
    const float mu  = s * (1.0f / 256.0f);
    const float var = fmaxf(s2 * (1.0f / 256.0f) - mu * mu, 0.0f);
    const float inv = rsqrtf(var + 1e-5f);
#pragma unroll
    for (int i = 0; i < 4; ++i) {
        const int c = lane + 64 * i;
        const float y = (v[i] - mu) * inv * __bfloat162float(gg[c]) + __bfloat162float(bb[c]);
        if (f32) ((float*)out)[(size_t)row * 256 + c] = y;
        else     ((bf16*)out)[(size_t)row * 256 + c] = __float2bfloat16(y);
    }
}

// ---------------------------------------------------------------------------
extern "C" void kernel_launch(void* const* d_in, const int* in_sizes, int n_in,
                              void* d_out, int out_size, void* d_ws, size_t ws_size,
                              hipStream_t stream)
{
    const int L = 4096, Mm = 1024, P = 4096;

    const int* mask_l = (const int*)d_in[3];
    const int* mask_p = (const int*)d_in[4];
    const unsigned short* sn = (const unsigned short*)d_in[0];

    char* ws = (char*)d_ws;
    size_t off = 0;
    auto alloc = [&](size_t bytes) {
        void* p = ws + off; off += (bytes + 255) & ~(size_t)255; return p;
    };

    // weight slots: 0:Wl 1:Wm 2:Wp 3:Wql 4:Wqp 5:Wkl 6:Wvl 7:Wkp 8:Wvp
    bf16* wt_all = (bf16*)alloc((size_t)9 * 512 * 512 * 2);
    bf16* WmlT   = (bf16*)alloc(1024 * 256 * 2);
    bf16* WmpT   = (bf16*)alloc(1024 * 256 * 2);
    bf16* b_l    = (bf16*)alloc(512 * 2);
    bf16* b_m    = (bf16*)alloc(512 * 2);
    bf16* b_p    = (bf16*)alloc(512 * 2);
    bf16* b_ql   = (bf16*)alloc(512 * 2);
    bf16* b_qp   = (bf16*)alloc(512 * 2);
    bf16* bcat   = (bf16*)alloc(2048 * 2);     // [bkl|bvl|bkp|bvp]
    bf16* bml_c  = (bf16*)alloc(256 * 2);
    bf16* bmp_c  = (bf16*)alloc(256 * 2);
    bf16* g1c    = (bf16*)alloc(256 * 2);
    bf16* be1c   = (bf16*)alloc(256 * 2);
    bf16* g2c    = (bf16*)alloc(256 * 2);
    bf16* be2c   = (bf16*)alloc(256 * 2);
    bf16* emb_all = (bf16*)alloc((size_t)(L + Mm + P) * 512 * 2);  // [l|m|p]
    bf16* embl   = emb_all;
    bf16* embm   = emb_all + (size_t)L * 512;
    bf16* embp   = embm + (size_t)Mm * 512;
    bf16* cat_l  = (bf16*)alloc((size_t)L * 1024 * 2);   // [lt | fin_l]
    bf16* cat_p  = (bf16*)alloc((size_t)P * 1024 * 2);   // [fin_p | pt]
    bf16* mt     = (bf16*)alloc((size_t)Mm * 512 * 2);
    bf16* Ql     = (bf16*)alloc((size_t)L * 512 * 2);
    bf16* Qp     = (bf16*)alloc((size_t)P * 512 * 2);
    bf16* kvcat  = (bf16*)alloc((size_t)Mm * 2048 * 2);  // [Kl|Vl|Kp|Vp]
    unsigned char* V8lT = (unsigned char*)alloc((size_t)512 * Mm);
    unsigned char* V8pT = (unsigned char*)alloc((size_t)512 * Mm);
    bf16* ctx_l  = (bf16*)alloc((size_t)L * 512 * 2);
    bf16* ctx_p  = (bf16*)alloc((size_t)P * 512 * 2);
    unsigned char* ctx8lT = (unsigned char*)alloc((size_t)512 * L);
    unsigned char* ctx8pT = (unsigned char*)alloc((size_t)512 * P);
    unsigned char* mutual8  = (unsigned char*)alloc((size_t)L * P);
    unsigned char* mutual8T = (unsigned char*)alloc((size_t)L * P);  // OWN buffer:
    // fused TOUT epilogue writes race with awl8 reads if overlaid (r8 bug)
    unsigned char* awl8 = (unsigned char*)alloc((size_t)L * 8192);
    unsigned char* awp8 = (unsigned char*)alloc((size_t)P * 8192);
    // overlay: awp8 dead after step 6 completes; tmp written in step 8
    float* tmp1 = (float*)awp8;                          // [8192, 256] fp32

    // 1. unified prep: 18 converts + 9 square + 2 rect transposes
    PrepArgs pa;
    pa.sn = sn;
    pa.cv[0]  = { d_in[0],  embl, L * 512 };
    pa.cv[1]  = { d_in[1],  embm, Mm * 512 };
    pa.cv[2]  = { d_in[2],  embp, P * 512 };
    pa.cv[3]  = { d_in[6],  b_l,  512 };
    pa.cv[4]  = { d_in[8],  b_m,  512 };
    pa.cv[5]  = { d_in[10], b_p,  512 };
    pa.cv[6]  = { d_in[12], b_ql, 512 };
    pa.cv[7]  = { d_in[18], b_qp, 512 };
    pa.cv[8]  = { d_in[14], bcat,        512 };
    pa.cv[9]  = { d_in[16], bcat + 512,  512 };
    pa.cv[10] = { d_in[20], bcat + 1024, 512 };
    pa.cv[11] = { d_in[22], bcat + 1536, 512 };
    pa.cv[12] = { d_in[24], bml_c, 256 };
    pa.cv[13] = { d_in[26], bmp_c, 256 };
    pa.cv[14] = { d_in[27], g1c,  256 };
    pa.cv[15] = { d_in[28], be1c, 256 };
    pa.cv[16] = { d_in[29], g2c,  256 };
    pa.cv[17] = { d_in[30], be2c, 256 };
    const int slot_of[9] = {0, 1, 2, 3, 5, 6, 4, 7, 8};
    for (int i = 0; i < 9; ++i) {
        pa.tsrc[i] = d_in[5 + 2 * i];
        pa.tdst[i] = wt_all + (size_t)slot_of[i] * 512 * 512;
    }
    pa.tsrc[9]  = d_in[23]; pa.tdst[9]  = WmlT;
    pa.tsrc[10] = d_in[25]; pa.tdst[10] = WmpT;
    prep<<<dim3(256, 29), 256, 0, stream>>>(pa);

    bf16* WlT  = wt_all;
    bf16* WmT  = wt_all + (size_t)1 * 512 * 512;
    bf16* WpT  = wt_all + (size_t)2 * 512 * 512;
    bf16* WqlT = wt_all + (size_t)3 * 512 * 512;
    bf16* WqpT = wt_all + (size_t)4 * 512 * 512;
    bf16* WkvT = wt_all + (size_t)5 * 512 * 512;  // [2048, 512]

    // 2. embedding projections (segment table)
    SegTab st;
    st.W[0] = WlT;  st.bias[0] = b_l; st.C[0] = cat_l;       st.ldc[0] = 1024; st.rs[0] = 0;
    st.W[1] = WmT;  st.bias[1] = b_m; st.C[1] = mt;          st.ldc[1] = 512;  st.rs[1] = 4096;
    st.W[2] = WpT;  st.bias[2] = b_p; st.C[2] = cat_p + 512; st.ldc[2] = 1024; st.rs[2] = 5120;
    gemm_bt_seg<<<dim3(8, 144), 256, 0, stream>>>(emb_all, st, 512);

    // 3. Q projections + KV projection, one launch (z=2 remapped to 32x16)
    BtSet qs;
    qs.s[0] = { cat_l,       WqlT, Ql,    b_ql, 1024, 512, 512 };
    qs.s[1] = { cat_p + 512, WqpT, Qp,    b_qp, 1024, 512, 512 };
    qs.s[2] = { mt,          WkvT, kvcat, bcat, 512,  512, 2048 };
    gemm_btx<false, true><<<dim3(8, 64, 3), 256, 0, stream>>>(qs, 512, 1.0f);

    // 4. scores+softmax (z<2) + V quant-transpose (z=2)
    ScSet sc;
    sc.s[0] = { Ql, kvcat,        mask_l, awl8 };
    sc.s[1] = { Qp, kvcat + 1024, mask_p, awp8 };
    sc.vsrc[0] = kvcat + 512;  sc.vdst[0] = V8lT;
    sc.vsrc[1] = kvcat + 1536; sc.vdst[1] = V8pT;
    scores_v8<<<dim3(256, 8, 3), 256, 0, stream>>>(sc, 2048, 0.125f);

    // 5. ctx = relu(aw @ V) per head, fused ctx8T = e4m3(ctx^T*16)
    B8Pair cx = { { { awl8, V8lT, ctx_l, ctx8lT },
                    { awp8, V8pT, ctx_p, ctx8pT } } };
    gemm_bt8_ctx<<<dim3(8, 64, 2), 256, 0, stream>>>(
        cx, 8192, 1024, 1024, 512, 4096, 1024, 1.0f / 128.0f);

    // 6. mutual8 = e4m3((awl @ awp^T)/8 * 256), 256x128 tile, fused T-write
    MxPair mu = { { { awl8, awp8, mutual8, nullptr, mutual8T },
                    { awl8, awp8, mutual8, nullptr, mutual8T } } };
    gemm_bt8mx<256, 128, false, true, true><<<dim3(32, 16, 1), 256, 0, stream>>>(
        mu, 8192, 8192, 4096, 0, 4096, 8192, 0.03125f);

    // 7. fin (MX fp8 pair, K=4096, BN=128): scale 1/(256*16) = 1/4096
    MxPair fn = { { { mutual8,  ctx8pT, cat_l + 512, ctx_l, nullptr },
                    { mutual8T, ctx8lT, cat_p,       ctx_p, nullptr } } };
    gemm_bt8mx<64, 128, true, false, false><<<dim3(4, 64, 2), 256, 0, stream>>>(
        fn, 4096, 4096, 1024, 512, 0, 4096, 1.0f / 4096.0f);

    // 8. final projections (pair, fp32 out)
    BtSet fp;
    fp.s[0] = { cat_l, WmlT, tmp1,                   bml_c, 1024, 1024, 256 };
    fp.s[1] = { cat_p, WmpT, tmp1 + (size_t)L * 256, bmp_c, 1024, 1024, 256 };
    fp.s[2] = fp.s[0];
    gemm_btx<true, false><<<dim3(4, 64, 2), 256, 0, stream>>>(fp, 1024, 1.0f);

    // 9. merged LayerNorm -> d_out
    ln_all<<<dim3(2048), 256, 0, stream>>>(tmp1, g1c, be1c, g2c, be2c, d_out, sn);
}